// Round 6
// baseline (2666.967 us; speedup 1.0000x reference)
//
#include <hip/hip_runtime.h>
#include <hip/hip_bf16.h>
#include <math.h>

#define N_NODES 50000
#define N_EDGES 400000
#define HID 128
#define NH 8
#define HS 16
#define TN 8
#define NR 8
#define TILE 32
#define MAXTILES 1571
#define PERM_SZ (MAXTILES * TILE)
#define SCAN_BLKS ((N_NODES + 255) / 256)   // 196
#define QWNT 8                               // nodes per qw_kernel block

// ---------- node type sort (counting sort, padded segments of TILE) ----------
__global__ void hist_kernel(const int* __restrict__ ntype, int* __restrict__ cnt) {
    int i = blockIdx.x * 256 + threadIdx.x;
    if (i < N_NODES) atomicAdd(&cnt[ntype[i]], 1);
}
__global__ void scan_kernel(const int* __restrict__ cnt, int* __restrict__ cursor) {
    if (threadIdx.x == 0 && blockIdx.x == 0) {
        int acc = 0;
        for (int t = 0; t < TN; ++t) {
            cursor[t] = acc;
            acc += ((cnt[t] + TILE - 1) / TILE) * TILE;
        }
    }
}
__global__ void scatter_kernel(const int* __restrict__ ntype, int* __restrict__ cursor,
                               int* __restrict__ perm) {
    int i = blockIdx.x * 256 + threadIdx.x;
    if (i < N_NODES) {
        int p = atomicAdd(&cursor[ntype[i]], 1);
        perm[p] = i;
    }
}

// ---------- edge CSR build (sort by dst) ----------
__global__ void hist_dst_kernel(const int* __restrict__ dst, int* __restrict__ cnt) {
    int e = blockIdx.x * 256 + threadIdx.x;
    if (e < N_EDGES) atomicAdd(&cnt[dst[e]], 1);
}
__global__ void scan_block_kernel(const int* __restrict__ cnt, int* __restrict__ excl,
                                  int* __restrict__ bsum) {
    __shared__ int s[256];
    int tid = threadIdx.x;
    int i = blockIdx.x * 256 + tid;
    int v = (i < N_NODES) ? cnt[i] : 0;
    s[tid] = v;
    __syncthreads();
    for (int off = 1; off < 256; off <<= 1) {
        int t = (tid >= off) ? s[tid - off] : 0;
        __syncthreads();
        s[tid] += t;
        __syncthreads();
    }
    if (i < N_NODES) excl[i] = s[tid] - v;
    if (tid == 255) bsum[blockIdx.x] = s[255];
}
__global__ void scan_top_kernel(int* __restrict__ bsum) {
    __shared__ int s[256];
    int tid = threadIdx.x;
    int v = (tid < SCAN_BLKS) ? bsum[tid] : 0;
    s[tid] = v;
    __syncthreads();
    for (int off = 1; off < 256; off <<= 1) {
        int t = (tid >= off) ? s[tid - off] : 0;
        __syncthreads();
        s[tid] += t;
        __syncthreads();
    }
    if (tid < SCAN_BLKS) bsum[tid] = s[tid] - v;   // exclusive
}
__global__ void scan_add_kernel(int* __restrict__ excl, const int* __restrict__ bsum,
                                int* __restrict__ cursor) {
    int i = blockIdx.x * 256 + threadIdx.x;
    if (i < N_NODES) {
        int v = excl[i] + bsum[blockIdx.x];
        excl[i] = v;        // becomes row_ptr
        cursor[i] = v;
    }
}
// pack src (16 bits) | etype (upper bits)
__global__ void scatter_edge_kernel(const int* __restrict__ src, const int* __restrict__ dst,
                                    const int* __restrict__ etype, int* __restrict__ cursor,
                                    int* __restrict__ epk) {
    int e = blockIdx.x * 256 + threadIdx.x;
    if (e < N_EDGES) {
        int p = atomicAdd(&cursor[dst[e]], 1);
        epk[p] = src[e] | (etype[e] << 16);
    }
}

// ---------- tiled typed GEMM: 32 nodes x 128 outs, 3 matrices (K,Q,V) ----------
__global__ __launch_bounds__(256) void gemm3_kernel(
    const float* __restrict__ x, const int* __restrict__ perm, const int* __restrict__ ntype,
    const float* __restrict__ Wk, const float* __restrict__ Wq, const float* __restrict__ Wv,
    float* __restrict__ K, float* __restrict__ Q, float* __restrict__ V) {
    __shared__ float xs[TILE][HID];
    __shared__ int nodes[TILE];
    int tid = threadIdx.x;
    const int* pp = perm + blockIdx.x * TILE;
    if (tid < TILE) nodes[tid] = pp[tid];
    __syncthreads();
    if (nodes[0] < 0) return;
    int t = ntype[nodes[0]];
#pragma unroll
    for (int c = 0; c < 4; ++c) {
        int v = tid + c * 256;
        int ns = v >> 5, ii = (v & 31) * 4;
        int node = nodes[ns];
        float4 val = (node >= 0) ? *(const float4*)(x + (size_t)node * HID + ii)
                                 : make_float4(0.f, 0.f, 0.f, 0.f);
        *(float4*)(&xs[ns][ii]) = val;
    }
    __syncthreads();
    int og = tid & 31, ng = tid >> 5;
    int j0 = og * 4, n0 = ng * 4;
    const float* wk = Wk + (size_t)t * HID * HID + j0;
    const float* wq = Wq + (size_t)t * HID * HID + j0;
    const float* wv = Wv + (size_t)t * HID * HID + j0;
    float aK[4][4] = {{0}}, aQ[4][4] = {{0}}, aV[4][4] = {{0}};
    for (int i = 0; i < HID; i += 4) {
        float4 xr[4];
#pragma unroll
        for (int nn = 0; nn < 4; ++nn) xr[nn] = *(const float4*)(&xs[n0 + nn][i]);
#pragma unroll
        for (int ii = 0; ii < 4; ++ii) {
            float4 wkv = *(const float4*)(wk + (size_t)(i + ii) * HID);
            float4 wqv = *(const float4*)(wq + (size_t)(i + ii) * HID);
            float4 wvv = *(const float4*)(wv + (size_t)(i + ii) * HID);
#pragma unroll
            for (int nn = 0; nn < 4; ++nn) {
                float xv = ((const float*)&xr[nn])[ii];
                aK[nn][0] = fmaf(xv, wkv.x, aK[nn][0]);
                aK[nn][1] = fmaf(xv, wkv.y, aK[nn][1]);
                aK[nn][2] = fmaf(xv, wkv.z, aK[nn][2]);
                aK[nn][3] = fmaf(xv, wkv.w, aK[nn][3]);
                aQ[nn][0] = fmaf(xv, wqv.x, aQ[nn][0]);
                aQ[nn][1] = fmaf(xv, wqv.y, aQ[nn][1]);
                aQ[nn][2] = fmaf(xv, wqv.z, aQ[nn][2]);
                aQ[nn][3] = fmaf(xv, wqv.w, aQ[nn][3]);
                aV[nn][0] = fmaf(xv, wvv.x, aV[nn][0]);
                aV[nn][1] = fmaf(xv, wvv.y, aV[nn][1]);
                aV[nn][2] = fmaf(xv, wvv.z, aV[nn][2]);
                aV[nn][3] = fmaf(xv, wvv.w, aV[nn][3]);
            }
        }
    }
#pragma unroll
    for (int nn = 0; nn < 4; ++nn) {
        int node = nodes[n0 + nn];
        if (node < 0) continue;
        size_t o = (size_t)node * HID + j0;
        *(float4*)(K + o) = make_float4(aK[nn][0], aK[nn][1], aK[nn][2], aK[nn][3]);
        *(float4*)(Q + o) = make_float4(aQ[nn][0], aQ[nn][1], aQ[nn][2], aQ[nn][3]);
        *(float4*)(V + o) = make_float4(aV[nn][0], aV[nn][1], aV[nn][2], aV[nn][3]);
    }
}

// ---------- tiled GEMM, 1 matrix; perm==null -> identity rows, type 0 ----------
__global__ __launch_bounds__(256) void gemm1_kernel(
    const float* __restrict__ x, const int* __restrict__ perm, const int* __restrict__ ntype,
    const float* __restrict__ W, const float* __restrict__ bias, float* __restrict__ out) {
    __shared__ float xs[TILE][HID];
    __shared__ int nodes[TILE];
    int tid = threadIdx.x;
    if (tid < TILE) {
        int n;
        if (perm) n = perm[blockIdx.x * TILE + tid];
        else { n = blockIdx.x * TILE + tid; if (n >= N_NODES) n = -1; }
        nodes[tid] = n;
    }
    __syncthreads();
    if (nodes[0] < 0) return;
    int t = perm ? ntype[nodes[0]] : 0;
#pragma unroll
    for (int c = 0; c < 4; ++c) {
        int v = tid + c * 256;
        int ns = v >> 5, ii = (v & 31) * 4;
        int node = nodes[ns];
        float4 val = (node >= 0) ? *(const float4*)(x + (size_t)node * HID + ii)
                                 : make_float4(0.f, 0.f, 0.f, 0.f);
        *(float4*)(&xs[ns][ii]) = val;
    }
    __syncthreads();
    int og = tid & 31, ng = tid >> 5;
    int j0 = og * 4, n0 = ng * 4;
    const float* w = W + (size_t)t * HID * HID + j0;
    float acc[4][4] = {{0}};
    for (int i = 0; i < HID; i += 4) {
        float4 xr[4];
#pragma unroll
        for (int nn = 0; nn < 4; ++nn) xr[nn] = *(const float4*)(&xs[n0 + nn][i]);
#pragma unroll
        for (int ii = 0; ii < 4; ++ii) {
            float4 wv = *(const float4*)(w + (size_t)(i + ii) * HID);
#pragma unroll
            for (int nn = 0; nn < 4; ++nn) {
                float xv = ((const float*)&xr[nn])[ii];
                acc[nn][0] = fmaf(xv, wv.x, acc[nn][0]);
                acc[nn][1] = fmaf(xv, wv.y, acc[nn][1]);
                acc[nn][2] = fmaf(xv, wv.z, acc[nn][2]);
                acc[nn][3] = fmaf(xv, wv.w, acc[nn][3]);
            }
        }
    }
    float4 bv = make_float4(0.f, 0.f, 0.f, 0.f);
    if (bias) bv = *(const float4*)(bias + j0);
#pragma unroll
    for (int nn = 0; nn < 4; ++nn) {
        int node = nodes[n0 + nn];
        if (node < 0) continue;
        size_t o = (size_t)node * HID + j0;
        *(float4*)(out + o) = make_float4(acc[nn][0] + bv.x, acc[nn][1] + bv.y,
                                          acc[nn][2] + bv.z, acc[nn][3] + bv.w);
    }
}

// ---------- QW precompute: QW[n][h][i][r] (bf16) = (Watt[h,r].q_n)[i] * pri[h,r]/4 ----------
__global__ __launch_bounds__(256) void qw_kernel(
    const float* __restrict__ Q, const float* __restrict__ Watt,
    const float* __restrict__ pri, uint4* __restrict__ QW) {
    __shared__ float qs[QWNT][HID];
    __shared__ __align__(16) unsigned short os[QWNT][1024];
    int tid = threadIdx.x;
    int n0 = blockIdx.x * QWNT;
    // load 8 node q-rows (8*128 = 1024 floats = 256 float4)
    {
        int ns = tid >> 5, ii = (tid & 31) * 4;
        *(float4*)(&qs[ns][ii]) = *(const float4*)(Q + (size_t)(n0 + ns) * HID + ii);
    }
    __syncthreads();
    int hr = tid >> 2;           // (h,r) pair 0..63
    int h = hr >> 3;
    int sub = tid & 3;           // rows i = sub*4 .. sub*4+3
    const float* W = Watt + (size_t)hr * 256;
    float prs = pri[hr] * 0.25f;
    float4 wr[4][4];
#pragma unroll
    for (int ri = 0; ri < 4; ++ri)
#pragma unroll
        for (int c = 0; c < 4; ++c)
            wr[ri][c] = *(const float4*)(W + (sub * 4 + ri) * 16 + c * 4);
#pragma unroll
    for (int nn = 0; nn < QWNT; ++nn) {
        const float* q = &qs[nn][h * HS];
#pragma unroll
        for (int ri = 0; ri < 4; ++ri) {
            float s = 0.f;
#pragma unroll
            for (int c = 0; c < 4; ++c) {
                s = fmaf(wr[ri][c].x, q[c * 4 + 0], s);
                s = fmaf(wr[ri][c].y, q[c * 4 + 1], s);
                s = fmaf(wr[ri][c].z, q[c * 4 + 2], s);
                s = fmaf(wr[ri][c].w, q[c * 4 + 3], s);
            }
            __hip_bfloat16 b = __float2bfloat16(s * prs);
            int i = sub * 4 + ri;
            os[nn][(h * HS + i) * NR + (hr & 7)] = *(unsigned short*)&b;
        }
    }
    __syncthreads();
    // write 8 nodes x 2KB = 1024 uint4, coalesced
#pragma unroll
    for (int c = 0; c < 4; ++c) {
        int idx = c * 256 + tid;
        int nn = idx >> 7, off = idx & 127;
        QW[(size_t)(n0 + nn) * 128 + off] = ((const uint4*)&os[nn][0])[off];
    }
}

// ---------- fused edge pipeline v5: slot structure + hoisted relation transforms ----------
// wave per (dst,head); lane = slot*16 + o (slot = edge-in-chunk, o = dim).
// qw[r] from precomputed QW (1 uint4 load) or in-kernel fallback.
// Per edge: a = k.qw[r] (4 shfl); t[r] += ex*v (online, wave-uniform scale).
// Epilogue: slot-merge t, agg = (sum_r Wmsg[h,r]^T t[r]) / den via fold-reduce.
__global__ __launch_bounds__(256) void fused_edge_kernel(
    const float* __restrict__ K, const float* __restrict__ Q, const float* __restrict__ V,
    const int* __restrict__ row_ptr, const int* __restrict__ deg,
    const int* __restrict__ epk,
    const float* __restrict__ Watt, const float* __restrict__ Wmsg,
    const float* __restrict__ pri, const uint4* __restrict__ QW,
    float* __restrict__ agg) {
    int u = blockIdx.x * 4 + (threadIdx.x >> 6);   // (d,h) unit, grid exact
    int lane = threadIdx.x & 63;
    int d = u >> 3, h = u & 7;
    int slot = lane >> 4, o = lane & 15;

    float qw[NR];
    if (QW) {
        uint4 qp = QW[(size_t)u * HS + o];
        qw[0] = __uint_as_float(qp.x << 16);
        qw[1] = __uint_as_float(qp.x & 0xffff0000u);
        qw[2] = __uint_as_float(qp.y << 16);
        qw[3] = __uint_as_float(qp.y & 0xffff0000u);
        qw[4] = __uint_as_float(qp.z << 16);
        qw[5] = __uint_as_float(qp.z & 0xffff0000u);
        qw[6] = __uint_as_float(qp.w << 16);
        qw[7] = __uint_as_float(qp.w & 0xffff0000u);
    } else {
        float q[16];
        const float4* qp = (const float4*)(Q + (size_t)d * HID + h * HS);
#pragma unroll
        for (int c = 0; c < 4; ++c) {
            float4 qq = qp[c];
            q[c * 4 + 0] = qq.x; q[c * 4 + 1] = qq.y;
            q[c * 4 + 2] = qq.z; q[c * 4 + 3] = qq.w;
        }
        const float* Wa_h = Watt + (size_t)h * NR * 256;
#pragma unroll
        for (int r = 0; r < NR; ++r) {
            const float4* wp = (const float4*)(Wa_h + r * 256 + o * 16);
            float s = 0.f;
#pragma unroll
            for (int c = 0; c < 4; ++c) {
                float4 w = wp[c];
                s = fmaf(w.x, q[c * 4 + 0], s);
                s = fmaf(w.y, q[c * 4 + 1], s);
                s = fmaf(w.z, q[c * 4 + 2], s);
                s = fmaf(w.w, q[c * 4 + 3], s);
            }
            qw[r] = s * (pri[h * NR + r] * 0.25f);
        }
    }

    int beg = row_ptr[d], dg = deg[d];
    const int* ep = epk + beg;
    float m = -INFINITY, den = 0.f;
    float t[NR] = {0.f, 0.f, 0.f, 0.f, 0.f, 0.f, 0.f, 0.f};

    for (int c = 0; c < dg; c += 4) {
        int idx = c + slot;
        bool valid = idx < dg;
        int pk = ep[valid ? idx : dg - 1];
        int s = pk & 0xFFFF, r = pk >> 16;
        float kv = K[(size_t)s * HID + h * HS + o];
        float vv = V[(size_t)s * HID + h * HS + o];
        float qsel = qw[0];
#pragma unroll
        for (int rr = 1; rr < NR; ++rr) qsel = (r == rr) ? qw[rr] : qsel;
        float a = kv * qsel;
        a += __shfl_xor(a, 1);
        a += __shfl_xor(a, 2);
        a += __shfl_xor(a, 4);
        a += __shfl_xor(a, 8);
        if (!valid) a = -INFINITY;
        float am = fmaxf(a, __shfl_xor(a, 16));
        am = fmaxf(am, __shfl_xor(am, 32));
        float mn = fmaxf(m, am);
        float scale = (m == -INFINITY) ? 0.f : expf(m - mn);
        float ex = expf(a - mn);                  // 0 for invalid slots
        float exs = ex + __shfl_xor(ex, 16);
        exs += __shfl_xor(exs, 32);
        den = den * scale + exs;
        float exv = ex * vv;
#pragma unroll
        for (int rr = 0; rr < NR; ++rr)
            t[rr] = fmaf(t[rr], scale, (r == rr) ? exv : 0.f);
        m = mn;
    }

    // merge per-slot t partials (wave-uniform scale history makes this exact)
#pragma unroll
    for (int rr = 0; rr < NR; ++rr) {
        t[rr] += __shfl_xor(t[rr], 16);
        t[rr] += __shfl_xor(t[rr], 32);
    }

    // pa[o'] = sum_r t[r][i=o] * Wmsg[h][r][i=o][o']
    const float* Wm_h = Wmsg + (size_t)h * NR * 256;
    float pa[16];
#pragma unroll
    for (int oo = 0; oo < 16; ++oo) pa[oo] = 0.f;
#pragma unroll
    for (int r = 0; r < NR; ++r) {
        const float4* wp = (const float4*)(Wm_h + r * 256 + o * 16);
        float tr = t[r];
#pragma unroll
        for (int c = 0; c < 4; ++c) {
            float4 w = wp[c];
            pa[c * 4 + 0] = fmaf(tr, w.x, pa[c * 4 + 0]);
            pa[c * 4 + 1] = fmaf(tr, w.y, pa[c * 4 + 1]);
            pa[c * 4 + 2] = fmaf(tr, w.z, pa[c * 4 + 2]);
            pa[c * 4 + 3] = fmaf(tr, w.w, pa[c * 4 + 3]);
        }
    }
    // fold-reduce over the 16 lanes of each slot group (redundant across slots)
    float b8[8];
    {
        bool hi = (o & 8) != 0;
#pragma unroll
        for (int k2 = 0; k2 < 8; ++k2) {
            float mine = hi ? pa[k2 + 8] : pa[k2];
            float oth  = hi ? pa[k2]     : pa[k2 + 8];
            b8[k2] = mine + __shfl_xor(oth, 8);
        }
    }
    float b4[4];
    {
        bool hi = (o & 4) != 0;
#pragma unroll
        for (int k2 = 0; k2 < 4; ++k2) {
            float mine = hi ? b4[0] : b4[0];  // placeholder avoided below
            (void)mine;
            float mi = hi ? b8[k2 + 4] : b8[k2];
            float ot = hi ? b8[k2]     : b8[k2 + 4];
            b4[k2] = mi + __shfl_xor(ot, 4);
        }
    }
    float b2[2];
    {
        bool hi = (o & 2) != 0;
#pragma unroll
        for (int k2 = 0; k2 < 2; ++k2) {
            float mi = hi ? b4[k2 + 2] : b4[k2];
            float ot = hi ? b4[k2]     : b4[k2 + 2];
            b2[k2] = mi + __shfl_xor(ot, 2);
        }
    }
    float b1;
    {
        bool hi = (o & 1) != 0;
        float mi = hi ? b2[1] : b2[0];
        float ot = hi ? b2[0] : b2[1];
        b1 = mi + __shfl_xor(ot, 1);
    }
    if (slot == 0)
        agg[(size_t)d * HID + h * HS + o] = b1 / (den + 1e-16f);
}

// ---------- epilogue: SiLU + gated residual + LayerNorm ----------
__global__ void out_elem_kernel(const float* __restrict__ pre, const float* __restrict__ xin,
                                const int* __restrict__ ntype, const float* __restrict__ skip,
                                const float* __restrict__ g, const float* __restrict__ b,
                                float* __restrict__ xout) {
    int n = blockIdx.x, j = threadIdx.x;
    __shared__ float red[HID];
    int t = ntype[n];
    float acc = pre[n * HID + j];
    float sil = acc / (1.f + expf(-acc));
    float al = 1.f / (1.f + expf(-skip[t]));
    float o = sil * al + xin[n * HID + j] * (1.f - al);
    red[j] = o; __syncthreads();
    for (int s2 = 64; s2; s2 >>= 1) { if (j < s2) red[j] += red[j + s2]; __syncthreads(); }
    float mu = red[0] * (1.f / HID);
    __syncthreads();
    float dv = o - mu;
    red[j] = dv * dv; __syncthreads();
    for (int s2 = 64; s2; s2 >>= 1) { if (j < s2) red[j] += red[j + s2]; __syncthreads(); }
    float var = red[0] * (1.f / HID);
    xout[n * HID + j] = dv * rsqrtf(var + 1e-5f) * g[j] + b[j];
}

extern "C" void kernel_launch(void* const* d_in, const int* in_sizes, int n_in,
                              void* d_out, int out_size, void* d_ws, size_t ws_size,
                              hipStream_t stream) {
    const float* x     = (const float*)d_in[0];
    const int*   eidx  = (const int*)d_in[1];
    const int*   ntype = (const int*)d_in[2];
    const int*   etype = (const int*)d_in[3];
    const float* Wk    = (const float*)d_in[4];
    const float* Wq    = (const float*)d_in[5];
    const float* Wv    = (const float*)d_in[6];
    const float* Wa    = (const float*)d_in[7];
    const float* pri   = (const float*)d_in[8];
    const float* Watt  = (const float*)d_in[9];
    const float* Wmsg  = (const float*)d_in[10];
    const float* skip  = (const float*)d_in[11];
    const float* ln_g  = (const float*)d_in[12];
    const float* ln_b  = (const float*)d_in[13];
    const float* Wff   = (const float*)d_in[14];
    const float* bff   = (const float*)d_in[15];
    const int* src = eidx;
    const int* dst = eidx + N_EDGES;

    char* ws = (char*)d_ws;
    size_t szN = (size_t)N_NODES * HID * sizeof(float);        // 25.6 MB
    float* embA = (float*)(ws);
    float* Kb   = (float*)(ws + szN);
    float* Qb   = (float*)(ws + 2 * szN);                      // Q, then agg, then l1-out
    float* Vb   = (float*)(ws + 3 * szN);                      // V, then pre-activation
    char*  p    = ws + 4 * szN;
    int* perm    = (int*)p;  p += (size_t)PERM_SZ * 4;
    int* cnt     = (int*)p;  p += TN * 4;
    int* cursor  = (int*)p;  p += TN * 4;
    int* row_ptr = (int*)p;  p += (size_t)N_NODES * 4;
    int* cnt_dst = (int*)p;  p += (size_t)N_NODES * 4;
    int* cur_dst = (int*)p;  p += (size_t)N_NODES * 4;
    int* bsum    = (int*)p;  p += 256 * 4;
    int* epk     = (int*)p;  p += (size_t)N_EDGES * 4;
    // optional QW buffer: N*NH*HS*NR bf16 = 102.4 MB, 16B-aligned
    size_t qw_off = (size_t)(p - ws);
    qw_off = (qw_off + 15) & ~(size_t)15;
    size_t qw_bytes = (size_t)N_NODES * NH * HS * NR * 2;
    uint4* QW16 = (ws_size >= qw_off + qw_bytes) ? (uint4*)(ws + qw_off) : nullptr;

    // node type sort (once)
    hipMemsetAsync(cnt, 0, TN * 4, stream);
    hipMemsetAsync(perm, 0xFF, (size_t)PERM_SZ * 4, stream);
    hist_kernel<<<(N_NODES + 255) / 256, 256, 0, stream>>>(ntype, cnt);
    scan_kernel<<<1, 64, 0, stream>>>(cnt, cursor);
    scatter_kernel<<<(N_NODES + 255) / 256, 256, 0, stream>>>(ntype, cursor, perm);

    // edge CSR by dst (once)
    hipMemsetAsync(cnt_dst, 0, (size_t)N_NODES * 4, stream);
    hist_dst_kernel<<<(N_EDGES + 255) / 256, 256, 0, stream>>>(dst, cnt_dst);
    scan_block_kernel<<<SCAN_BLKS, 256, 0, stream>>>(cnt_dst, row_ptr, bsum);
    scan_top_kernel<<<1, 256, 0, stream>>>(bsum);
    scan_add_kernel<<<SCAN_BLKS, 256, 0, stream>>>(row_ptr, bsum, cur_dst);
    scatter_edge_kernel<<<(N_EDGES + 255) / 256, 256, 0, stream>>>(src, dst, etype, cur_dst,
                                                                   epk);

    for (int l = 0; l < 2; ++l) {
        const float* xin = l ? embA : x;
        float* xout = l ? Qb : embA;
        const float* Wk_l   = Wk   + (size_t)l * TN * HID * HID;
        const float* Wq_l   = Wq   + (size_t)l * TN * HID * HID;
        const float* Wv_l   = Wv   + (size_t)l * TN * HID * HID;
        const float* Wa_l   = Wa   + (size_t)l * TN * HID * HID;
        const float* Watt_l = Watt + (size_t)l * NH * NR * HS * HS;
        const float* Wmsg_l = Wmsg + (size_t)l * NH * NR * HS * HS;
        const float* pri_l  = pri  + (size_t)l * NH * NR;
        const float* skip_l = skip + (size_t)l * TN;
        const float* g_l    = ln_g + (size_t)l * HID;
        const float* b_l    = ln_b + (size_t)l * HID;

        gemm3_kernel<<<MAXTILES, 256, 0, stream>>>(xin, perm, ntype, Wk_l, Wq_l, Wv_l,
                                                   Kb, Qb, Vb);
        if (QW16)
            qw_kernel<<<N_NODES / QWNT, 256, 0, stream>>>(Qb, Watt_l, pri_l, QW16);
        // fused edge pass: agg written into Qb (Q only read via QW / own row)
        fused_edge_kernel<<<N_NODES * NH / 4, 256, 0, stream>>>(
            Kb, Qb, Vb, row_ptr, cnt_dst, epk, Watt_l, Wmsg_l, pri_l, QW16, Qb);
        // Wa typed GEMM: agg(Qb) -> pre(Vb)
        gemm1_kernel<<<MAXTILES, 256, 0, stream>>>(Qb, perm, ntype, Wa_l, nullptr, Vb);
        out_elem_kernel<<<N_NODES, HID, 0, stream>>>(Vb, xin, ntype, skip_l, g_l, b_l, xout);
    }
    // final FF: emb(Qb) @ Wff + bff -> d_out
    gemm1_kernel<<<(N_NODES + TILE - 1) / TILE, 256, 0, stream>>>(Qb, nullptr, ntype, Wff,
                                                                  bff, (float*)d_out);
}

// Round 7
// 1519.423 us; speedup vs baseline: 1.7552x; 1.7552x over previous
//
#include <hip/hip_runtime.h>
#include <hip/hip_bf16.h>
#include <math.h>

#define N_NODES 50000
#define N_EDGES 400000
#define HID 128
#define NH 8
#define HS 16
#define TN 8
#define NR 8
#define TILE 32
#define MAXTILES 1571
#define PERM_SZ (MAXTILES * TILE)
#define SCAN_BLKS ((N_NODES + 255) / 256)   // 196

typedef __attribute__((ext_vector_type(8))) short bf16x8;
typedef __attribute__((ext_vector_type(4))) float f32x4;

__device__ __forceinline__ unsigned short f2bf(float f) {
    __hip_bfloat16 h = __float2bfloat16(f);
    return *reinterpret_cast<unsigned short*>(&h);
}

// ---------- node type sort (counting sort, padded segments of TILE) ----------
__global__ void hist_kernel(const int* __restrict__ ntype, int* __restrict__ cnt) {
    int i = blockIdx.x * 256 + threadIdx.x;
    if (i < N_NODES) atomicAdd(&cnt[ntype[i]], 1);
}
__global__ void scan_kernel(const int* __restrict__ cnt, int* __restrict__ cursor) {
    if (threadIdx.x == 0 && blockIdx.x == 0) {
        int acc = 0;
        for (int t = 0; t < TN; ++t) {
            cursor[t] = acc;
            acc += ((cnt[t] + TILE - 1) / TILE) * TILE;
        }
    }
}
__global__ void scatter_kernel(const int* __restrict__ ntype, int* __restrict__ cursor,
                               int* __restrict__ perm) {
    int i = blockIdx.x * 256 + threadIdx.x;
    if (i < N_NODES) {
        int p = atomicAdd(&cursor[ntype[i]], 1);
        perm[p] = i;
    }
}

// ---------- edge CSR build (sort by dst) ----------
__global__ void hist_dst_kernel(const int* __restrict__ dst, int* __restrict__ cnt) {
    int e = blockIdx.x * 256 + threadIdx.x;
    if (e < N_EDGES) atomicAdd(&cnt[dst[e]], 1);
}
__global__ void scan_block_kernel(const int* __restrict__ cnt, int* __restrict__ excl,
                                  int* __restrict__ bsum) {
    __shared__ int s[256];
    int tid = threadIdx.x;
    int i = blockIdx.x * 256 + tid;
    int v = (i < N_NODES) ? cnt[i] : 0;
    s[tid] = v;
    __syncthreads();
    for (int off = 1; off < 256; off <<= 1) {
        int t = (tid >= off) ? s[tid - off] : 0;
        __syncthreads();
        s[tid] += t;
        __syncthreads();
    }
    if (i < N_NODES) excl[i] = s[tid] - v;
    if (tid == 255) bsum[blockIdx.x] = s[255];
}
__global__ void scan_top_kernel(int* __restrict__ bsum) {
    __shared__ int s[256];
    int tid = threadIdx.x;
    int v = (tid < SCAN_BLKS) ? bsum[tid] : 0;
    s[tid] = v;
    __syncthreads();
    for (int off = 1; off < 256; off <<= 1) {
        int t = (tid >= off) ? s[tid - off] : 0;
        __syncthreads();
        s[tid] += t;
        __syncthreads();
    }
    if (tid < SCAN_BLKS) bsum[tid] = s[tid] - v;   // exclusive
}
__global__ void scan_add_kernel(int* __restrict__ excl, const int* __restrict__ bsum,
                                int* __restrict__ cursor) {
    int i = blockIdx.x * 256 + threadIdx.x;
    if (i < N_NODES) {
        int v = excl[i] + bsum[blockIdx.x];
        excl[i] = v;        // becomes row_ptr
        cursor[i] = v;
    }
}
// pack src (16 bits) | etype (upper bits)
__global__ void scatter_edge_kernel(const int* __restrict__ src, const int* __restrict__ dst,
                                    const int* __restrict__ etype, int* __restrict__ cursor,
                                    int* __restrict__ epk) {
    int e = blockIdx.x * 256 + threadIdx.x;
    if (e < N_EDGES) {
        int p = atomicAdd(&cursor[dst[e]], 1);
        epk[p] = src[e] | (etype[e] << 16);
    }
}

// ---------- weight convert: fp32 [*, i, j] -> bf16 transposed [*, j, i] ----------
__global__ void wconv_kernel(const float* __restrict__ W, unsigned short* __restrict__ out) {
    const float* w = W + (size_t)blockIdx.x * HID * HID;
    unsigned short* o = out + (size_t)blockIdx.x * HID * HID;
#pragma unroll 4
    for (int c = 0; c < 64; ++c) {
        int idx = c * 256 + threadIdx.x;
        int i = idx >> 7, j = idx & 127;
        o[j * HID + i] = f2bf(w[idx]);
    }
}

// ---------- MFMA typed GEMM: 32 nodes x 128 outs, 3 matrices (K,Q,V) ----------
// A-frag: lane l, elem j = A[l&15][(l>>4)*8+j].  B-frag: elem j = B[(l>>4)*8+j][l&15]
// (B read from transposed bf16 weights -> contiguous 16B).  C/D: col=l&15, row=(l>>4)*4+q.
__global__ __launch_bounds__(256) void gemm3_mfma(
    const float* __restrict__ x, const int* __restrict__ perm, const int* __restrict__ ntype,
    const unsigned short* __restrict__ WkT, const unsigned short* __restrict__ WqT,
    const unsigned short* __restrict__ WvT,
    float* __restrict__ K, float* __restrict__ Q, float* __restrict__ V) {
    __shared__ unsigned short xs[TILE][HID + 8];
    __shared__ int nodes[TILE];
    int tid = threadIdx.x;
    if (tid < TILE) nodes[tid] = perm[blockIdx.x * TILE + tid];
    __syncthreads();
    if (nodes[0] < 0) return;
    int t = ntype[nodes[0]];
#pragma unroll
    for (int c = 0; c < 4; ++c) {
        int v = tid + c * 256;            // float4 index 0..1023
        int ns = v >> 5, ii = (v & 31) * 4;
        int node = nodes[ns];
        float4 val = (node >= 0) ? *(const float4*)(x + (size_t)node * HID + ii)
                                 : make_float4(0.f, 0.f, 0.f, 0.f);
        uint2 pk;
        pk.x = (unsigned)f2bf(val.x) | ((unsigned)f2bf(val.y) << 16);
        pk.y = (unsigned)f2bf(val.z) | ((unsigned)f2bf(val.w) << 16);
        *(uint2*)&xs[ns][ii] = pk;
    }
    __syncthreads();
    int wv = tid >> 6, lane = tid & 63;
    int lrow = lane & 15, lk = lane >> 4;
    bf16x8 af[2][4];
#pragma unroll
    for (int rt = 0; rt < 2; ++rt)
#pragma unroll
        for (int kk = 0; kk < 4; ++kk)
            af[rt][kk] = *(const bf16x8*)&xs[rt * 16 + lrow][kk * 32 + lk * 8];
    size_t woff = (size_t)t * HID * HID + (size_t)lrow * HID + lk * 8;
#pragma unroll
    for (int pp = 0; pp < 6; ++pp) {
        int p = wv * 6 + pp;
        int mat = p >> 3, ct = p & 7;
        const unsigned short* wb =
            (mat == 0 ? WkT : (mat == 1 ? WqT : WvT)) + woff + (size_t)ct * 16 * HID;
        float* ob = mat == 0 ? K : (mat == 1 ? Q : V);
        f32x4 a0 = {0.f, 0.f, 0.f, 0.f}, a1 = {0.f, 0.f, 0.f, 0.f};
#pragma unroll
        for (int kk = 0; kk < 4; ++kk) {
            bf16x8 bfr = *(const bf16x8*)(wb + kk * 32);
            a0 = __builtin_amdgcn_mfma_f32_16x16x32_bf16(af[0][kk], bfr, a0, 0, 0, 0);
            a1 = __builtin_amdgcn_mfma_f32_16x16x32_bf16(af[1][kk], bfr, a1, 0, 0, 0);
        }
#pragma unroll
        for (int q = 0; q < 4; ++q) {
            int r0 = lk * 4 + q;
            int n0 = nodes[r0], n1 = nodes[16 + r0];
            if (n0 >= 0) ob[(size_t)n0 * HID + ct * 16 + lrow] = a0[q];
            if (n1 >= 0) ob[(size_t)n1 * HID + ct * 16 + lrow] = a1[q];
        }
    }
}

// ---------- MFMA GEMM, 1 matrix; perm==null -> identity rows, type 0, +bias ----------
__global__ __launch_bounds__(256) void gemm1_mfma(
    const float* __restrict__ x, const int* __restrict__ perm, const int* __restrict__ ntype,
    const unsigned short* __restrict__ Wt, const float* __restrict__ bias,
    float* __restrict__ out) {
    __shared__ unsigned short xs[TILE][HID + 8];
    __shared__ int nodes[TILE];
    int tid = threadIdx.x;
    if (tid < TILE) {
        int n;
        if (perm) n = perm[blockIdx.x * TILE + tid];
        else { n = blockIdx.x * TILE + tid; if (n >= N_NODES) n = -1; }
        nodes[tid] = n;
    }
    __syncthreads();
    if (nodes[0] < 0) return;
    int t = perm ? ntype[nodes[0]] : 0;
#pragma unroll
    for (int c = 0; c < 4; ++c) {
        int v = tid + c * 256;
        int ns = v >> 5, ii = (v & 31) * 4;
        int node = nodes[ns];
        float4 val = (node >= 0) ? *(const float4*)(x + (size_t)node * HID + ii)
                                 : make_float4(0.f, 0.f, 0.f, 0.f);
        uint2 pk;
        pk.x = (unsigned)f2bf(val.x) | ((unsigned)f2bf(val.y) << 16);
        pk.y = (unsigned)f2bf(val.z) | ((unsigned)f2bf(val.w) << 16);
        *(uint2*)&xs[ns][ii] = pk;
    }
    __syncthreads();
    int wv = tid >> 6, lane = tid & 63;
    int lrow = lane & 15, lk = lane >> 4;
    bf16x8 af[2][4];
#pragma unroll
    for (int rt = 0; rt < 2; ++rt)
#pragma unroll
        for (int kk = 0; kk < 4; ++kk)
            af[rt][kk] = *(const bf16x8*)&xs[rt * 16 + lrow][kk * 32 + lk * 8];
    const unsigned short* wb0 = Wt + (size_t)t * HID * HID + (size_t)lrow * HID + lk * 8;
#pragma unroll
    for (int pp = 0; pp < 2; ++pp) {
        int ct = wv * 2 + pp;
        const unsigned short* wb = wb0 + (size_t)ct * 16 * HID;
        f32x4 a0 = {0.f, 0.f, 0.f, 0.f}, a1 = {0.f, 0.f, 0.f, 0.f};
#pragma unroll
        for (int kk = 0; kk < 4; ++kk) {
            bf16x8 bfr = *(const bf16x8*)(wb + kk * 32);
            a0 = __builtin_amdgcn_mfma_f32_16x16x32_bf16(af[0][kk], bfr, a0, 0, 0, 0);
            a1 = __builtin_amdgcn_mfma_f32_16x16x32_bf16(af[1][kk], bfr, a1, 0, 0, 0);
        }
        float bv = bias ? bias[ct * 16 + lrow] : 0.f;
#pragma unroll
        for (int q = 0; q < 4; ++q) {
            int r0 = lk * 4 + q;
            int n0 = nodes[r0], n1 = nodes[16 + r0];
            if (n0 >= 0) out[(size_t)n0 * HID + ct * 16 + lrow] = a0[q] + bv;
            if (n1 >= 0) out[(size_t)n1 * HID + ct * 16 + lrow] = a1[q] + bv;
        }
    }
}

// ---------- fused edge pipeline v2 (round-4 version, verbatim) ----------
__global__ __launch_bounds__(256) void fused_edge_kernel(
    const float* __restrict__ K, const float* __restrict__ Q, const float* __restrict__ V,
    const int* __restrict__ row_ptr, const int* __restrict__ deg,
    const int* __restrict__ epk,
    const float* __restrict__ Watt, const float* __restrict__ Wmsg,
    const float* __restrict__ pri, float* __restrict__ agg) {
    int u = blockIdx.x * 4 + (threadIdx.x >> 6);   // unit = d*NH + h, grid exact
    int lane = threadIdx.x & 63;
    int d = u >> 3, h = u & 7;
    int slot = lane >> 4, o = lane & 15;
    int base = slot << 4;

    float q_o = Q[(size_t)d * HID + h * HS + o];
    int beg = row_ptr[d], dg = deg[d];
    const float* Wa_h = Watt + (size_t)(h * NR) * HS * HS;
    const float* Wm_h = Wmsg + (size_t)(h * NR) * HS * HS;

    float m = -INFINITY, den = 0.f, acc = 0.f;

    for (int c = 0; c < dg; c += 4) {
        int idx = c + slot;
        bool valid = idx < dg;
        int pk = epk[beg + (valid ? idx : dg - 1)];
        int s = pk & 0xFFFF;
        int r = pk >> 16;
        float k_o = K[(size_t)s * HID + h * HS + o];
        float v_o = V[(size_t)s * HID + h * HS + o];
        const float* Wa_ = Wa_h + r * HS * HS;
        const float* Wm_ = Wm_h + r * HS * HS;
        float kw = 0.f, mg = 0.f;
#pragma unroll
        for (int i = 0; i < HS; ++i) {
            float ki = __shfl(k_o, base + i);
            float vi = __shfl(v_o, base + i);
            kw = fmaf(ki, Wa_[i * HS + o], kw);
            mg = fmaf(vi, Wm_[i * HS + o], mg);
        }
        float a = kw * q_o;
        a += __shfl_xor(a, 1);
        a += __shfl_xor(a, 2);
        a += __shfl_xor(a, 4);
        a += __shfl_xor(a, 8);
        a *= pri[h * NR + r] * 0.25f;
        if (!valid) a = -INFINITY;
        float am = fmaxf(a, __shfl_xor(a, 16));
        am = fmaxf(am, __shfl_xor(am, 32));
        float mn = fmaxf(m, am);
        float scale = (m == -INFINITY) ? 0.f : expf(m - mn);
        float ex = expf(a - mn);                   // 0 for invalid slots
        float exs = ex + __shfl_xor(ex, 16);
        exs += __shfl_xor(exs, 32);
        den = den * scale + exs;
        acc = acc * scale + ex * mg;
        m = mn;
    }
    acc += __shfl_xor(acc, 16);
    acc += __shfl_xor(acc, 32);
    if (slot == 0)
        agg[(size_t)d * HID + h * HS + o] = acc / (den + 1e-16f);
}

// ---------- epilogue: SiLU + gated residual + LayerNorm ----------
__global__ void out_elem_kernel(const float* __restrict__ pre, const float* __restrict__ xin,
                                const int* __restrict__ ntype, const float* __restrict__ skip,
                                const float* __restrict__ g, const float* __restrict__ b,
                                float* __restrict__ xout) {
    int n = blockIdx.x, j = threadIdx.x;
    __shared__ float red[HID];
    int t = ntype[n];
    float acc = pre[n * HID + j];
    float sil = acc / (1.f + expf(-acc));
    float al = 1.f / (1.f + expf(-skip[t]));
    float o = sil * al + xin[n * HID + j] * (1.f - al);
    red[j] = o; __syncthreads();
    for (int s2 = 64; s2; s2 >>= 1) { if (j < s2) red[j] += red[j + s2]; __syncthreads(); }
    float mu = red[0] * (1.f / HID);
    __syncthreads();
    float dv = o - mu;
    red[j] = dv * dv; __syncthreads();
    for (int s2 = 64; s2; s2 >>= 1) { if (j < s2) red[j] += red[j + s2]; __syncthreads(); }
    float var = red[0] * (1.f / HID);
    xout[n * HID + j] = dv * rsqrtf(var + 1e-5f) * g[j] + b[j];
}

extern "C" void kernel_launch(void* const* d_in, const int* in_sizes, int n_in,
                              void* d_out, int out_size, void* d_ws, size_t ws_size,
                              hipStream_t stream) {
    const float* x     = (const float*)d_in[0];
    const int*   eidx  = (const int*)d_in[1];
    const int*   ntype = (const int*)d_in[2];
    const int*   etype = (const int*)d_in[3];
    const float* Wk    = (const float*)d_in[4];
    const float* Wq    = (const float*)d_in[5];
    const float* Wv    = (const float*)d_in[6];
    const float* Wa    = (const float*)d_in[7];
    const float* pri   = (const float*)d_in[8];
    const float* Watt  = (const float*)d_in[9];
    const float* Wmsg  = (const float*)d_in[10];
    const float* skip  = (const float*)d_in[11];
    const float* ln_g  = (const float*)d_in[12];
    const float* ln_b  = (const float*)d_in[13];
    const float* Wff   = (const float*)d_in[14];
    const float* bff   = (const float*)d_in[15];
    const int* src = eidx;
    const int* dst = eidx + N_EDGES;

    char* ws = (char*)d_ws;
    size_t szN = (size_t)N_NODES * HID * sizeof(float);        // 25.6 MB
    float* embA = (float*)(ws);
    float* Kb   = (float*)(ws + szN);
    float* Qb   = (float*)(ws + 2 * szN);                      // Q, then agg, then l1-out
    float* Vb   = (float*)(ws + 3 * szN);                      // V, then pre-activation
    char*  p    = ws + 4 * szN;
    int* perm    = (int*)p;  p += (size_t)PERM_SZ * 4;
    int* cnt     = (int*)p;  p += TN * 4;
    int* cursor  = (int*)p;  p += TN * 4;
    int* row_ptr = (int*)p;  p += (size_t)N_NODES * 4;
    int* cnt_dst = (int*)p;  p += (size_t)N_NODES * 4;
    int* cur_dst = (int*)p;  p += (size_t)N_NODES * 4;
    int* bsum    = (int*)p;  p += 256 * 4;
    int* epk     = (int*)p;  p += (size_t)N_EDGES * 4;
    // bf16 transposed weights
    size_t wmat = (size_t)HID * HID;                           // 16384 elems
    unsigned short* WkT  = (unsigned short*)p;  p += 2 * TN * wmat * 2;   // 512 KB each
    unsigned short* WqT  = (unsigned short*)p;  p += 2 * TN * wmat * 2;
    unsigned short* WvT  = (unsigned short*)p;  p += 2 * TN * wmat * 2;
    unsigned short* WaT  = (unsigned short*)p;  p += 2 * TN * wmat * 2;
    unsigned short* WffT = (unsigned short*)p;  p += wmat * 2;

    // weight conversion (once per launch)
    wconv_kernel<<<2 * TN, 256, 0, stream>>>(Wk, WkT);
    wconv_kernel<<<2 * TN, 256, 0, stream>>>(Wq, WqT);
    wconv_kernel<<<2 * TN, 256, 0, stream>>>(Wv, WvT);
    wconv_kernel<<<2 * TN, 256, 0, stream>>>(Wa, WaT);
    wconv_kernel<<<1, 256, 0, stream>>>(Wff, WffT);

    // node type sort (once)
    hipMemsetAsync(cnt, 0, TN * 4, stream);
    hipMemsetAsync(perm, 0xFF, (size_t)PERM_SZ * 4, stream);
    hist_kernel<<<(N_NODES + 255) / 256, 256, 0, stream>>>(ntype, cnt);
    scan_kernel<<<1, 64, 0, stream>>>(cnt, cursor);
    scatter_kernel<<<(N_NODES + 255) / 256, 256, 0, stream>>>(ntype, cursor, perm);

    // edge CSR by dst (once)
    hipMemsetAsync(cnt_dst, 0, (size_t)N_NODES * 4, stream);
    hist_dst_kernel<<<(N_EDGES + 255) / 256, 256, 0, stream>>>(dst, cnt_dst);
    scan_block_kernel<<<SCAN_BLKS, 256, 0, stream>>>(cnt_dst, row_ptr, bsum);
    scan_top_kernel<<<1, 256, 0, stream>>>(bsum);
    scan_add_kernel<<<SCAN_BLKS, 256, 0, stream>>>(row_ptr, bsum, cur_dst);
    scatter_edge_kernel<<<(N_EDGES + 255) / 256, 256, 0, stream>>>(src, dst, etype, cur_dst,
                                                                   epk);

    for (int l = 0; l < 2; ++l) {
        const float* xin = l ? embA : x;
        float* xout = l ? Qb : embA;
        const float* Watt_l = Watt + (size_t)l * NH * NR * HS * HS;
        const float* Wmsg_l = Wmsg + (size_t)l * NH * NR * HS * HS;
        const float* pri_l  = pri  + (size_t)l * NH * NR;
        const float* skip_l = skip + (size_t)l * TN;
        const float* g_l    = ln_g + (size_t)l * HID;
        const float* b_l    = ln_b + (size_t)l * HID;
        const unsigned short* WkT_l = WkT + (size_t)l * TN * wmat;
        const unsigned short* WqT_l = WqT + (size_t)l * TN * wmat;
        const unsigned short* WvT_l = WvT + (size_t)l * TN * wmat;
        const unsigned short* WaT_l = WaT + (size_t)l * TN * wmat;

        gemm3_mfma<<<MAXTILES, 256, 0, stream>>>(xin, perm, ntype, WkT_l, WqT_l, WvT_l,
                                                 Kb, Qb, Vb);
        // fused edge pass: agg written into Qb (each (d,h) unit reads only its own Q slice)
        fused_edge_kernel<<<N_NODES * NH / 4, 256, 0, stream>>>(Kb, Qb, Vb, row_ptr, cnt_dst,
                                                                epk, Watt_l, Wmsg_l,
                                                                pri_l, Qb);
        // Wa typed GEMM: agg(Qb) -> pre(Vb)
        gemm1_mfma<<<MAXTILES, 256, 0, stream>>>(Qb, perm, ntype, WaT_l, nullptr, Vb);
        out_elem_kernel<<<N_NODES, HID, 0, stream>>>(Vb, xin, ntype, skip_l, g_l, b_l, xout);
    }
    // final FF: emb(Qb) @ Wff + bff -> d_out
    gemm1_mfma<<<(N_NODES + TILE - 1) / TILE, 256, 0, stream>>>(Qb, nullptr, ntype, WffT,
                                                                bff, (float*)d_out);
}

// Round 8
// 1280.614 us; speedup vs baseline: 2.0826x; 1.1865x over previous
//
#include <hip/hip_runtime.h>
#include <hip/hip_bf16.h>
#include <math.h>

#define N_NODES 50000
#define N_EDGES 400000
#define HID 128
#define NH 8
#define HS 16
#define TN 8
#define NR 8
#define TILE 32
#define MAXTILES 1571
#define PERM_SZ (MAXTILES * TILE)
#define SCAN_BLKS ((N_NODES + 255) / 256)   // 196
#define RL_CAP 400128                        // E + 8*16 pad, multiple of 16
#define RT_TILES (RL_CAP / 16)               // 25008 (multiple of 4)

typedef __attribute__((ext_vector_type(8))) short bf16x8;
typedef __attribute__((ext_vector_type(4))) float f32x4;

__device__ __forceinline__ unsigned short f2bf(float f) {
    __hip_bfloat16 h = __float2bfloat16(f);
    return *reinterpret_cast<unsigned short*>(&h);
}
__device__ __forceinline__ float bf2f(unsigned short u) {
    return __uint_as_float((unsigned)u << 16);
}

// ---------- node type sort (counting sort, padded segments of TILE) ----------
__global__ void hist_kernel(const int* __restrict__ ntype, int* __restrict__ cnt) {
    int i = blockIdx.x * 256 + threadIdx.x;
    if (i < N_NODES) atomicAdd(&cnt[ntype[i]], 1);
}
__global__ void scan_kernel(const int* __restrict__ cnt, int* __restrict__ cursor) {
    if (threadIdx.x == 0 && blockIdx.x == 0) {
        int acc = 0;
        for (int t = 0; t < TN; ++t) {
            cursor[t] = acc;
            acc += ((cnt[t] + TILE - 1) / TILE) * TILE;
        }
    }
}
__global__ void scatter_kernel(const int* __restrict__ ntype, int* __restrict__ cursor,
                               int* __restrict__ perm) {
    int i = blockIdx.x * 256 + threadIdx.x;
    if (i < N_NODES) {
        int p = atomicAdd(&cursor[ntype[i]], 1);
        perm[p] = i;
    }
}

// ---------- edge CSR build (sort by dst) ----------
__global__ void hist_dst_kernel(const int* __restrict__ dst, int* __restrict__ cnt) {
    int e = blockIdx.x * 256 + threadIdx.x;
    if (e < N_EDGES) atomicAdd(&cnt[dst[e]], 1);
}
__global__ void scan_block_kernel(const int* __restrict__ cnt, int* __restrict__ excl,
                                  int* __restrict__ bsum) {
    __shared__ int s[256];
    int tid = threadIdx.x;
    int i = blockIdx.x * 256 + tid;
    int v = (i < N_NODES) ? cnt[i] : 0;
    s[tid] = v;
    __syncthreads();
    for (int off = 1; off < 256; off <<= 1) {
        int t = (tid >= off) ? s[tid - off] : 0;
        __syncthreads();
        s[tid] += t;
        __syncthreads();
    }
    if (i < N_NODES) excl[i] = s[tid] - v;
    if (tid == 255) bsum[blockIdx.x] = s[255];
}
__global__ void scan_top_kernel(int* __restrict__ bsum) {
    __shared__ int s[256];
    int tid = threadIdx.x;
    int v = (tid < SCAN_BLKS) ? bsum[tid] : 0;
    s[tid] = v;
    __syncthreads();
    for (int off = 1; off < 256; off <<= 1) {
        int t = (tid >= off) ? s[tid - off] : 0;
        __syncthreads();
        s[tid] += t;
        __syncthreads();
    }
    if (tid < SCAN_BLKS) bsum[tid] = s[tid] - v;   // exclusive
}
__global__ void scan_add_kernel(int* __restrict__ excl, const int* __restrict__ bsum,
                                int* __restrict__ cursor) {
    int i = blockIdx.x * 256 + threadIdx.x;
    if (i < N_NODES) {
        int v = excl[i] + bsum[blockIdx.x];
        excl[i] = v;        // becomes row_ptr
        cursor[i] = v;
    }
}

// ---------- relation sort ----------
__global__ void ehist_kernel(const int* __restrict__ etype, int* __restrict__ ecnt) {
    __shared__ int l[NR];
    if (threadIdx.x < NR) l[threadIdx.x] = 0;
    __syncthreads();
    int e = blockIdx.x * 256 + threadIdx.x;
    if (e < N_EDGES) atomicAdd(&l[etype[e]], 1);
    __syncthreads();
    if (threadIdx.x < NR) atomicAdd(&ecnt[threadIdx.x], l[threadIdx.x]);
}
__global__ void escan_kernel(const int* __restrict__ ecnt, int* __restrict__ rbase,
                             int* __restrict__ rcur) {
    if (threadIdx.x == 0 && blockIdx.x == 0) {
        int acc = 0;
        for (int r = 0; r < NR; ++r) {
            rbase[r] = acc; rcur[r] = acc;
            acc += ((ecnt[r] + 15) / 16) * 16;
        }
        rbase[NR] = acc;
    }
}
__global__ void rinit_kernel(int* __restrict__ rsd, int* __restrict__ rpos) {
    int i = blockIdx.x * 256 + threadIdx.x;
    if (i < RL_CAP) { rsd[i] = 0; rpos[i] = N_EDGES; }   // sentinel -> scratch row E
}
// combined scatter: CSR position (by dst) + relation-sorted list entry
__global__ void rscatter_kernel(const int* __restrict__ src, const int* __restrict__ dst,
                                const int* __restrict__ etype, int* __restrict__ cur_dst,
                                int* __restrict__ rcur, int* __restrict__ rsd,
                                int* __restrict__ rpos) {
    __shared__ int lcnt[NR], lbase[NR];
    if (threadIdx.x < NR) lcnt[threadIdx.x] = 0;
    __syncthreads();
    int e = blockIdx.x * 256 + threadIdx.x;
    int r = 0, myoff = 0;
    if (e < N_EDGES) {
        r = etype[e];
        myoff = atomicAdd(&lcnt[r], 1);
    }
    __syncthreads();
    if (threadIdx.x < NR) lbase[threadIdx.x] = atomicAdd(&rcur[threadIdx.x], lcnt[threadIdx.x]);
    __syncthreads();
    if (e < N_EDGES) {
        int p = atomicAdd(&cur_dst[dst[e]], 1);
        int rp = lbase[r] + myoff;
        rsd[rp] = src[e] | (dst[e] << 16);
        rpos[rp] = p;
    }
}

// ---------- weight converts ----------
// big typed weights: fp32 [*, i, j] -> bf16 transposed [*, j, i]
__global__ void wconv_kernel(const float* __restrict__ W, unsigned short* __restrict__ out) {
    const float* w = W + (size_t)blockIdx.x * HID * HID;
    unsigned short* o = out + (size_t)blockIdx.x * HID * HID;
#pragma unroll 4
    for (int c = 0; c < 64; ++c) {
        int idx = c * 256 + threadIdx.x;
        int i = idx >> 7, j = idx & 127;
        o[j * HID + i] = f2bf(w[idx]);
    }
}
// small relation weights: fp32 [blk][i][o] -> bf16 [blk][o][i], optional pri/4 scale
__global__ void wsmall_conv(const float* __restrict__ W, const float* __restrict__ pri,
                            unsigned short* __restrict__ out) {
    int blk = blockIdx.x;                 // l*64 + h*8 + r
    int tid = threadIdx.x;                // 256 = 16x16
    int i = tid >> 4, o = tid & 15;
    float s = pri ? pri[blk] * 0.25f : 1.f;
    out[blk * 256 + o * 16 + i] = f2bf(W[blk * 256 + i * 16 + o] * s);
}

// ---------- MFMA typed GEMM: 32 nodes x 128 outs; K,V out bf16, Q out fp32 ----------
__global__ __launch_bounds__(256) void gemm3_mfma(
    const float* __restrict__ x, const int* __restrict__ perm, const int* __restrict__ ntype,
    const unsigned short* __restrict__ WkT, const unsigned short* __restrict__ WqT,
    const unsigned short* __restrict__ WvT,
    unsigned short* __restrict__ Kb, float* __restrict__ Q, unsigned short* __restrict__ Vb) {
    __shared__ unsigned short xs[TILE][HID + 8];
    __shared__ int nodes[TILE];
    int tid = threadIdx.x;
    if (tid < TILE) nodes[tid] = perm[blockIdx.x * TILE + tid];
    __syncthreads();
    if (nodes[0] < 0) return;
    int t = ntype[nodes[0]];
#pragma unroll
    for (int c = 0; c < 4; ++c) {
        int v = tid + c * 256;
        int ns = v >> 5, ii = (v & 31) * 4;
        int node = nodes[ns];
        float4 val = (node >= 0) ? *(const float4*)(x + (size_t)node * HID + ii)
                                 : make_float4(0.f, 0.f, 0.f, 0.f);
        uint2 pk;
        pk.x = (unsigned)f2bf(val.x) | ((unsigned)f2bf(val.y) << 16);
        pk.y = (unsigned)f2bf(val.z) | ((unsigned)f2bf(val.w) << 16);
        *(uint2*)&xs[ns][ii] = pk;
    }
    __syncthreads();
    int wv = tid >> 6, lane = tid & 63;
    int lrow = lane & 15, lk = lane >> 4;
    bf16x8 af[2][4];
#pragma unroll
    for (int rt = 0; rt < 2; ++rt)
#pragma unroll
        for (int kk = 0; kk < 4; ++kk)
            af[rt][kk] = *(const bf16x8*)&xs[rt * 16 + lrow][kk * 32 + lk * 8];
    size_t woff = (size_t)t * HID * HID + (size_t)lrow * HID + lk * 8;
#pragma unroll
    for (int pp = 0; pp < 6; ++pp) {
        int p = wv * 6 + pp;
        int mat = p >> 3, ct = p & 7;
        const unsigned short* wb =
            (mat == 0 ? WkT : (mat == 1 ? WqT : WvT)) + woff + (size_t)ct * 16 * HID;
        f32x4 a0 = {0.f, 0.f, 0.f, 0.f}, a1 = {0.f, 0.f, 0.f, 0.f};
#pragma unroll
        for (int kk = 0; kk < 4; ++kk) {
            bf16x8 bfr = *(const bf16x8*)(wb + kk * 32);
            a0 = __builtin_amdgcn_mfma_f32_16x16x32_bf16(af[0][kk], bfr, a0, 0, 0, 0);
            a1 = __builtin_amdgcn_mfma_f32_16x16x32_bf16(af[1][kk], bfr, a1, 0, 0, 0);
        }
        int col = ct * 16 + lrow;
#pragma unroll
        for (int q = 0; q < 4; ++q) {
            int r0 = lk * 4 + q;
            int n0 = nodes[r0], n1 = nodes[16 + r0];
            if (mat == 1) {
                if (n0 >= 0) Q[(size_t)n0 * HID + col] = a0[q];
                if (n1 >= 0) Q[(size_t)n1 * HID + col] = a1[q];
            } else {
                unsigned short* ob = (mat == 0) ? Kb : Vb;
                if (n0 >= 0) ob[(size_t)n0 * HID + col] = f2bf(a0[q]);
                if (n1 >= 0) ob[(size_t)n1 * HID + col] = f2bf(a1[q]);
            }
        }
    }
}

// ---------- MFMA GEMM, 1 matrix; perm==null -> identity rows, type 0, +bias ----------
__global__ __launch_bounds__(256) void gemm1_mfma(
    const float* __restrict__ x, const int* __restrict__ perm, const int* __restrict__ ntype,
    const unsigned short* __restrict__ Wt, const float* __restrict__ bias,
    float* __restrict__ out) {
    __shared__ unsigned short xs[TILE][HID + 8];
    __shared__ int nodes[TILE];
    int tid = threadIdx.x;
    if (tid < TILE) {
        int n;
        if (perm) n = perm[blockIdx.x * TILE + tid];
        else { n = blockIdx.x * TILE + tid; if (n >= N_NODES) n = -1; }
        nodes[tid] = n;
    }
    __syncthreads();
    if (nodes[0] < 0) return;
    int t = perm ? ntype[nodes[0]] : 0;
#pragma unroll
    for (int c = 0; c < 4; ++c) {
        int v = tid + c * 256;
        int ns = v >> 5, ii = (v & 31) * 4;
        int node = nodes[ns];
        float4 val = (node >= 0) ? *(const float4*)(x + (size_t)node * HID + ii)
                                 : make_float4(0.f, 0.f, 0.f, 0.f);
        uint2 pk;
        pk.x = (unsigned)f2bf(val.x) | ((unsigned)f2bf(val.y) << 16);
        pk.y = (unsigned)f2bf(val.z) | ((unsigned)f2bf(val.w) << 16);
        *(uint2*)&xs[ns][ii] = pk;
    }
    __syncthreads();
    int wv = tid >> 6, lane = tid & 63;
    int lrow = lane & 15, lk = lane >> 4;
    bf16x8 af[2][4];
#pragma unroll
    for (int rt = 0; rt < 2; ++rt)
#pragma unroll
        for (int kk = 0; kk < 4; ++kk)
            af[rt][kk] = *(const bf16x8*)&xs[rt * 16 + lrow][kk * 32 + lk * 8];
    const unsigned short* wb0 = Wt + (size_t)t * HID * HID + (size_t)lrow * HID + lk * 8;
#pragma unroll
    for (int pp = 0; pp < 2; ++pp) {
        int ct = wv * 2 + pp;
        const unsigned short* wb = wb0 + (size_t)ct * 16 * HID;
        f32x4 a0 = {0.f, 0.f, 0.f, 0.f}, a1 = {0.f, 0.f, 0.f, 0.f};
#pragma unroll
        for (int kk = 0; kk < 4; ++kk) {
            bf16x8 bfr = *(const bf16x8*)(wb + kk * 32);
            a0 = __builtin_amdgcn_mfma_f32_16x16x32_bf16(af[0][kk], bfr, a0, 0, 0, 0);
            a1 = __builtin_amdgcn_mfma_f32_16x16x32_bf16(af[1][kk], bfr, a1, 0, 0, 0);
        }
        float bv = bias ? bias[ct * 16 + lrow] : 0.f;
#pragma unroll
        for (int q = 0; q < 4; ++q) {
            int r0 = lk * 4 + q;
            int n0 = nodes[r0], n1 = nodes[16 + r0];
            if (n0 >= 0) out[(size_t)n0 * HID + ct * 16 + lrow] = a0[q] + bv;
            if (n1 >= 0) out[(size_t)n1 * HID + ct * 16 + lrow] = a1[q] + bv;
        }
    }
}

// ---------- edge transform: per 16-edge tile (uniform r), MFMA kw/mg + score ----------
// C = A x B : A = W^T (16 rows o, K=16 padded to 32), B = K/V rows (K=16 pad, 16 edge cols)
// A-frag lane: A[l&15][(l>>4)*8+j]; B-frag: B[(l>>4)*8+j][l&15]; C: col=l&15(edge), row=(l>>4)*4+q(o)
__global__ __launch_bounds__(256) void transform_kernel(
    const unsigned short* __restrict__ Kb, const unsigned short* __restrict__ Vb,
    const float* __restrict__ Q,
    const int* __restrict__ rsd, const int* __restrict__ rpos, const int* __restrict__ rbase,
    const unsigned short* __restrict__ WattT, const unsigned short* __restrict__ WmsgT,
    float* __restrict__ scores, unsigned short* __restrict__ mg) {
    int tw = (blockIdx.x * 256 + threadIdx.x) >> 6;    // tile id, grid exact
    int lane = threadIdx.x & 63;
    int ecol = lane & 15, lk = lane >> 4;
    int entry = tw * 16 + ecol;
    int sd = rsd[entry];
    int s = sd & 0xFFFF, dd = (sd >> 16) & 0xFFFF;
    int p = rpos[entry];
    int base16 = tw * 16;
    int r = 0;
#pragma unroll
    for (int j = 1; j < NR; ++j) r = (base16 >= rbase[j]) ? j : r;

    const bf16x8 zz = {0, 0, 0, 0, 0, 0, 0, 0};
#pragma unroll
    for (int h = 0; h < NH; ++h) {
        bf16x8 bk = zz, bv = zz, aa = zz, am = zz;
        if (lk < 2) {
            bk = *(const bf16x8*)(Kb + (size_t)s * HID + h * HS + lk * 8);
            bv = *(const bf16x8*)(Vb + (size_t)s * HID + h * HS + lk * 8);
            int wo = ((h * NR + r) * 16 + ecol) * 16 + lk * 8;
            aa = *(const bf16x8*)(WattT + wo);
            am = *(const bf16x8*)(WmsgT + wo);
        }
        f32x4 ck = {0.f, 0.f, 0.f, 0.f}, cm = {0.f, 0.f, 0.f, 0.f};
        ck = __builtin_amdgcn_mfma_f32_16x16x32_bf16(aa, bk, ck, 0, 0, 0);
        cm = __builtin_amdgcn_mfma_f32_16x16x32_bf16(am, bv, cm, 0, 0, 0);
        // score: dot(kw, q) over o; lane holds o = lk*4+q for edge ecol
        float4 qv = *(const float4*)(Q + (size_t)dd * HID + h * HS + lk * 4);
        float xsc = ck[0] * qv.x + ck[1] * qv.y + ck[2] * qv.z + ck[3] * qv.w;
        xsc += __shfl_xor(xsc, 16);
        xsc += __shfl_xor(xsc, 32);
        if (lk == 0) scores[p * NH + h] = xsc;
        uint2 pk2;
        pk2.x = (unsigned)f2bf(cm[0]) | ((unsigned)f2bf(cm[1]) << 16);
        pk2.y = (unsigned)f2bf(cm[2]) | ((unsigned)f2bf(cm[3]) << 16);
        *(uint2*)(mg + (size_t)p * HID + h * HS + lk * 4) = pk2;
    }
}

// ---------- edge softmax pass: wave per (dst,head), streams scores+mg ----------
__global__ __launch_bounds__(256) void edge_soft_kernel(
    const float* __restrict__ scores, const unsigned short* __restrict__ mg,
    const int* __restrict__ row_ptr, const int* __restrict__ deg, float* __restrict__ agg) {
    int u = blockIdx.x * 4 + (threadIdx.x >> 6);   // (d,h) unit, grid exact
    int lane = threadIdx.x & 63;
    int d = u >> 3, h = u & 7;
    int slot = lane >> 4, o = lane & 15;
    int beg = row_ptr[d], dg = deg[d];

    float m = -INFINITY, den = 0.f, acc = 0.f;
    for (int c = 0; c < dg; c += 4) {
        int idx = c + slot;
        bool valid = idx < dg;
        int p = beg + (valid ? idx : dg - 1);
        float a = scores[p * NH + h];
        float mgv = bf2f(mg[(size_t)p * HID + h * HS + o]);
        if (!valid) a = -INFINITY;
        float am = fmaxf(a, __shfl_xor(a, 16));
        am = fmaxf(am, __shfl_xor(am, 32));
        float mn = fmaxf(m, am);
        float scale = (m == -INFINITY) ? 0.f : expf(m - mn);
        float ex = expf(a - mn);
        float exs = ex + __shfl_xor(ex, 16);
        exs += __shfl_xor(exs, 32);
        den = den * scale + exs;
        acc = acc * scale + ex * mgv;
        m = mn;
    }
    acc += __shfl_xor(acc, 16);
    acc += __shfl_xor(acc, 32);
    if (slot == 0)
        agg[(size_t)d * HID + h * HS + o] = acc / (den + 1e-16f);
}

// ---------- epilogue: SiLU + gated residual + LayerNorm ----------
__global__ void out_elem_kernel(const float* __restrict__ pre, const float* __restrict__ xin,
                                const int* __restrict__ ntype, const float* __restrict__ skip,
                                const float* __restrict__ g, const float* __restrict__ b,
                                float* __restrict__ xout) {
    int n = blockIdx.x, j = threadIdx.x;
    __shared__ float red[HID];
    int t = ntype[n];
    float acc = pre[n * HID + j];
    float sil = acc / (1.f + expf(-acc));
    float al = 1.f / (1.f + expf(-skip[t]));
    float o = sil * al + xin[n * HID + j] * (1.f - al);
    red[j] = o; __syncthreads();
    for (int s2 = 64; s2; s2 >>= 1) { if (j < s2) red[j] += red[j + s2]; __syncthreads(); }
    float mu = red[0] * (1.f / HID);
    __syncthreads();
    float dv = o - mu;
    red[j] = dv * dv; __syncthreads();
    for (int s2 = 64; s2; s2 >>= 1) { if (j < s2) red[j] += red[j + s2]; __syncthreads(); }
    float var = red[0] * (1.f / HID);
    xout[n * HID + j] = dv * rsqrtf(var + 1e-5f) * g[j] + b[j];
}

extern "C" void kernel_launch(void* const* d_in, const int* in_sizes, int n_in,
                              void* d_out, int out_size, void* d_ws, size_t ws_size,
                              hipStream_t stream) {
    const float* x     = (const float*)d_in[0];
    const int*   eidx  = (const int*)d_in[1];
    const int*   ntype = (const int*)d_in[2];
    const int*   etype = (const int*)d_in[3];
    const float* Wk    = (const float*)d_in[4];
    const float* Wq    = (const float*)d_in[5];
    const float* Wv    = (const float*)d_in[6];
    const float* Wa    = (const float*)d_in[7];
    const float* pri   = (const float*)d_in[8];
    const float* Watt  = (const float*)d_in[9];
    const float* Wmsg  = (const float*)d_in[10];
    const float* skip  = (const float*)d_in[11];
    const float* ln_g  = (const float*)d_in[12];
    const float* ln_b  = (const float*)d_in[13];
    const float* Wff   = (const float*)d_in[14];
    const float* bff   = (const float*)d_in[15];
    const int* src = eidx;
    const int* dst = eidx + N_EDGES;

    char* ws = (char*)d_ws;
    size_t szN = (size_t)N_NODES * HID * sizeof(float);        // 25.6 MB
    float* embA = (float*)(ws);                                // layer-0 out
    float* Qb   = (float*)(ws + szN);                          // Q / agg / layer-1 out
    char*  kv   = ws + 2 * szN;                                // bf16 K,V; later fp32 pre
    unsigned short* Kbf = (unsigned short*)kv;
    unsigned short* Vbf = (unsigned short*)(kv + (size_t)N_NODES * HID * 2);
    float* preb = (float*)kv;
    char*  p    = ws + 3 * szN;
    int* perm    = (int*)p;  p += (size_t)PERM_SZ * 4;
    int* cnt     = (int*)p;  p += TN * 4;
    int* cursor  = (int*)p;  p += TN * 4;
    int* row_ptr = (int*)p;  p += (size_t)N_NODES * 4;
    int* cnt_dst = (int*)p;  p += (size_t)N_NODES * 4;
    int* cur_dst = (int*)p;  p += (size_t)N_NODES * 4;
    int* bsum    = (int*)p;  p += 256 * 4;
    int* ecnt    = (int*)p;  p += NR * 4;
    int* rbase   = (int*)p;  p += (NR + 1) * 4;
    int* rcur    = (int*)p;  p += NR * 4;
    int* rsd     = (int*)p;  p += (size_t)RL_CAP * 4;
    int* rpos    = (int*)p;  p += (size_t)RL_CAP * 4;
    size_t wmat = (size_t)HID * HID;
    unsigned short* WkT  = (unsigned short*)p;  p += 2 * TN * wmat * 2;
    unsigned short* WqT  = (unsigned short*)p;  p += 2 * TN * wmat * 2;
    unsigned short* WvT  = (unsigned short*)p;  p += 2 * TN * wmat * 2;
    unsigned short* WaT  = (unsigned short*)p;  p += 2 * TN * wmat * 2;
    unsigned short* WffT = (unsigned short*)p;  p += wmat * 2;
    unsigned short* WattT = (unsigned short*)p; p += 2 * 64 * 256 * 2;
    unsigned short* WmsgT = (unsigned short*)p; p += 2 * 64 * 256 * 2;
    p = (char*)(((size_t)p + 255) & ~(size_t)255);
    float* scores = (float*)p;          p += (size_t)(N_EDGES + 16) * NH * 4;   // 12.8 MB
    unsigned short* mg = (unsigned short*)p;  p += (size_t)(N_EDGES + 16) * HID * 2; // 102.4 MB

    // weight conversion (once per launch)
    wconv_kernel<<<2 * TN, 256, 0, stream>>>(Wk, WkT);
    wconv_kernel<<<2 * TN, 256, 0, stream>>>(Wq, WqT);
    wconv_kernel<<<2 * TN, 256, 0, stream>>>(Wv, WvT);
    wconv_kernel<<<2 * TN, 256, 0, stream>>>(Wa, WaT);
    wconv_kernel<<<1, 256, 0, stream>>>(Wff, WffT);
    wsmall_conv<<<128, 256, 0, stream>>>(Watt, pri, WattT);     // pri/4 baked in
    wsmall_conv<<<128, 256, 0, stream>>>(Wmsg, nullptr, WmsgT);

    // node type sort (once)
    hipMemsetAsync(cnt, 0, TN * 4, stream);
    hipMemsetAsync(perm, 0xFF, (size_t)PERM_SZ * 4, stream);
    hist_kernel<<<(N_NODES + 255) / 256, 256, 0, stream>>>(ntype, cnt);
    scan_kernel<<<1, 64, 0, stream>>>(cnt, cursor);
    scatter_kernel<<<(N_NODES + 255) / 256, 256, 0, stream>>>(ntype, cursor, perm);

    // edge CSR by dst + relation sort (once)
    hipMemsetAsync(cnt_dst, 0, (size_t)N_NODES * 4, stream);
    hipMemsetAsync(ecnt, 0, NR * 4, stream);
    hist_dst_kernel<<<(N_EDGES + 255) / 256, 256, 0, stream>>>(dst, cnt_dst);
    ehist_kernel<<<(N_EDGES + 255) / 256, 256, 0, stream>>>(etype, ecnt);
    scan_block_kernel<<<SCAN_BLKS, 256, 0, stream>>>(cnt_dst, row_ptr, bsum);
    scan_top_kernel<<<1, 256, 0, stream>>>(bsum);
    scan_add_kernel<<<SCAN_BLKS, 256, 0, stream>>>(row_ptr, bsum, cur_dst);
    escan_kernel<<<1, 64, 0, stream>>>(ecnt, rbase, rcur);
    rinit_kernel<<<(RL_CAP + 255) / 256, 256, 0, stream>>>(rsd, rpos);
    rscatter_kernel<<<(N_EDGES + 255) / 256, 256, 0, stream>>>(src, dst, etype, cur_dst,
                                                               rcur, rsd, rpos);

    for (int l = 0; l < 2; ++l) {
        const float* xin = l ? embA : x;
        float* xout = l ? Qb : embA;
        const float* skip_l = skip + (size_t)l * TN;
        const float* g_l    = ln_g + (size_t)l * HID;
        const float* b_l    = ln_b + (size_t)l * HID;
        const unsigned short* WkT_l = WkT + (size_t)l * TN * wmat;
        const unsigned short* WqT_l = WqT + (size_t)l * TN * wmat;
        const unsigned short* WvT_l = WvT + (size_t)l * TN * wmat;
        const unsigned short* WaT_l = WaT + (size_t)l * TN * wmat;
        const unsigned short* WattT_l = WattT + (size_t)l * 64 * 256;
        const unsigned short* WmsgT_l = WmsgT + (size_t)l * 64 * 256;

        gemm3_mfma<<<MAXTILES, 256, 0, stream>>>(xin, perm, ntype, WkT_l, WqT_l, WvT_l,
                                                 Kbf, Qb, Vbf);
        transform_kernel<<<RT_TILES / 4, 256, 0, stream>>>(Kbf, Vbf, Qb, rsd, rpos, rbase,
                                                           WattT_l, WmsgT_l, scores, mg);
        // softmax+aggregate: agg written into Qb (Q fully consumed by transform)
        edge_soft_kernel<<<N_NODES * NH / 4, 256, 0, stream>>>(scores, mg, row_ptr, cnt_dst,
                                                               Qb);
        // Wa typed GEMM: agg(Qb) -> pre (aliases Kbf/Vbf region, dead now)
        gemm1_mfma<<<MAXTILES, 256, 0, stream>>>(Qb, perm, ntype, WaT_l, nullptr, preb);
        out_elem_kernel<<<N_NODES, HID, 0, stream>>>(preb, xin, ntype, skip_l, g_l, b_l, xout);
    }
    // final FF: emb(Qb) @ Wff + bff -> d_out
    gemm1_mfma<<<(N_NODES + TILE - 1) / TILE, 256, 0, stream>>>(Qb, nullptr, ntype, WffT,
                                                                bff, (float*)d_out);
}

// Round 9
// 854.467 us; speedup vs baseline: 3.1212x; 1.4987x over previous
//
#include <hip/hip_runtime.h>
#include <hip/hip_bf16.h>
#include <math.h>

#define N_NODES 50000
#define N_EDGES 400000
#define HID 128
#define NH 8
#define HS 16
#define TN 8
#define NR 8
#define TILE 32
#define MAXTILES 1571
#define PERM_SZ (MAXTILES * TILE)
#define SCAN_BLKS ((N_NODES + 255) / 256)   // 196
#define RL_CAP 400128                        // E + 8*16 pad, multiple of 16
#define RT_TILES (RL_CAP / 16)               // 25008 (multiple of 4)

typedef __attribute__((ext_vector_type(8))) short bf16x8;
typedef __attribute__((ext_vector_type(4))) float f32x4;

__device__ __forceinline__ unsigned short f2bf(float f) {
    __hip_bfloat16 h = __float2bfloat16(f);
    return *reinterpret_cast<unsigned short*>(&h);
}
__device__ __forceinline__ float bf2f(unsigned short u) {
    return __uint_as_float((unsigned)u << 16);
}

// ---------- node type sort (LDS-aggregated counting sort) ----------
__global__ void hist_kernel(const int* __restrict__ ntype, int* __restrict__ cnt) {
    __shared__ int l[TN];
    if (threadIdx.x < TN) l[threadIdx.x] = 0;
    __syncthreads();
    int i = blockIdx.x * 256 + threadIdx.x;
    if (i < N_NODES) atomicAdd(&l[ntype[i]], 1);
    __syncthreads();
    if (threadIdx.x < TN) atomicAdd(&cnt[threadIdx.x], l[threadIdx.x]);
}
__global__ void scan_kernel(const int* __restrict__ cnt, int* __restrict__ cursor) {
    if (threadIdx.x == 0 && blockIdx.x == 0) {
        int acc = 0;
        for (int t = 0; t < TN; ++t) {
            cursor[t] = acc;
            acc += ((cnt[t] + TILE - 1) / TILE) * TILE;
        }
    }
}
__global__ void scatter_kernel(const int* __restrict__ ntype, int* __restrict__ cursor,
                               int* __restrict__ perm) {
    __shared__ int lcnt[TN], lbase[TN];
    if (threadIdx.x < TN) lcnt[threadIdx.x] = 0;
    __syncthreads();
    int i = blockIdx.x * 256 + threadIdx.x;
    int t = 0, off = 0;
    if (i < N_NODES) {
        t = ntype[i];
        off = atomicAdd(&lcnt[t], 1);
    }
    __syncthreads();
    if (threadIdx.x < TN)
        lbase[threadIdx.x] = atomicAdd(&cursor[threadIdx.x], lcnt[threadIdx.x]);
    __syncthreads();
    if (i < N_NODES) perm[lbase[t] + off] = i;
}

// ---------- edge CSR build (sort by dst) ----------
__global__ void hist_dst_kernel(const int* __restrict__ dst, int* __restrict__ cnt) {
    int e = blockIdx.x * 256 + threadIdx.x;
    if (e < N_EDGES) atomicAdd(&cnt[dst[e]], 1);
}
__global__ void scan_block_kernel(const int* __restrict__ cnt, int* __restrict__ excl,
                                  int* __restrict__ bsum) {
    __shared__ int s[256];
    int tid = threadIdx.x;
    int i = blockIdx.x * 256 + tid;
    int v = (i < N_NODES) ? cnt[i] : 0;
    s[tid] = v;
    __syncthreads();
    for (int off = 1; off < 256; off <<= 1) {
        int t = (tid >= off) ? s[tid - off] : 0;
        __syncthreads();
        s[tid] += t;
        __syncthreads();
    }
    if (i < N_NODES) excl[i] = s[tid] - v;
    if (tid == 255) bsum[blockIdx.x] = s[255];
}
__global__ void scan_top_kernel(int* __restrict__ bsum) {
    __shared__ int s[256];
    int tid = threadIdx.x;
    int v = (tid < SCAN_BLKS) ? bsum[tid] : 0;
    s[tid] = v;
    __syncthreads();
    for (int off = 1; off < 256; off <<= 1) {
        int t = (tid >= off) ? s[tid - off] : 0;
        __syncthreads();
        s[tid] += t;
        __syncthreads();
    }
    if (tid < SCAN_BLKS) bsum[tid] = s[tid] - v;   // exclusive
}
__global__ void scan_add_kernel(int* __restrict__ excl, const int* __restrict__ bsum,
                                int* __restrict__ cursor) {
    int i = blockIdx.x * 256 + threadIdx.x;
    if (i < N_NODES) {
        int v = excl[i] + bsum[blockIdx.x];
        excl[i] = v;        // becomes row_ptr
        cursor[i] = v;
    }
}

// ---------- relation sort ----------
__global__ void ehist_kernel(const int* __restrict__ etype, int* __restrict__ ecnt) {
    __shared__ int l[NR];
    if (threadIdx.x < NR) l[threadIdx.x] = 0;
    __syncthreads();
    int e = blockIdx.x * 256 + threadIdx.x;
    if (e < N_EDGES) atomicAdd(&l[etype[e]], 1);
    __syncthreads();
    if (threadIdx.x < NR) atomicAdd(&ecnt[threadIdx.x], l[threadIdx.x]);
}
__global__ void escan_kernel(const int* __restrict__ ecnt, int* __restrict__ rbase,
                             int* __restrict__ rcur) {
    if (threadIdx.x == 0 && blockIdx.x == 0) {
        int acc = 0;
        for (int r = 0; r < NR; ++r) {
            rbase[r] = acc; rcur[r] = acc;
            acc += ((ecnt[r] + 15) / 16) * 16;
        }
        rbase[NR] = acc;
    }
}
__global__ void rinit_kernel(int* __restrict__ rsd, int* __restrict__ rpos) {
    int i = blockIdx.x * 256 + threadIdx.x;
    if (i < RL_CAP) { rsd[i] = 0; rpos[i] = N_EDGES; }   // sentinel -> scratch row E
}
// combined scatter: CSR position (by dst) + relation-sorted list entry
__global__ void rscatter_kernel(const int* __restrict__ src, const int* __restrict__ dst,
                                const int* __restrict__ etype, int* __restrict__ cur_dst,
                                int* __restrict__ rcur, int* __restrict__ rsd,
                                int* __restrict__ rpos) {
    __shared__ int lcnt[NR], lbase[NR];
    if (threadIdx.x < NR) lcnt[threadIdx.x] = 0;
    __syncthreads();
    int e = blockIdx.x * 256 + threadIdx.x;
    int r = 0, myoff = 0;
    if (e < N_EDGES) {
        r = etype[e];
        myoff = atomicAdd(&lcnt[r], 1);
    }
    __syncthreads();
    if (threadIdx.x < NR) lbase[threadIdx.x] = atomicAdd(&rcur[threadIdx.x], lcnt[threadIdx.x]);
    __syncthreads();
    if (e < N_EDGES) {
        int p = atomicAdd(&cur_dst[dst[e]], 1);
        int rp = lbase[r] + myoff;
        rsd[rp] = src[e] | (dst[e] << 16);
        rpos[rp] = p;
    }
}

// ---------- weight converts ----------
// big typed weights: fp32 [*, i, j] -> bf16 transposed [*, j, i]; 8 blocks per matrix
__global__ void wconv_kernel(const float* __restrict__ W, unsigned short* __restrict__ out) {
    int mat = blockIdx.x >> 3, seg = blockIdx.x & 7;
    const float* w = W + (size_t)mat * HID * HID;
    unsigned short* o = out + (size_t)mat * HID * HID;
#pragma unroll
    for (int c = 0; c < 8; ++c) {
        int idx = seg * 2048 + c * 256 + threadIdx.x;
        int i = idx >> 7, j = idx & 127;
        o[j * HID + i] = f2bf(w[idx]);
    }
}
// small relation weights: fp32 [blk][i][o] -> bf16 [blk][o][i], optional pri/4 scale
__global__ void wsmall_conv(const float* __restrict__ W, const float* __restrict__ pri,
                            unsigned short* __restrict__ out) {
    int blk = blockIdx.x;                 // l*64 + h*8 + r
    int tid = threadIdx.x;                // 256 = 16x16
    int i = tid >> 4, o = tid & 15;
    float s = pri ? pri[blk] * 0.25f : 1.f;
    out[blk * 256 + o * 16 + i] = f2bf(W[blk * 256 + i * 16 + o] * s);
}

// ---------- MFMA typed GEMM: 32 nodes x 128 outs; K,V out bf16, Q out fp32 ----------
__global__ __launch_bounds__(256) void gemm3_mfma(
    const float* __restrict__ x, const int* __restrict__ perm, const int* __restrict__ ntype,
    const unsigned short* __restrict__ WkT, const unsigned short* __restrict__ WqT,
    const unsigned short* __restrict__ WvT,
    unsigned short* __restrict__ Kb, float* __restrict__ Q, unsigned short* __restrict__ Vb) {
    __shared__ unsigned short xs[TILE][HID + 8];
    __shared__ int nodes[TILE];
    int tid = threadIdx.x;
    if (tid < TILE) nodes[tid] = perm[blockIdx.x * TILE + tid];
    __syncthreads();
    if (nodes[0] < 0) return;
    int t = ntype[nodes[0]];
#pragma unroll
    for (int c = 0; c < 4; ++c) {
        int v = tid + c * 256;
        int ns = v >> 5, ii = (v & 31) * 4;
        int node = nodes[ns];
        float4 val = (node >= 0) ? *(const float4*)(x + (size_t)node * HID + ii)
                                 : make_float4(0.f, 0.f, 0.f, 0.f);
        uint2 pk;
        pk.x = (unsigned)f2bf(val.x) | ((unsigned)f2bf(val.y) << 16);
        pk.y = (unsigned)f2bf(val.z) | ((unsigned)f2bf(val.w) << 16);
        *(uint2*)&xs[ns][ii] = pk;
    }
    __syncthreads();
    int wv = tid >> 6, lane = tid & 63;
    int lrow = lane & 15, lk = lane >> 4;
    bf16x8 af[2][4];
#pragma unroll
    for (int rt = 0; rt < 2; ++rt)
#pragma unroll
        for (int kk = 0; kk < 4; ++kk)
            af[rt][kk] = *(const bf16x8*)&xs[rt * 16 + lrow][kk * 32 + lk * 8];
    size_t woff = (size_t)t * HID * HID + (size_t)lrow * HID + lk * 8;
#pragma unroll
    for (int pp = 0; pp < 6; ++pp) {
        int p = wv * 6 + pp;
        int mat = p >> 3, ct = p & 7;
        const unsigned short* wb =
            (mat == 0 ? WkT : (mat == 1 ? WqT : WvT)) + woff + (size_t)ct * 16 * HID;
        f32x4 a0 = {0.f, 0.f, 0.f, 0.f}, a1 = {0.f, 0.f, 0.f, 0.f};
#pragma unroll
        for (int kk = 0; kk < 4; ++kk) {
            bf16x8 bfr = *(const bf16x8*)(wb + kk * 32);
            a0 = __builtin_amdgcn_mfma_f32_16x16x32_bf16(af[0][kk], bfr, a0, 0, 0, 0);
            a1 = __builtin_amdgcn_mfma_f32_16x16x32_bf16(af[1][kk], bfr, a1, 0, 0, 0);
        }
        int col = ct * 16 + lrow;
#pragma unroll
        for (int q = 0; q < 4; ++q) {
            int r0 = lk * 4 + q;
            int n0 = nodes[r0], n1 = nodes[16 + r0];
            if (mat == 1) {
                if (n0 >= 0) Q[(size_t)n0 * HID + col] = a0[q];
                if (n1 >= 0) Q[(size_t)n1 * HID + col] = a1[q];
            } else {
                unsigned short* ob = (mat == 0) ? Kb : Vb;
                if (n0 >= 0) ob[(size_t)n0 * HID + col] = f2bf(a0[q]);
                if (n1 >= 0) ob[(size_t)n1 * HID + col] = f2bf(a1[q]);
            }
        }
    }
}

// ---------- MFMA GEMM, 1 matrix; perm==null -> identity rows, type 0, +bias ----------
__global__ __launch_bounds__(256) void gemm1_mfma(
    const float* __restrict__ x, const int* __restrict__ perm, const int* __restrict__ ntype,
    const unsigned short* __restrict__ Wt, const float* __restrict__ bias,
    float* __restrict__ out) {
    __shared__ unsigned short xs[TILE][HID + 8];
    __shared__ int nodes[TILE];
    int tid = threadIdx.x;
    if (tid < TILE) {
        int n;
        if (perm) n = perm[blockIdx.x * TILE + tid];
        else { n = blockIdx.x * TILE + tid; if (n >= N_NODES) n = -1; }
        nodes[tid] = n;
    }
    __syncthreads();
    if (nodes[0] < 0) return;
    int t = perm ? ntype[nodes[0]] : 0;
#pragma unroll
    for (int c = 0; c < 4; ++c) {
        int v = tid + c * 256;
        int ns = v >> 5, ii = (v & 31) * 4;
        int node = nodes[ns];
        float4 val = (node >= 0) ? *(const float4*)(x + (size_t)node * HID + ii)
                                 : make_float4(0.f, 0.f, 0.f, 0.f);
        uint2 pk;
        pk.x = (unsigned)f2bf(val.x) | ((unsigned)f2bf(val.y) << 16);
        pk.y = (unsigned)f2bf(val.z) | ((unsigned)f2bf(val.w) << 16);
        *(uint2*)&xs[ns][ii] = pk;
    }
    __syncthreads();
    int wv = tid >> 6, lane = tid & 63;
    int lrow = lane & 15, lk = lane >> 4;
    bf16x8 af[2][4];
#pragma unroll
    for (int rt = 0; rt < 2; ++rt)
#pragma unroll
        for (int kk = 0; kk < 4; ++kk)
            af[rt][kk] = *(const bf16x8*)&xs[rt * 16 + lrow][kk * 32 + lk * 8];
    const unsigned short* wb0 = Wt + (size_t)t * HID * HID + (size_t)lrow * HID + lk * 8;
#pragma unroll
    for (int pp = 0; pp < 2; ++pp) {
        int ct = wv * 2 + pp;
        const unsigned short* wb = wb0 + (size_t)ct * 16 * HID;
        f32x4 a0 = {0.f, 0.f, 0.f, 0.f}, a1 = {0.f, 0.f, 0.f, 0.f};
#pragma unroll
        for (int kk = 0; kk < 4; ++kk) {
            bf16x8 bfr = *(const bf16x8*)(wb + kk * 32);
            a0 = __builtin_amdgcn_mfma_f32_16x16x32_bf16(af[0][kk], bfr, a0, 0, 0, 0);
            a1 = __builtin_amdgcn_mfma_f32_16x16x32_bf16(af[1][kk], bfr, a1, 0, 0, 0);
        }
        float bv = bias ? bias[ct * 16 + lrow] : 0.f;
#pragma unroll
        for (int q = 0; q < 4; ++q) {
            int r0 = lk * 4 + q;
            int n0 = nodes[r0], n1 = nodes[16 + r0];
            if (n0 >= 0) out[(size_t)n0 * HID + ct * 16 + lrow] = a0[q] + bv;
            if (n1 >= 0) out[(size_t)n1 * HID + ct * 16 + lrow] = a1[q] + bv;
        }
    }
}

// ---------- edge transform: per 16-edge tile (uniform r), MFMA kw/mg + score ----------
__global__ __launch_bounds__(256) void transform_kernel(
    const unsigned short* __restrict__ Kb, const unsigned short* __restrict__ Vb,
    const float* __restrict__ Q,
    const int* __restrict__ rsd, const int* __restrict__ rpos, const int* __restrict__ rbase,
    const unsigned short* __restrict__ WattT, const unsigned short* __restrict__ WmsgT,
    float* __restrict__ scores, unsigned short* __restrict__ mg) {
    int tw = (blockIdx.x * 256 + threadIdx.x) >> 6;    // tile id, grid exact
    int lane = threadIdx.x & 63;
    int ecol = lane & 15, lk = lane >> 4;
    int entry = tw * 16 + ecol;
    int sd = rsd[entry];
    int s = sd & 0xFFFF, dd = (sd >> 16) & 0xFFFF;
    int p = rpos[entry];
    int base16 = tw * 16;
    int r = 0;
#pragma unroll
    for (int j = 1; j < NR; ++j) r = (base16 >= rbase[j]) ? j : r;

    const bf16x8 zz = {0, 0, 0, 0, 0, 0, 0, 0};
#pragma unroll
    for (int h = 0; h < NH; ++h) {
        bf16x8 bk = zz, bv = zz, aa = zz, am = zz;
        if (lk < 2) {
            bk = *(const bf16x8*)(Kb + (size_t)s * HID + h * HS + lk * 8);
            bv = *(const bf16x8*)(Vb + (size_t)s * HID + h * HS + lk * 8);
            int wo = ((h * NR + r) * 16 + ecol) * 16 + lk * 8;
            aa = *(const bf16x8*)(WattT + wo);
            am = *(const bf16x8*)(WmsgT + wo);
        }
        f32x4 ck = {0.f, 0.f, 0.f, 0.f}, cm = {0.f, 0.f, 0.f, 0.f};
        ck = __builtin_amdgcn_mfma_f32_16x16x32_bf16(aa, bk, ck, 0, 0, 0);
        cm = __builtin_amdgcn_mfma_f32_16x16x32_bf16(am, bv, cm, 0, 0, 0);
        // score: dot(kw, q) over o; lane holds o = lk*4+q for edge ecol
        float4 qv = *(const float4*)(Q + (size_t)dd * HID + h * HS + lk * 4);
        float xsc = ck[0] * qv.x + ck[1] * qv.y + ck[2] * qv.z + ck[3] * qv.w;
        xsc += __shfl_xor(xsc, 16);
        xsc += __shfl_xor(xsc, 32);
        if (lk == 0) scores[p * NH + h] = xsc;
        uint2 pk2;
        pk2.x = (unsigned)f2bf(cm[0]) | ((unsigned)f2bf(cm[1]) << 16);
        pk2.y = (unsigned)f2bf(cm[2]) | ((unsigned)f2bf(cm[3]) << 16);
        *(uint2*)(mg + (size_t)p * HID + h * HS + lk * 4) = pk2;
    }
}

// ---------- edge softmax pass: wave per (dst,head), streams scores+mg ----------
__global__ __launch_bounds__(256) void edge_soft_kernel(
    const float* __restrict__ scores, const unsigned short* __restrict__ mg,
    const int* __restrict__ row_ptr, const int* __restrict__ deg, float* __restrict__ agg) {
    int u = blockIdx.x * 4 + (threadIdx.x >> 6);   // (d,h) unit, grid exact
    int lane = threadIdx.x & 63;
    int d = u >> 3, h = u & 7;
    int slot = lane >> 4, o = lane & 15;
    int beg = row_ptr[d], dg = deg[d];

    float m = -INFINITY, den = 0.f, acc = 0.f;
    for (int c = 0; c < dg; c += 4) {
        int idx = c + slot;
        bool valid = idx < dg;
        int p = beg + (valid ? idx : dg - 1);
        float a = scores[p * NH + h];
        float mgv = bf2f(mg[(size_t)p * HID + h * HS + o]);
        if (!valid) a = -INFINITY;
        float am = fmaxf(a, __shfl_xor(a, 16));
        am = fmaxf(am, __shfl_xor(am, 32));
        float mn = fmaxf(m, am);
        float scale = (m == -INFINITY) ? 0.f : expf(m - mn);
        float ex = expf(a - mn);
        float exs = ex + __shfl_xor(ex, 16);
        exs += __shfl_xor(exs, 32);
        den = den * scale + exs;
        acc = acc * scale + ex * mgv;
        m = mn;
    }
    acc += __shfl_xor(acc, 16);
    acc += __shfl_xor(acc, 32);
    if (slot == 0)
        agg[(size_t)d * HID + h * HS + o] = acc / (den + 1e-16f);
}

// ---------- epilogue: SiLU + gated residual + LayerNorm ----------
__global__ void out_elem_kernel(const float* __restrict__ pre, const float* __restrict__ xin,
                                const int* __restrict__ ntype, const float* __restrict__ skip,
                                const float* __restrict__ g, const float* __restrict__ b,
                                float* __restrict__ xout) {
    int n = blockIdx.x, j = threadIdx.x;
    __shared__ float red[HID];
    int t = ntype[n];
    float acc = pre[n * HID + j];
    float sil = acc / (1.f + expf(-acc));
    float al = 1.f / (1.f + expf(-skip[t]));
    float o = sil * al + xin[n * HID + j] * (1.f - al);
    red[j] = o; __syncthreads();
    for (int s2 = 64; s2; s2 >>= 1) { if (j < s2) red[j] += red[j + s2]; __syncthreads(); }
    float mu = red[0] * (1.f / HID);
    __syncthreads();
    float dv = o - mu;
    red[j] = dv * dv; __syncthreads();
    for (int s2 = 64; s2; s2 >>= 1) { if (j < s2) red[j] += red[j + s2]; __syncthreads(); }
    float var = red[0] * (1.f / HID);
    xout[n * HID + j] = dv * rsqrtf(var + 1e-5f) * g[j] + b[j];
}

extern "C" void kernel_launch(void* const* d_in, const int* in_sizes, int n_in,
                              void* d_out, int out_size, void* d_ws, size_t ws_size,
                              hipStream_t stream) {
    const float* x     = (const float*)d_in[0];
    const int*   eidx  = (const int*)d_in[1];
    const int*   ntype = (const int*)d_in[2];
    const int*   etype = (const int*)d_in[3];
    const float* Wk    = (const float*)d_in[4];
    const float* Wq    = (const float*)d_in[5];
    const float* Wv    = (const float*)d_in[6];
    const float* Wa    = (const float*)d_in[7];
    const float* pri   = (const float*)d_in[8];
    const float* Watt  = (const float*)d_in[9];
    const float* Wmsg  = (const float*)d_in[10];
    const float* skip  = (const float*)d_in[11];
    const float* ln_g  = (const float*)d_in[12];
    const float* ln_b  = (const float*)d_in[13];
    const float* Wff   = (const float*)d_in[14];
    const float* bff   = (const float*)d_in[15];
    const int* src = eidx;
    const int* dst = eidx + N_EDGES;

    char* ws = (char*)d_ws;
    size_t szN = (size_t)N_NODES * HID * sizeof(float);        // 25.6 MB
    float* embA = (float*)(ws);                                // layer-0 out
    float* Qb   = (float*)(ws + szN);                          // Q / agg / layer-1 out
    char*  kv   = ws + 2 * szN;                                // bf16 K,V; later fp32 pre
    unsigned short* Kbf = (unsigned short*)kv;
    unsigned short* Vbf = (unsigned short*)(kv + (size_t)N_NODES * HID * 2);
    float* preb = (float*)kv;
    char*  p    = ws + 3 * szN;
    int* perm    = (int*)p;  p += (size_t)PERM_SZ * 4;
    int* cnt     = (int*)p;  p += TN * 4;
    int* cursor  = (int*)p;  p += TN * 4;
    int* row_ptr = (int*)p;  p += (size_t)N_NODES * 4;
    int* cnt_dst = (int*)p;  p += (size_t)N_NODES * 4;
    int* cur_dst = (int*)p;  p += (size_t)N_NODES * 4;
    int* bsum    = (int*)p;  p += 256 * 4;
    int* ecnt    = (int*)p;  p += NR * 4;
    int* rbase   = (int*)p;  p += (NR + 1) * 4;
    int* rcur    = (int*)p;  p += NR * 4;
    int* rsd     = (int*)p;  p += (size_t)RL_CAP * 4;
    int* rpos    = (int*)p;  p += (size_t)RL_CAP * 4;
    size_t wmat = (size_t)HID * HID;
    unsigned short* WkT  = (unsigned short*)p;  p += 2 * TN * wmat * 2;
    unsigned short* WqT  = (unsigned short*)p;  p += 2 * TN * wmat * 2;
    unsigned short* WvT  = (unsigned short*)p;  p += 2 * TN * wmat * 2;
    unsigned short* WaT  = (unsigned short*)p;  p += 2 * TN * wmat * 2;
    unsigned short* WffT = (unsigned short*)p;  p += wmat * 2;
    unsigned short* WattT = (unsigned short*)p; p += 2 * 64 * 256 * 2;
    unsigned short* WmsgT = (unsigned short*)p; p += 2 * 64 * 256 * 2;
    p = (char*)(((size_t)p + 255) & ~(size_t)255);
    float* scores = (float*)p;          p += (size_t)(N_EDGES + 16) * NH * 4;   // 12.8 MB
    unsigned short* mg = (unsigned short*)p;  p += (size_t)(N_EDGES + 16) * HID * 2; // 102.4 MB

    // weight conversion (once per launch)
    wconv_kernel<<<2 * TN * 8, 256, 0, stream>>>(Wk, WkT);
    wconv_kernel<<<2 * TN * 8, 256, 0, stream>>>(Wq, WqT);
    wconv_kernel<<<2 * TN * 8, 256, 0, stream>>>(Wv, WvT);
    wconv_kernel<<<2 * TN * 8, 256, 0, stream>>>(Wa, WaT);
    wconv_kernel<<<8, 256, 0, stream>>>(Wff, WffT);
    wsmall_conv<<<128, 256, 0, stream>>>(Watt, pri, WattT);     // pri/4 baked in
    wsmall_conv<<<128, 256, 0, stream>>>(Wmsg, nullptr, WmsgT);

    // node type sort (once)
    hipMemsetAsync(cnt, 0, TN * 4, stream);
    hipMemsetAsync(perm, 0xFF, (size_t)PERM_SZ * 4, stream);
    hist_kernel<<<(N_NODES + 255) / 256, 256, 0, stream>>>(ntype, cnt);
    scan_kernel<<<1, 64, 0, stream>>>(cnt, cursor);
    scatter_kernel<<<(N_NODES + 255) / 256, 256, 0, stream>>>(ntype, cursor, perm);

    // edge CSR by dst + relation sort (once)
    hipMemsetAsync(cnt_dst, 0, (size_t)N_NODES * 4, stream);
    hipMemsetAsync(ecnt, 0, NR * 4, stream);
    hist_dst_kernel<<<(N_EDGES + 255) / 256, 256, 0, stream>>>(dst, cnt_dst);
    ehist_kernel<<<(N_EDGES + 255) / 256, 256, 0, stream>>>(etype, ecnt);
    scan_block_kernel<<<SCAN_BLKS, 256, 0, stream>>>(cnt_dst, row_ptr, bsum);
    scan_top_kernel<<<1, 256, 0, stream>>>(bsum);
    scan_add_kernel<<<SCAN_BLKS, 256, 0, stream>>>(row_ptr, bsum, cur_dst);
    escan_kernel<<<1, 64, 0, stream>>>(ecnt, rbase, rcur);
    rinit_kernel<<<(RL_CAP + 255) / 256, 256, 0, stream>>>(rsd, rpos);
    rscatter_kernel<<<(N_EDGES + 255) / 256, 256, 0, stream>>>(src, dst, etype, cur_dst,
                                                               rcur, rsd, rpos);

    for (int l = 0; l < 2; ++l) {
        const float* xin = l ? embA : x;
        float* xout = l ? Qb : embA;
        const float* skip_l = skip + (size_t)l * TN;
        const float* g_l    = ln_g + (size_t)l * HID;
        const float* b_l    = ln_b + (size_t)l * HID;
        const unsigned short* WkT_l = WkT + (size_t)l * TN * wmat;
        const unsigned short* WqT_l = WqT + (size_t)l * TN * wmat;
        const unsigned short* WvT_l = WvT + (size_t)l * TN * wmat;
        const unsigned short* WaT_l = WaT + (size_t)l * TN * wmat;
        const unsigned short* WattT_l = WattT + (size_t)l * 64 * 256;
        const unsigned short* WmsgT_l = WmsgT + (size_t)l * 64 * 256;

        gemm3_mfma<<<MAXTILES, 256, 0, stream>>>(xin, perm, ntype, WkT_l, WqT_l, WvT_l,
                                                 Kbf, Qb, Vbf);
        transform_kernel<<<RT_TILES / 4, 256, 0, stream>>>(Kbf, Vbf, Qb, rsd, rpos, rbase,
                                                           WattT_l, WmsgT_l, scores, mg);
        // softmax+aggregate: agg written into Qb (Q fully consumed by transform)
        edge_soft_kernel<<<N_NODES * NH / 4, 256, 0, stream>>>(scores, mg, row_ptr, cnt_dst,
                                                               Qb);
        // Wa typed GEMM: agg(Qb) -> pre (aliases Kbf/Vbf region, dead now)
        gemm1_mfma<<<MAXTILES, 256, 0, stream>>>(Qb, perm, ntype, WaT_l, nullptr, preb);
        out_elem_kernel<<<N_NODES, HID, 0, stream>>>(preb, xin, ntype, skip_l, g_l, b_l, xout);
    }
    // final FF: emb(Qb) @ Wff + bff -> d_out
    gemm1_mfma<<<(N_NODES + TILE - 1) / TILE, 256, 0, stream>>>(Qb, nullptr, ntype, WffT,
                                                                bff, (float*)d_out);
}

// Round 10
// 772.795 us; speedup vs baseline: 3.4511x; 1.1057x over previous
//
#include <hip/hip_runtime.h>
#include <hip/hip_bf16.h>
#include <math.h>

#define N_NODES 50000
#define N_EDGES 400000
#define HID 128
#define NH 8
#define HS 16
#define TN 8
#define NR 8
#define TILE 32
#define MAXTILES 1571
#define PERM_SZ (MAXTILES * TILE)
#define SCAN_BLKS ((N_NODES + 255) / 256)   // 196
#define RL_CAP 400128                        // E + 8*16 pad, multiple of 16
#define RT_TILES (RL_CAP / 16)               // 25008 (multiple of 4)

typedef __attribute__((ext_vector_type(8))) short bf16x8;
typedef __attribute__((ext_vector_type(4))) float f32x4;

__device__ __forceinline__ unsigned short f2bf(float f) {
    __hip_bfloat16 h = __float2bfloat16(f);
    return *reinterpret_cast<unsigned short*>(&h);
}
__device__ __forceinline__ float bf2f(unsigned short u) {
    return __uint_as_float((unsigned)u << 16);
}

// ---------- node type sort (LDS-aggregated counting sort) ----------
__global__ void hist_kernel(const int* __restrict__ ntype, int* __restrict__ cnt) {
    __shared__ int l[TN];
    if (threadIdx.x < TN) l[threadIdx.x] = 0;
    __syncthreads();
    int i = blockIdx.x * 256 + threadIdx.x;
    if (i < N_NODES) atomicAdd(&l[ntype[i]], 1);
    __syncthreads();
    if (threadIdx.x < TN) atomicAdd(&cnt[threadIdx.x], l[threadIdx.x]);
}
__global__ void scan_kernel(const int* __restrict__ cnt, int* __restrict__ cursor) {
    if (threadIdx.x == 0 && blockIdx.x == 0) {
        int acc = 0;
        for (int t = 0; t < TN; ++t) {
            cursor[t] = acc;
            acc += ((cnt[t] + TILE - 1) / TILE) * TILE;
        }
    }
}
__global__ void scatter_kernel(const int* __restrict__ ntype, int* __restrict__ cursor,
                               int* __restrict__ perm) {
    __shared__ int lcnt[TN], lbase[TN];
    if (threadIdx.x < TN) lcnt[threadIdx.x] = 0;
    __syncthreads();
    int i = blockIdx.x * 256 + threadIdx.x;
    int t = 0, off = 0;
    if (i < N_NODES) {
        t = ntype[i];
        off = atomicAdd(&lcnt[t], 1);
    }
    __syncthreads();
    if (threadIdx.x < TN)
        lbase[threadIdx.x] = atomicAdd(&cursor[threadIdx.x], lcnt[threadIdx.x]);
    __syncthreads();
    if (i < N_NODES) perm[lbase[t] + off] = i;
}

// ---------- edge CSR build (sort by dst) ----------
__global__ void hist_dst_kernel(const int* __restrict__ dst, int* __restrict__ cnt) {
    int e = blockIdx.x * 256 + threadIdx.x;
    if (e < N_EDGES) atomicAdd(&cnt[dst[e]], 1);
}
__global__ void scan_block_kernel(const int* __restrict__ cnt, int* __restrict__ excl,
                                  int* __restrict__ bsum) {
    __shared__ int s[256];
    int tid = threadIdx.x;
    int i = blockIdx.x * 256 + tid;
    int v = (i < N_NODES) ? cnt[i] : 0;
    s[tid] = v;
    __syncthreads();
    for (int off = 1; off < 256; off <<= 1) {
        int t = (tid >= off) ? s[tid - off] : 0;
        __syncthreads();
        s[tid] += t;
        __syncthreads();
    }
    if (i < N_NODES) excl[i] = s[tid] - v;
    if (tid == 255) bsum[blockIdx.x] = s[255];
}
__global__ void scan_top_kernel(int* __restrict__ bsum) {
    __shared__ int s[256];
    int tid = threadIdx.x;
    int v = (tid < SCAN_BLKS) ? bsum[tid] : 0;
    s[tid] = v;
    __syncthreads();
    for (int off = 1; off < 256; off <<= 1) {
        int t = (tid >= off) ? s[tid - off] : 0;
        __syncthreads();
        s[tid] += t;
        __syncthreads();
    }
    if (tid < SCAN_BLKS) bsum[tid] = s[tid] - v;   // exclusive
}
__global__ void scan_add_kernel(int* __restrict__ excl, const int* __restrict__ bsum,
                                int* __restrict__ cursor) {
    int i = blockIdx.x * 256 + threadIdx.x;
    if (i < N_NODES) {
        int v = excl[i] + bsum[blockIdx.x];
        excl[i] = v;        // becomes row_ptr
        cursor[i] = v;
    }
}
// pass 1: place edges at CSR positions (by dst)
__global__ void csr_scatter_kernel(const int* __restrict__ src, const int* __restrict__ dst,
                                   const int* __restrict__ etype, int* __restrict__ cur_dst,
                                   int* __restrict__ csr_sd, int* __restrict__ csr_et) {
    int e = blockIdx.x * 256 + threadIdx.x;
    if (e < N_EDGES) {
        int p = atomicAdd(&cur_dst[dst[e]], 1);
        csr_sd[p] = src[e] | (dst[e] << 16);
        csr_et[p] = etype[e];
    }
}

// ---------- relation sort (approximately CSR-ordered within segments) ----------
__global__ void ehist_kernel(const int* __restrict__ etype, int* __restrict__ ecnt) {
    __shared__ int l[NR];
    if (threadIdx.x < NR) l[threadIdx.x] = 0;
    __syncthreads();
    int e = blockIdx.x * 256 + threadIdx.x;
    if (e < N_EDGES) atomicAdd(&l[etype[e]], 1);
    __syncthreads();
    if (threadIdx.x < NR) atomicAdd(&ecnt[threadIdx.x], l[threadIdx.x]);
}
__global__ void escan_kernel(const int* __restrict__ ecnt, int* __restrict__ rbase,
                             int* __restrict__ rcur) {
    if (threadIdx.x == 0 && blockIdx.x == 0) {
        int acc = 0;
        for (int r = 0; r < NR; ++r) {
            rbase[r] = acc; rcur[r] = acc;
            acc += ((ecnt[r] + 15) / 16) * 16;
        }
        rbase[NR] = acc;
    }
}
__global__ void rinit_kernel(int* __restrict__ rsd, int* __restrict__ rpos) {
    int i = blockIdx.x * 256 + threadIdx.x;
    if (i < RL_CAP) { rsd[i] = 0; rpos[i] = N_EDGES; }   // sentinel -> scratch row E
}
// pass 2: walk CSR positions in order, append to relation segments
__global__ void rel_scatter_kernel(const int* __restrict__ csr_sd, const int* __restrict__ csr_et,
                                   int* __restrict__ rcur, int* __restrict__ rsd,
                                   int* __restrict__ rpos) {
    __shared__ int lcnt[NR], lbase[NR];
    if (threadIdx.x < NR) lcnt[threadIdx.x] = 0;
    __syncthreads();
    int p = blockIdx.x * 256 + threadIdx.x;
    int r = 0, off = 0;
    if (p < N_EDGES) {
        r = csr_et[p];
        off = atomicAdd(&lcnt[r], 1);
    }
    __syncthreads();
    if (threadIdx.x < NR) lbase[threadIdx.x] = atomicAdd(&rcur[threadIdx.x], lcnt[threadIdx.x]);
    __syncthreads();
    if (p < N_EDGES) {
        int rp = lbase[r] + off;
        rsd[rp] = csr_sd[p];
        rpos[rp] = p;
    }
}

// ---------- weight converts ----------
__global__ void wconv_kernel(const float* __restrict__ W, unsigned short* __restrict__ out) {
    int mat = blockIdx.x >> 3, seg = blockIdx.x & 7;
    const float* w = W + (size_t)mat * HID * HID;
    unsigned short* o = out + (size_t)mat * HID * HID;
#pragma unroll
    for (int c = 0; c < 8; ++c) {
        int idx = seg * 2048 + c * 256 + threadIdx.x;
        int i = idx >> 7, j = idx & 127;
        o[j * HID + i] = f2bf(w[idx]);
    }
}
__global__ void wsmall_conv(const float* __restrict__ W, const float* __restrict__ pri,
                            unsigned short* __restrict__ out) {
    int blk = blockIdx.x;                 // l*64 + h*8 + r
    int tid = threadIdx.x;                // 256 = 16x16
    int i = tid >> 4, o = tid & 15;
    float s = pri ? pri[blk] * 0.25f : 1.f;
    out[blk * 256 + o * 16 + i] = f2bf(W[blk * 256 + i * 16 + o] * s);
}

// ---------- MFMA typed GEMM: 32 nodes x 128 outs; K,Q,V all bf16 ----------
__global__ __launch_bounds__(256) void gemm3_mfma(
    const float* __restrict__ x, const int* __restrict__ perm, const int* __restrict__ ntype,
    const unsigned short* __restrict__ WkT, const unsigned short* __restrict__ WqT,
    const unsigned short* __restrict__ WvT,
    unsigned short* __restrict__ Kb, unsigned short* __restrict__ Qb,
    unsigned short* __restrict__ Vb) {
    __shared__ unsigned short xs[TILE][HID + 8];
    __shared__ int nodes[TILE];
    int tid = threadIdx.x;
    if (tid < TILE) nodes[tid] = perm[blockIdx.x * TILE + tid];
    __syncthreads();
    if (nodes[0] < 0) return;
    int t = ntype[nodes[0]];
#pragma unroll
    for (int c = 0; c < 4; ++c) {
        int v = tid + c * 256;
        int ns = v >> 5, ii = (v & 31) * 4;
        int node = nodes[ns];
        float4 val = (node >= 0) ? *(const float4*)(x + (size_t)node * HID + ii)
                                 : make_float4(0.f, 0.f, 0.f, 0.f);
        uint2 pk;
        pk.x = (unsigned)f2bf(val.x) | ((unsigned)f2bf(val.y) << 16);
        pk.y = (unsigned)f2bf(val.z) | ((unsigned)f2bf(val.w) << 16);
        *(uint2*)&xs[ns][ii] = pk;
    }
    __syncthreads();
    int wv = tid >> 6, lane = tid & 63;
    int lrow = lane & 15, lk = lane >> 4;
    bf16x8 af[2][4];
#pragma unroll
    for (int rt = 0; rt < 2; ++rt)
#pragma unroll
        for (int kk = 0; kk < 4; ++kk)
            af[rt][kk] = *(const bf16x8*)&xs[rt * 16 + lrow][kk * 32 + lk * 8];
    size_t woff = (size_t)t * HID * HID + (size_t)lrow * HID + lk * 8;
#pragma unroll
    for (int pp = 0; pp < 6; ++pp) {
        int p = wv * 6 + pp;
        int mat = p >> 3, ct = p & 7;
        const unsigned short* wb =
            (mat == 0 ? WkT : (mat == 1 ? WqT : WvT)) + woff + (size_t)ct * 16 * HID;
        unsigned short* ob = (mat == 0) ? Kb : (mat == 1 ? Qb : Vb);
        f32x4 a0 = {0.f, 0.f, 0.f, 0.f}, a1 = {0.f, 0.f, 0.f, 0.f};
#pragma unroll
        for (int kk = 0; kk < 4; ++kk) {
            bf16x8 bfr = *(const bf16x8*)(wb + kk * 32);
            a0 = __builtin_amdgcn_mfma_f32_16x16x32_bf16(af[0][kk], bfr, a0, 0, 0, 0);
            a1 = __builtin_amdgcn_mfma_f32_16x16x32_bf16(af[1][kk], bfr, a1, 0, 0, 0);
        }
        int col = ct * 16 + lrow;
#pragma unroll
        for (int q = 0; q < 4; ++q) {
            int r0 = lk * 4 + q;
            int n0 = nodes[r0], n1 = nodes[16 + r0];
            if (n0 >= 0) ob[(size_t)n0 * HID + col] = f2bf(a0[q]);
            if (n1 >= 0) ob[(size_t)n1 * HID + col] = f2bf(a1[q]);
        }
    }
}

// ---------- MFMA GEMM (plain, fp32 in, fp32 out, +bias) for final FF ----------
__global__ __launch_bounds__(256) void gemm1_mfma(
    const float* __restrict__ x, const int* __restrict__ perm, const int* __restrict__ ntype,
    const unsigned short* __restrict__ Wt, const float* __restrict__ bias,
    float* __restrict__ out) {
    __shared__ unsigned short xs[TILE][HID + 8];
    __shared__ int nodes[TILE];
    int tid = threadIdx.x;
    if (tid < TILE) {
        int n;
        if (perm) n = perm[blockIdx.x * TILE + tid];
        else { n = blockIdx.x * TILE + tid; if (n >= N_NODES) n = -1; }
        nodes[tid] = n;
    }
    __syncthreads();
    if (nodes[0] < 0) return;
    int t = perm ? ntype[nodes[0]] : 0;
#pragma unroll
    for (int c = 0; c < 4; ++c) {
        int v = tid + c * 256;
        int ns = v >> 5, ii = (v & 31) * 4;
        int node = nodes[ns];
        float4 val = (node >= 0) ? *(const float4*)(x + (size_t)node * HID + ii)
                                 : make_float4(0.f, 0.f, 0.f, 0.f);
        uint2 pk;
        pk.x = (unsigned)f2bf(val.x) | ((unsigned)f2bf(val.y) << 16);
        pk.y = (unsigned)f2bf(val.z) | ((unsigned)f2bf(val.w) << 16);
        *(uint2*)&xs[ns][ii] = pk;
    }
    __syncthreads();
    int wv = tid >> 6, lane = tid & 63;
    int lrow = lane & 15, lk = lane >> 4;
    bf16x8 af[2][4];
#pragma unroll
    for (int rt = 0; rt < 2; ++rt)
#pragma unroll
        for (int kk = 0; kk < 4; ++kk)
            af[rt][kk] = *(const bf16x8*)&xs[rt * 16 + lrow][kk * 32 + lk * 8];
    const unsigned short* wb0 = Wt + (size_t)t * HID * HID + (size_t)lrow * HID + lk * 8;
#pragma unroll
    for (int pp = 0; pp < 2; ++pp) {
        int ct = wv * 2 + pp;
        const unsigned short* wb = wb0 + (size_t)ct * 16 * HID;
        f32x4 a0 = {0.f, 0.f, 0.f, 0.f}, a1 = {0.f, 0.f, 0.f, 0.f};
#pragma unroll
        for (int kk = 0; kk < 4; ++kk) {
            bf16x8 bfr = *(const bf16x8*)(wb + kk * 32);
            a0 = __builtin_amdgcn_mfma_f32_16x16x32_bf16(af[0][kk], bfr, a0, 0, 0, 0);
            a1 = __builtin_amdgcn_mfma_f32_16x16x32_bf16(af[1][kk], bfr, a1, 0, 0, 0);
        }
        float bv = bias ? bias[ct * 16 + lrow] : 0.f;
#pragma unroll
        for (int q = 0; q < 4; ++q) {
            int r0 = lk * 4 + q;
            int n0 = nodes[r0], n1 = nodes[16 + r0];
            if (n0 >= 0) out[(size_t)n0 * HID + ct * 16 + lrow] = a0[q] + bv;
            if (n1 >= 0) out[(size_t)n1 * HID + ct * 16 + lrow] = a1[q] + bv;
        }
    }
}

// ---------- MFMA typed GEMM + SiLU + gated residual + LayerNorm (fused) ----------
__global__ __launch_bounds__(256) void gemm1_ln_mfma(
    const float* __restrict__ agg, const int* __restrict__ perm, const int* __restrict__ ntype,
    const unsigned short* __restrict__ Wt, const float* __restrict__ xin,
    const float* __restrict__ skip, const float* __restrict__ g, const float* __restrict__ b,
    float* __restrict__ xout) {
    __shared__ unsigned short xs[TILE][HID + 8];
    __shared__ int nodes[TILE];
    __shared__ float psum[TILE][4], psq[TILE][4];
    __shared__ float mu_s[TILE], rv_s[TILE];
    int tid = threadIdx.x;
    if (tid < TILE) nodes[tid] = perm[blockIdx.x * TILE + tid];
    __syncthreads();
    if (nodes[0] < 0) return;
    int t = ntype[nodes[0]];
#pragma unroll
    for (int c = 0; c < 4; ++c) {
        int v = tid + c * 256;
        int ns = v >> 5, ii = (v & 31) * 4;
        int node = nodes[ns];
        float4 val = (node >= 0) ? *(const float4*)(agg + (size_t)node * HID + ii)
                                 : make_float4(0.f, 0.f, 0.f, 0.f);
        uint2 pk;
        pk.x = (unsigned)f2bf(val.x) | ((unsigned)f2bf(val.y) << 16);
        pk.y = (unsigned)f2bf(val.z) | ((unsigned)f2bf(val.w) << 16);
        *(uint2*)&xs[ns][ii] = pk;
    }
    __syncthreads();
    int wv = tid >> 6, lane = tid & 63;
    int lrow = lane & 15, lk = lane >> 4;
    bf16x8 af[2][4];
#pragma unroll
    for (int rt = 0; rt < 2; ++rt)
#pragma unroll
        for (int kk = 0; kk < 4; ++kk)
            af[rt][kk] = *(const bf16x8*)&xs[rt * 16 + lrow][kk * 32 + lk * 8];
    const unsigned short* wb0 = Wt + (size_t)t * HID * HID + (size_t)lrow * HID + lk * 8;
    float al = 1.f / (1.f + expf(-skip[t]));
    float om = 1.f - al;
    float ov[2][2][4];   // [pp][half][q]
#pragma unroll
    for (int pp = 0; pp < 2; ++pp) {
        int ct = wv * 2 + pp;
        const unsigned short* wb = wb0 + (size_t)ct * 16 * HID;
        f32x4 a0 = {0.f, 0.f, 0.f, 0.f}, a1 = {0.f, 0.f, 0.f, 0.f};
#pragma unroll
        for (int kk = 0; kk < 4; ++kk) {
            bf16x8 bfr = *(const bf16x8*)(wb + kk * 32);
            a0 = __builtin_amdgcn_mfma_f32_16x16x32_bf16(af[0][kk], bfr, a0, 0, 0, 0);
            a1 = __builtin_amdgcn_mfma_f32_16x16x32_bf16(af[1][kk], bfr, a1, 0, 0, 0);
        }
        int col = ct * 16 + lrow;
#pragma unroll
        for (int q = 0; q < 4; ++q) {
            int n0 = nodes[lk * 4 + q], n1 = nodes[16 + lk * 4 + q];
            float s0 = a0[q] / (1.f + expf(-a0[q]));
            float s1 = a1[q] / (1.f + expf(-a1[q]));
            float x0 = (n0 >= 0) ? xin[(size_t)n0 * HID + col] : 0.f;
            float x1 = (n1 >= 0) ? xin[(size_t)n1 * HID + col] : 0.f;
            ov[pp][0][q] = s0 * al + x0 * om;
            ov[pp][1][q] = s1 * al + x1 * om;
        }
    }
    // per-node sums over the 128 cols: reduce over lrow (16 lanes), then over waves via LDS
#pragma unroll
    for (int half = 0; half < 2; ++half)
#pragma unroll
        for (int q = 0; q < 4; ++q) {
            float s = ov[0][half][q] + ov[1][half][q];
            float s2 = ov[0][half][q] * ov[0][half][q] + ov[1][half][q] * ov[1][half][q];
            s += __shfl_xor(s, 1); s += __shfl_xor(s, 2);
            s += __shfl_xor(s, 4); s += __shfl_xor(s, 8);
            s2 += __shfl_xor(s2, 1); s2 += __shfl_xor(s2, 2);
            s2 += __shfl_xor(s2, 4); s2 += __shfl_xor(s2, 8);
            if (lrow == 0) {
                int nd = half * 16 + lk * 4 + q;
                psum[nd][wv] = s;
                psq[nd][wv] = s2;
            }
        }
    __syncthreads();
    if (tid < TILE) {
        float s = psum[tid][0] + psum[tid][1] + psum[tid][2] + psum[tid][3];
        float s2 = psq[tid][0] + psq[tid][1] + psq[tid][2] + psq[tid][3];
        float mu = s * (1.f / HID);
        float var = s2 * (1.f / HID) - mu * mu;
        mu_s[tid] = mu;
        rv_s[tid] = rsqrtf(fmaxf(var, 0.f) + 1e-5f);
    }
    __syncthreads();
#pragma unroll
    for (int pp = 0; pp < 2; ++pp) {
        int col = (wv * 2 + pp) * 16 + lrow;
        float gg = g[col], bb = b[col];
#pragma unroll
        for (int q = 0; q < 4; ++q) {
            int i0 = lk * 4 + q, i1 = 16 + lk * 4 + q;
            int n0 = nodes[i0], n1 = nodes[i1];
            if (n0 >= 0) xout[(size_t)n0 * HID + col] = (ov[pp][0][q] - mu_s[i0]) * rv_s[i0] * gg + bb;
            if (n1 >= 0) xout[(size_t)n1 * HID + col] = (ov[pp][1][q] - mu_s[i1]) * rv_s[i1] * gg + bb;
        }
    }
}

// ---------- edge transform: per 16-edge tile (uniform r), MFMA kw/mg + score ----------
__global__ __launch_bounds__(256) void transform_kernel(
    const unsigned short* __restrict__ Kb, const unsigned short* __restrict__ Vb,
    const unsigned short* __restrict__ Qb,
    const int* __restrict__ rsd, const int* __restrict__ rpos, const int* __restrict__ rbase,
    const unsigned short* __restrict__ WattT, const unsigned short* __restrict__ WmsgT,
    float* __restrict__ scores, unsigned short* __restrict__ mg) {
    int tw = (blockIdx.x * 256 + threadIdx.x) >> 6;    // tile id, grid exact
    int lane = threadIdx.x & 63;
    int ecol = lane & 15, lk = lane >> 4;
    int entry = tw * 16 + ecol;
    int sd = rsd[entry];
    int s = sd & 0xFFFF, dd = (sd >> 16) & 0xFFFF;
    int p = rpos[entry];
    int base16 = tw * 16;
    int r = 0;
#pragma unroll
    for (int j = 1; j < NR; ++j) r = (base16 >= rbase[j]) ? j : r;

    const bf16x8 zz = {0, 0, 0, 0, 0, 0, 0, 0};
#pragma unroll
    for (int h = 0; h < NH; ++h) {
        bf16x8 bk = zz, bv = zz, aa = zz, am = zz;
        if (lk < 2) {
            bk = *(const bf16x8*)(Kb + (size_t)s * HID + h * HS + lk * 8);
            bv = *(const bf16x8*)(Vb + (size_t)s * HID + h * HS + lk * 8);
            int wo = ((h * NR + r) * 16 + ecol) * 16 + lk * 8;
            aa = *(const bf16x8*)(WattT + wo);
            am = *(const bf16x8*)(WmsgT + wo);
        }
        f32x4 ck = {0.f, 0.f, 0.f, 0.f}, cm = {0.f, 0.f, 0.f, 0.f};
        ck = __builtin_amdgcn_mfma_f32_16x16x32_bf16(aa, bk, ck, 0, 0, 0);
        cm = __builtin_amdgcn_mfma_f32_16x16x32_bf16(am, bv, cm, 0, 0, 0);
        // score: dot(kw, q) over o; lane holds o = lk*4+q for edge ecol
        uint2 qraw = *(const uint2*)(Qb + (size_t)dd * HID + h * HS + lk * 4);
        float q0 = __uint_as_float(qraw.x << 16);
        float q1 = __uint_as_float(qraw.x & 0xffff0000u);
        float q2 = __uint_as_float(qraw.y << 16);
        float q3 = __uint_as_float(qraw.y & 0xffff0000u);
        float xsc = ck[0] * q0 + ck[1] * q1 + ck[2] * q2 + ck[3] * q3;
        xsc += __shfl_xor(xsc, 16);
        xsc += __shfl_xor(xsc, 32);
        if (lk == 0) scores[p * NH + h] = xsc;
        uint2 pk2;
        pk2.x = (unsigned)f2bf(cm[0]) | ((unsigned)f2bf(cm[1]) << 16);
        pk2.y = (unsigned)f2bf(cm[2]) | ((unsigned)f2bf(cm[3]) << 16);
        *(uint2*)(mg + (size_t)p * HID + h * HS + lk * 4) = pk2;
    }
}

// ---------- edge softmax pass: wave per (dst,head), streams scores+mg ----------
__global__ __launch_bounds__(256) void edge_soft_kernel(
    const float* __restrict__ scores, const unsigned short* __restrict__ mg,
    const int* __restrict__ row_ptr, const int* __restrict__ deg, float* __restrict__ agg) {
    int u = blockIdx.x * 4 + (threadIdx.x >> 6);   // (d,h) unit, grid exact
    int lane = threadIdx.x & 63;
    int d = u >> 3, h = u & 7;
    int slot = lane >> 4, o = lane & 15;
    int beg = row_ptr[d], dg = deg[d];

    float m = -INFINITY, den = 0.f, acc = 0.f;
    for (int c = 0; c < dg; c += 4) {
        int idx = c + slot;
        bool valid = idx < dg;
        int p = beg + (valid ? idx : dg - 1);
        float a = scores[p * NH + h];
        float mgv = bf2f(mg[(size_t)p * HID + h * HS + o]);
        if (!valid) a = -INFINITY;
        float am = fmaxf(a, __shfl_xor(a, 16));
        am = fmaxf(am, __shfl_xor(am, 32));
        float mn = fmaxf(m, am);
        float scale = (m == -INFINITY) ? 0.f : expf(m - mn);
        float ex = expf(a - mn);
        float exs = ex + __shfl_xor(ex, 16);
        exs += __shfl_xor(exs, 32);
        den = den * scale + exs;
        acc = acc * scale + ex * mgv;
        m = mn;
    }
    acc += __shfl_xor(acc, 16);
    acc += __shfl_xor(acc, 32);
    if (slot == 0)
        agg[(size_t)d * HID + h * HS + o] = acc / (den + 1e-16f);
}

extern "C" void kernel_launch(void* const* d_in, const int* in_sizes, int n_in,
                              void* d_out, int out_size, void* d_ws, size_t ws_size,
                              hipStream_t stream) {
    const float* x     = (const float*)d_in[0];
    const int*   eidx  = (const int*)d_in[1];
    const int*   ntype = (const int*)d_in[2];
    const int*   etype = (const int*)d_in[3];
    const float* Wk    = (const float*)d_in[4];
    const float* Wq    = (const float*)d_in[5];
    const float* Wv    = (const float*)d_in[6];
    const float* Wa    = (const float*)d_in[7];
    const float* pri   = (const float*)d_in[8];
    const float* Watt  = (const float*)d_in[9];
    const float* Wmsg  = (const float*)d_in[10];
    const float* skip  = (const float*)d_in[11];
    const float* ln_g  = (const float*)d_in[12];
    const float* ln_b  = (const float*)d_in[13];
    const float* Wff   = (const float*)d_in[14];
    const float* bff   = (const float*)d_in[15];
    const int* src = eidx;
    const int* dst = eidx + N_EDGES;

    char* ws = (char*)d_ws;
    size_t szN = (size_t)N_NODES * HID * sizeof(float);        // 25.6 MB
    float* embA = (float*)(ws);                                // layer-0 out
    float* AGG  = (float*)(ws + szN);                          // edge_soft out
    char*  kvq  = ws + 2 * szN;
    unsigned short* Kbf = (unsigned short*)kvq;                          // 12.8 MB
    unsigned short* Vbf = (unsigned short*)(kvq + (size_t)N_NODES * HID * 2);
    unsigned short* Qbf = (unsigned short*)(kvq + 2 * (size_t)N_NODES * HID * 2);
    float* l1out = (float*)kvq;                                // aliases K+V (dead by then)
    char*  p    = kvq + 3 * (size_t)N_NODES * HID * 2;
    int* perm    = (int*)p;  p += (size_t)PERM_SZ * 4;
    int* cnt     = (int*)p;  p += TN * 4;
    int* cursor  = (int*)p;  p += TN * 4;
    int* row_ptr = (int*)p;  p += (size_t)N_NODES * 4;
    int* cnt_dst = (int*)p;  p += (size_t)N_NODES * 4;
    int* cur_dst = (int*)p;  p += (size_t)N_NODES * 4;
    int* bsum    = (int*)p;  p += 256 * 4;
    int* ecnt    = (int*)p;  p += NR * 4;
    int* rbase   = (int*)p;  p += (NR + 1) * 4;
    int* rcur    = (int*)p;  p += NR * 4;
    int* csr_sd  = (int*)p;  p += (size_t)N_EDGES * 4;
    int* csr_et  = (int*)p;  p += (size_t)N_EDGES * 4;
    int* rsd     = (int*)p;  p += (size_t)RL_CAP * 4;
    int* rpos    = (int*)p;  p += (size_t)RL_CAP * 4;
    size_t wmat = (size_t)HID * HID;
    unsigned short* WkT  = (unsigned short*)p;  p += 2 * TN * wmat * 2;
    unsigned short* WqT  = (unsigned short*)p;  p += 2 * TN * wmat * 2;
    unsigned short* WvT  = (unsigned short*)p;  p += 2 * TN * wmat * 2;
    unsigned short* WaT  = (unsigned short*)p;  p += 2 * TN * wmat * 2;
    unsigned short* WffT = (unsigned short*)p;  p += wmat * 2;
    unsigned short* WattT = (unsigned short*)p; p += 2 * 64 * 256 * 2;
    unsigned short* WmsgT = (unsigned short*)p; p += 2 * 64 * 256 * 2;
    p = (char*)(((size_t)p + 255) & ~(size_t)255);
    float* scores = (float*)p;          p += (size_t)(N_EDGES + 16) * NH * 4;   // 12.8 MB
    unsigned short* mg = (unsigned short*)p;  p += (size_t)(N_EDGES + 16) * HID * 2; // 102.4 MB

    // weight conversion (once per launch)
    wconv_kernel<<<2 * TN * 8, 256, 0, stream>>>(Wk, WkT);
    wconv_kernel<<<2 * TN * 8, 256, 0, stream>>>(Wq, WqT);
    wconv_kernel<<<2 * TN * 8, 256, 0, stream>>>(Wv, WvT);
    wconv_kernel<<<2 * TN * 8, 256, 0, stream>>>(Wa, WaT);
    wconv_kernel<<<8, 256, 0, stream>>>(Wff, WffT);
    wsmall_conv<<<128, 256, 0, stream>>>(Watt, pri, WattT);     // pri/4 baked in
    wsmall_conv<<<128, 256, 0, stream>>>(Wmsg, nullptr, WmsgT);

    // node type sort (once)
    hipMemsetAsync(cnt, 0, TN * 4, stream);
    hipMemsetAsync(perm, 0xFF, (size_t)PERM_SZ * 4, stream);
    hist_kernel<<<(N_NODES + 255) / 256, 256, 0, stream>>>(ntype, cnt);
    scan_kernel<<<1, 64, 0, stream>>>(cnt, cursor);
    scatter_kernel<<<(N_NODES + 255) / 256, 256, 0, stream>>>(ntype, cursor, perm);

    // edge CSR by dst, then CSR-ordered relation segments (once)
    hipMemsetAsync(cnt_dst, 0, (size_t)N_NODES * 4, stream);
    hipMemsetAsync(ecnt, 0, NR * 4, stream);
    hist_dst_kernel<<<(N_EDGES + 255) / 256, 256, 0, stream>>>(dst, cnt_dst);
    ehist_kernel<<<(N_EDGES + 255) / 256, 256, 0, stream>>>(etype, ecnt);
    scan_block_kernel<<<SCAN_BLKS, 256, 0, stream>>>(cnt_dst, row_ptr, bsum);
    scan_top_kernel<<<1, 256, 0, stream>>>(bsum);
    scan_add_kernel<<<SCAN_BLKS, 256, 0, stream>>>(row_ptr, bsum, cur_dst);
    csr_scatter_kernel<<<(N_EDGES + 255) / 256, 256, 0, stream>>>(src, dst, etype, cur_dst,
                                                                  csr_sd, csr_et);
    escan_kernel<<<1, 64, 0, stream>>>(ecnt, rbase, rcur);
    rinit_kernel<<<(RL_CAP + 255) / 256, 256, 0, stream>>>(rsd, rpos);
    rel_scatter_kernel<<<(N_EDGES + 255) / 256, 256, 0, stream>>>(csr_sd, csr_et, rcur,
                                                                  rsd, rpos);

    for (int l = 0; l < 2; ++l) {
        const float* xin = l ? embA : x;
        float* xout = l ? l1out : embA;
        const float* skip_l = skip + (size_t)l * TN;
        const float* g_l    = ln_g + (size_t)l * HID;
        const float* b_l    = ln_b + (size_t)l * HID;
        const unsigned short* WkT_l = WkT + (size_t)l * TN * wmat;
        const unsigned short* WqT_l = WqT + (size_t)l * TN * wmat;
        const unsigned short* WvT_l = WvT + (size_t)l * TN * wmat;
        const unsigned short* WaT_l = WaT + (size_t)l * TN * wmat;
        const unsigned short* WattT_l = WattT + (size_t)l * 64 * 256;
        const unsigned short* WmsgT_l = WmsgT + (size_t)l * 64 * 256;

        gemm3_mfma<<<MAXTILES, 256, 0, stream>>>(xin, perm, ntype, WkT_l, WqT_l, WvT_l,
                                                 Kbf, Qbf, Vbf);
        transform_kernel<<<RT_TILES / 4, 256, 0, stream>>>(Kbf, Vbf, Qbf, rsd, rpos, rbase,
                                                           WattT_l, WmsgT_l, scores, mg);
        edge_soft_kernel<<<N_NODES * NH / 4, 256, 0, stream>>>(scores, mg, row_ptr, cnt_dst,
                                                               AGG);
        // Wa typed GEMM + SiLU + gated residual + LayerNorm (fused)
        gemm1_ln_mfma<<<MAXTILES, 256, 0, stream>>>(AGG, perm, ntype, WaT_l, xin,
                                                    skip_l, g_l, b_l, xout);
    }
    // final FF: l1out @ Wff + bff -> d_out
    gemm1_mfma<<<(N_NODES + TILE - 1) / TILE, 256, 0, stream>>>(l1out, nullptr, ntype, WffT,
                                                                bff, (float*)d_out);
}

// Round 11
// 745.868 us; speedup vs baseline: 3.5757x; 1.0361x over previous
//
#include <hip/hip_runtime.h>
#include <hip/hip_bf16.h>
#include <math.h>

#define N_NODES 50000
#define N_EDGES 400000
#define HID 128
#define NH 8
#define HS 16
#define TN 8
#define NR 8
#define TILE 32
#define MAXTILES 1571
#define PERM_SZ (MAXTILES * TILE)
#define SCAN_BLKS ((N_NODES + 255) / 256)   // 196
#define RL_CAP 400128                        // E + 8*16 pad, multiple of 16
#define T_GRID 3280                          // >= max tiles per relation segment

typedef __attribute__((ext_vector_type(8))) short bf16x8;
typedef __attribute__((ext_vector_type(4))) float f32x4;

__device__ __forceinline__ unsigned short f2bf(float f) {
    __hip_bfloat16 h = __float2bfloat16(f);
    return *reinterpret_cast<unsigned short*>(&h);
}
__device__ __forceinline__ float bf2f(unsigned short u) {
    return __uint_as_float((unsigned)u << 16);
}

// ---------- node type sort (LDS-aggregated counting sort) ----------
__global__ void hist_kernel(const int* __restrict__ ntype, int* __restrict__ cnt) {
    __shared__ int l[TN];
    if (threadIdx.x < TN) l[threadIdx.x] = 0;
    __syncthreads();
    int i = blockIdx.x * 256 + threadIdx.x;
    if (i < N_NODES) atomicAdd(&l[ntype[i]], 1);
    __syncthreads();
    if (threadIdx.x < TN) atomicAdd(&cnt[threadIdx.x], l[threadIdx.x]);
}
__global__ void scan_kernel(const int* __restrict__ cnt, int* __restrict__ cursor) {
    if (threadIdx.x == 0 && blockIdx.x == 0) {
        int acc = 0;
        for (int t = 0; t < TN; ++t) {
            cursor[t] = acc;
            acc += ((cnt[t] + TILE - 1) / TILE) * TILE;
        }
    }
}
__global__ void scatter_kernel(const int* __restrict__ ntype, int* __restrict__ cursor,
                               int* __restrict__ perm) {
    __shared__ int lcnt[TN], lbase[TN];
    if (threadIdx.x < TN) lcnt[threadIdx.x] = 0;
    __syncthreads();
    int i = blockIdx.x * 256 + threadIdx.x;
    int t = 0, off = 0;
    if (i < N_NODES) {
        t = ntype[i];
        off = atomicAdd(&lcnt[t], 1);
    }
    __syncthreads();
    if (threadIdx.x < TN)
        lbase[threadIdx.x] = atomicAdd(&cursor[threadIdx.x], lcnt[threadIdx.x]);
    __syncthreads();
    if (i < N_NODES) perm[lbase[t] + off] = i;
}

// ---------- edge CSR build (sort by dst) ----------
__global__ void hist_dst_kernel(const int* __restrict__ dst, int* __restrict__ cnt) {
    int e = blockIdx.x * 256 + threadIdx.x;
    if (e < N_EDGES) atomicAdd(&cnt[dst[e]], 1);
}
__global__ void scan_block_kernel(const int* __restrict__ cnt, int* __restrict__ excl,
                                  int* __restrict__ bsum) {
    __shared__ int s[256];
    int tid = threadIdx.x;
    int i = blockIdx.x * 256 + tid;
    int v = (i < N_NODES) ? cnt[i] : 0;
    s[tid] = v;
    __syncthreads();
    for (int off = 1; off < 256; off <<= 1) {
        int t = (tid >= off) ? s[tid - off] : 0;
        __syncthreads();
        s[tid] += t;
        __syncthreads();
    }
    if (i < N_NODES) excl[i] = s[tid] - v;
    if (tid == 255) bsum[blockIdx.x] = s[255];
}
__global__ void scan_top_kernel(int* __restrict__ bsum) {
    __shared__ int s[256];
    int tid = threadIdx.x;
    int v = (tid < SCAN_BLKS) ? bsum[tid] : 0;
    s[tid] = v;
    __syncthreads();
    for (int off = 1; off < 256; off <<= 1) {
        int t = (tid >= off) ? s[tid - off] : 0;
        __syncthreads();
        s[tid] += t;
        __syncthreads();
    }
    if (tid < SCAN_BLKS) bsum[tid] = s[tid] - v;   // exclusive
}
__global__ void scan_add_kernel(int* __restrict__ excl, const int* __restrict__ bsum,
                                int* __restrict__ cursor) {
    int i = blockIdx.x * 256 + threadIdx.x;
    if (i < N_NODES) {
        int v = excl[i] + bsum[blockIdx.x];
        excl[i] = v;        // becomes row_ptr
        cursor[i] = v;
    }
}
// pass 1: place edges at CSR positions (by dst)
__global__ void csr_scatter_kernel(const int* __restrict__ src, const int* __restrict__ dst,
                                   const int* __restrict__ etype, int* __restrict__ cur_dst,
                                   int* __restrict__ csr_sd, int* __restrict__ csr_et) {
    int e = blockIdx.x * 256 + threadIdx.x;
    if (e < N_EDGES) {
        int p = atomicAdd(&cur_dst[dst[e]], 1);
        csr_sd[p] = src[e] | (dst[e] << 16);
        csr_et[p] = etype[e];
    }
}

// ---------- relation sort (CSR-ordered within segments) ----------
__global__ void ehist_kernel(const int* __restrict__ etype, int* __restrict__ ecnt) {
    __shared__ int l[NR];
    if (threadIdx.x < NR) l[threadIdx.x] = 0;
    __syncthreads();
    int e = blockIdx.x * 256 + threadIdx.x;
    if (e < N_EDGES) atomicAdd(&l[etype[e]], 1);
    __syncthreads();
    if (threadIdx.x < NR) atomicAdd(&ecnt[threadIdx.x], l[threadIdx.x]);
}
__global__ void escan_kernel(const int* __restrict__ ecnt, int* __restrict__ rbase,
                             int* __restrict__ rcur) {
    if (threadIdx.x == 0 && blockIdx.x == 0) {
        int acc = 0;
        for (int r = 0; r < NR; ++r) {
            rbase[r] = acc; rcur[r] = acc;
            acc += ((ecnt[r] + 15) / 16) * 16;
        }
        rbase[NR] = acc;
    }
}
__global__ void rinit_kernel(int* __restrict__ rsd, int* __restrict__ rpos) {
    int i = blockIdx.x * 256 + threadIdx.x;
    if (i < RL_CAP) { rsd[i] = 0; rpos[i] = N_EDGES; }   // sentinel -> scratch row E
}
// pass 2: walk CSR positions in order, append to relation segments
__global__ void rel_scatter_kernel(const int* __restrict__ csr_sd, const int* __restrict__ csr_et,
                                   int* __restrict__ rcur, int* __restrict__ rsd,
                                   int* __restrict__ rpos) {
    __shared__ int lcnt[NR], lbase[NR];
    if (threadIdx.x < NR) lcnt[threadIdx.x] = 0;
    __syncthreads();
    int p = blockIdx.x * 256 + threadIdx.x;
    int r = 0, off = 0;
    if (p < N_EDGES) {
        r = csr_et[p];
        off = atomicAdd(&lcnt[r], 1);
    }
    __syncthreads();
    if (threadIdx.x < NR) lbase[threadIdx.x] = atomicAdd(&rcur[threadIdx.x], lcnt[threadIdx.x]);
    __syncthreads();
    if (p < N_EDGES) {
        int rp = lbase[r] + off;
        rsd[rp] = csr_sd[p];
        rpos[rp] = p;
    }
}

// ---------- weight converts ----------
__global__ void wconv_kernel(const float* __restrict__ W, unsigned short* __restrict__ out) {
    int mat = blockIdx.x >> 3, seg = blockIdx.x & 7;
    const float* w = W + (size_t)mat * HID * HID;
    unsigned short* o = out + (size_t)mat * HID * HID;
#pragma unroll
    for (int c = 0; c < 8; ++c) {
        int idx = seg * 2048 + c * 256 + threadIdx.x;
        int i = idx >> 7, j = idx & 127;
        o[j * HID + i] = f2bf(w[idx]);
    }
}
__global__ void wsmall_conv(const float* __restrict__ W, const float* __restrict__ pri,
                            unsigned short* __restrict__ out) {
    int blk = blockIdx.x;                 // l*64 + h*8 + r
    int tid = threadIdx.x;                // 256 = 16x16
    int i = tid >> 4, o = tid & 15;
    float s = pri ? pri[blk] * 0.25f : 1.f;
    out[blk * 256 + o * 16 + i] = f2bf(W[blk * 256 + i * 16 + o] * s);
}

// ---------- MFMA typed GEMM: 32 nodes x 128 outs; K,Q,V all bf16 ----------
__global__ __launch_bounds__(256) void gemm3_mfma(
    const float* __restrict__ x, const int* __restrict__ perm, const int* __restrict__ ntype,
    const unsigned short* __restrict__ WkT, const unsigned short* __restrict__ WqT,
    const unsigned short* __restrict__ WvT,
    unsigned short* __restrict__ Kb, unsigned short* __restrict__ Qb,
    unsigned short* __restrict__ Vb) {
    __shared__ unsigned short xs[TILE][HID + 8];
    __shared__ int nodes[TILE];
    int tid = threadIdx.x;
    if (tid < TILE) nodes[tid] = perm[blockIdx.x * TILE + tid];
    __syncthreads();
    if (nodes[0] < 0) return;
    int t = ntype[nodes[0]];
#pragma unroll
    for (int c = 0; c < 4; ++c) {
        int v = tid + c * 256;
        int ns = v >> 5, ii = (v & 31) * 4;
        int node = nodes[ns];
        float4 val = (node >= 0) ? *(const float4*)(x + (size_t)node * HID + ii)
                                 : make_float4(0.f, 0.f, 0.f, 0.f);
        uint2 pk;
        pk.x = (unsigned)f2bf(val.x) | ((unsigned)f2bf(val.y) << 16);
        pk.y = (unsigned)f2bf(val.z) | ((unsigned)f2bf(val.w) << 16);
        *(uint2*)&xs[ns][ii] = pk;
    }
    __syncthreads();
    int wv = tid >> 6, lane = tid & 63;
    int lrow = lane & 15, lk = lane >> 4;
    bf16x8 af[2][4];
#pragma unroll
    for (int rt = 0; rt < 2; ++rt)
#pragma unroll
        for (int kk = 0; kk < 4; ++kk)
            af[rt][kk] = *(const bf16x8*)&xs[rt * 16 + lrow][kk * 32 + lk * 8];
    size_t woff = (size_t)t * HID * HID + (size_t)lrow * HID + lk * 8;
#pragma unroll
    for (int pp = 0; pp < 6; ++pp) {
        int p = wv * 6 + pp;
        int mat = p >> 3, ct = p & 7;
        const unsigned short* wb =
            (mat == 0 ? WkT : (mat == 1 ? WqT : WvT)) + woff + (size_t)ct * 16 * HID;
        unsigned short* ob = (mat == 0) ? Kb : (mat == 1 ? Qb : Vb);
        f32x4 a0 = {0.f, 0.f, 0.f, 0.f}, a1 = {0.f, 0.f, 0.f, 0.f};
#pragma unroll
        for (int kk = 0; kk < 4; ++kk) {
            bf16x8 bfr = *(const bf16x8*)(wb + kk * 32);
            a0 = __builtin_amdgcn_mfma_f32_16x16x32_bf16(af[0][kk], bfr, a0, 0, 0, 0);
            a1 = __builtin_amdgcn_mfma_f32_16x16x32_bf16(af[1][kk], bfr, a1, 0, 0, 0);
        }
        int col = ct * 16 + lrow;
#pragma unroll
        for (int q = 0; q < 4; ++q) {
            int r0 = lk * 4 + q;
            int n0 = nodes[r0], n1 = nodes[16 + r0];
            if (n0 >= 0) ob[(size_t)n0 * HID + col] = f2bf(a0[q]);
            if (n1 >= 0) ob[(size_t)n1 * HID + col] = f2bf(a1[q]);
        }
    }
}

// ---------- MFMA GEMM (plain, fp32 in, fp32 out, +bias) for final FF ----------
__global__ __launch_bounds__(256) void gemm1_mfma(
    const float* __restrict__ x, const int* __restrict__ perm, const int* __restrict__ ntype,
    const unsigned short* __restrict__ Wt, const float* __restrict__ bias,
    float* __restrict__ out) {
    __shared__ unsigned short xs[TILE][HID + 8];
    __shared__ int nodes[TILE];
    int tid = threadIdx.x;
    if (tid < TILE) {
        int n;
        if (perm) n = perm[blockIdx.x * TILE + tid];
        else { n = blockIdx.x * TILE + tid; if (n >= N_NODES) n = -1; }
        nodes[tid] = n;
    }
    __syncthreads();
    if (nodes[0] < 0) return;
    int t = perm ? ntype[nodes[0]] : 0;
#pragma unroll
    for (int c = 0; c < 4; ++c) {
        int v = tid + c * 256;
        int ns = v >> 5, ii = (v & 31) * 4;
        int node = nodes[ns];
        float4 val = (node >= 0) ? *(const float4*)(x + (size_t)node * HID + ii)
                                 : make_float4(0.f, 0.f, 0.f, 0.f);
        uint2 pk;
        pk.x = (unsigned)f2bf(val.x) | ((unsigned)f2bf(val.y) << 16);
        pk.y = (unsigned)f2bf(val.z) | ((unsigned)f2bf(val.w) << 16);
        *(uint2*)&xs[ns][ii] = pk;
    }
    __syncthreads();
    int wv = tid >> 6, lane = tid & 63;
    int lrow = lane & 15, lk = lane >> 4;
    bf16x8 af[2][4];
#pragma unroll
    for (int rt = 0; rt < 2; ++rt)
#pragma unroll
        for (int kk = 0; kk < 4; ++kk)
            af[rt][kk] = *(const bf16x8*)&xs[rt * 16 + lrow][kk * 32 + lk * 8];
    const unsigned short* wb0 = Wt + (size_t)t * HID * HID + (size_t)lrow * HID + lk * 8;
#pragma unroll
    for (int pp = 0; pp < 2; ++pp) {
        int ct = wv * 2 + pp;
        const unsigned short* wb = wb0 + (size_t)ct * 16 * HID;
        f32x4 a0 = {0.f, 0.f, 0.f, 0.f}, a1 = {0.f, 0.f, 0.f, 0.f};
#pragma unroll
        for (int kk = 0; kk < 4; ++kk) {
            bf16x8 bfr = *(const bf16x8*)(wb + kk * 32);
            a0 = __builtin_amdgcn_mfma_f32_16x16x32_bf16(af[0][kk], bfr, a0, 0, 0, 0);
            a1 = __builtin_amdgcn_mfma_f32_16x16x32_bf16(af[1][kk], bfr, a1, 0, 0, 0);
        }
        float bv = bias ? bias[ct * 16 + lrow] : 0.f;
#pragma unroll
        for (int q = 0; q < 4; ++q) {
            int r0 = lk * 4 + q;
            int n0 = nodes[r0], n1 = nodes[16 + r0];
            if (n0 >= 0) out[(size_t)n0 * HID + ct * 16 + lrow] = a0[q] + bv;
            if (n1 >= 0) out[(size_t)n1 * HID + ct * 16 + lrow] = a1[q] + bv;
        }
    }
}

// ---------- MFMA typed GEMM (bf16 agg in) + SiLU + gated residual + LayerNorm ----------
__global__ __launch_bounds__(256) void gemm1_ln_mfma(
    const unsigned short* __restrict__ aggb, const int* __restrict__ perm,
    const int* __restrict__ ntype, const unsigned short* __restrict__ Wt,
    const float* __restrict__ xin, const float* __restrict__ skip,
    const float* __restrict__ g, const float* __restrict__ b, float* __restrict__ xout) {
    __shared__ unsigned short xs[TILE][HID + 8];
    __shared__ int nodes[TILE];
    __shared__ float psum[TILE][4], psq[TILE][4];
    __shared__ float mu_s[TILE], rv_s[TILE];
    int tid = threadIdx.x;
    if (tid < TILE) nodes[tid] = perm[blockIdx.x * TILE + tid];
    __syncthreads();
    if (nodes[0] < 0) return;
    int t = ntype[nodes[0]];
#pragma unroll
    for (int c = 0; c < 4; ++c) {
        int v = tid + c * 256;
        int ns = v >> 5, ii = (v & 31) * 4;
        int node = nodes[ns];
        uint2 pk = make_uint2(0u, 0u);
        if (node >= 0) pk = *(const uint2*)(aggb + (size_t)node * HID + ii);
        *(uint2*)&xs[ns][ii] = pk;
    }
    __syncthreads();
    int wv = tid >> 6, lane = tid & 63;
    int lrow = lane & 15, lk = lane >> 4;
    bf16x8 af[2][4];
#pragma unroll
    for (int rt = 0; rt < 2; ++rt)
#pragma unroll
        for (int kk = 0; kk < 4; ++kk)
            af[rt][kk] = *(const bf16x8*)&xs[rt * 16 + lrow][kk * 32 + lk * 8];
    const unsigned short* wb0 = Wt + (size_t)t * HID * HID + (size_t)lrow * HID + lk * 8;
    float al = 1.f / (1.f + expf(-skip[t]));
    float om = 1.f - al;
    float ov[2][2][4];   // [pp][half][q]
#pragma unroll
    for (int pp = 0; pp < 2; ++pp) {
        int ct = wv * 2 + pp;
        const unsigned short* wb = wb0 + (size_t)ct * 16 * HID;
        f32x4 a0 = {0.f, 0.f, 0.f, 0.f}, a1 = {0.f, 0.f, 0.f, 0.f};
#pragma unroll
        for (int kk = 0; kk < 4; ++kk) {
            bf16x8 bfr = *(const bf16x8*)(wb + kk * 32);
            a0 = __builtin_amdgcn_mfma_f32_16x16x32_bf16(af[0][kk], bfr, a0, 0, 0, 0);
            a1 = __builtin_amdgcn_mfma_f32_16x16x32_bf16(af[1][kk], bfr, a1, 0, 0, 0);
        }
        int col = ct * 16 + lrow;
#pragma unroll
        for (int q = 0; q < 4; ++q) {
            int n0 = nodes[lk * 4 + q], n1 = nodes[16 + lk * 4 + q];
            float s0 = a0[q] / (1.f + expf(-a0[q]));
            float s1 = a1[q] / (1.f + expf(-a1[q]));
            float x0 = (n0 >= 0) ? xin[(size_t)n0 * HID + col] : 0.f;
            float x1 = (n1 >= 0) ? xin[(size_t)n1 * HID + col] : 0.f;
            ov[pp][0][q] = s0 * al + x0 * om;
            ov[pp][1][q] = s1 * al + x1 * om;
        }
    }
#pragma unroll
    for (int half = 0; half < 2; ++half)
#pragma unroll
        for (int q = 0; q < 4; ++q) {
            float s = ov[0][half][q] + ov[1][half][q];
            float s2 = ov[0][half][q] * ov[0][half][q] + ov[1][half][q] * ov[1][half][q];
            s += __shfl_xor(s, 1); s += __shfl_xor(s, 2);
            s += __shfl_xor(s, 4); s += __shfl_xor(s, 8);
            s2 += __shfl_xor(s2, 1); s2 += __shfl_xor(s2, 2);
            s2 += __shfl_xor(s2, 4); s2 += __shfl_xor(s2, 8);
            if (lrow == 0) {
                int nd = half * 16 + lk * 4 + q;
                psum[nd][wv] = s;
                psq[nd][wv] = s2;
            }
        }
    __syncthreads();
    if (tid < TILE) {
        float s = psum[tid][0] + psum[tid][1] + psum[tid][2] + psum[tid][3];
        float s2 = psq[tid][0] + psq[tid][1] + psq[tid][2] + psq[tid][3];
        float mu = s * (1.f / HID);
        float var = s2 * (1.f / HID) - mu * mu;
        mu_s[tid] = mu;
        rv_s[tid] = rsqrtf(fmaxf(var, 0.f) + 1e-5f);
    }
    __syncthreads();
#pragma unroll
    for (int pp = 0; pp < 2; ++pp) {
        int col = (wv * 2 + pp) * 16 + lrow;
        float gg = g[col], bb = b[col];
#pragma unroll
        for (int q = 0; q < 4; ++q) {
            int i0 = lk * 4 + q, i1 = 16 + lk * 4 + q;
            int n0 = nodes[i0], n1 = nodes[i1];
            if (n0 >= 0) xout[(size_t)n0 * HID + col] = (ov[pp][0][q] - mu_s[i0]) * rv_s[i0] * gg + bb;
            if (n1 >= 0) xout[(size_t)n1 * HID + col] = (ov[pp][1][q] - mu_s[i1]) * rv_s[i1] * gg + bb;
        }
    }
}

// ---------- edge transform: block j = j-th 16-edge tile of ALL 8 relations ----------
// 512 threads, wave w = relation w. All writes of a ~128-position CSR window come
// from one block (one XCD) -> full-line write combining for scores/mg.
__global__ __launch_bounds__(512) void transform_kernel(
    const unsigned short* __restrict__ Kb, const unsigned short* __restrict__ Vb,
    const unsigned short* __restrict__ Qb,
    const int* __restrict__ rsd, const int* __restrict__ rpos, const int* __restrict__ rbase,
    const unsigned short* __restrict__ WattT, const unsigned short* __restrict__ WmsgT,
    float* __restrict__ scores, unsigned short* __restrict__ mg) {
    int r = threadIdx.x >> 6;                      // wave = relation
    int lane = threadIdx.x & 63;
    int ecol = lane & 15, lk = lane >> 4;
    int tbeg = rbase[r] + blockIdx.x * 16;
    if (tbeg >= rbase[r + 1]) return;              // past this relation's segment
    int entry = tbeg + ecol;
    int sd = rsd[entry];
    int s = sd & 0xFFFF, dd = (sd >> 16) & 0xFFFF;
    int p = rpos[entry];

    const bf16x8 zz = {0, 0, 0, 0, 0, 0, 0, 0};
#pragma unroll
    for (int h = 0; h < NH; ++h) {
        bf16x8 bk = zz, bv = zz, aa = zz, am = zz;
        if (lk < 2) {
            bk = *(const bf16x8*)(Kb + (size_t)s * HID + h * HS + lk * 8);
            bv = *(const bf16x8*)(Vb + (size_t)s * HID + h * HS + lk * 8);
            int wo = ((h * NR + r) * 16 + ecol) * 16 + lk * 8;
            aa = *(const bf16x8*)(WattT + wo);
            am = *(const bf16x8*)(WmsgT + wo);
        }
        f32x4 ck = {0.f, 0.f, 0.f, 0.f}, cm = {0.f, 0.f, 0.f, 0.f};
        ck = __builtin_amdgcn_mfma_f32_16x16x32_bf16(aa, bk, ck, 0, 0, 0);
        cm = __builtin_amdgcn_mfma_f32_16x16x32_bf16(am, bv, cm, 0, 0, 0);
        uint2 qraw = *(const uint2*)(Qb + (size_t)dd * HID + h * HS + lk * 4);
        float q0 = __uint_as_float(qraw.x << 16);
        float q1 = __uint_as_float(qraw.x & 0xffff0000u);
        float q2 = __uint_as_float(qraw.y << 16);
        float q3 = __uint_as_float(qraw.y & 0xffff0000u);
        float xsc = ck[0] * q0 + ck[1] * q1 + ck[2] * q2 + ck[3] * q3;
        xsc += __shfl_xor(xsc, 16);
        xsc += __shfl_xor(xsc, 32);
        if (lk == 0) scores[p * NH + h] = xsc;
        uint2 pk2;
        pk2.x = (unsigned)f2bf(cm[0]) | ((unsigned)f2bf(cm[1]) << 16);
        pk2.y = (unsigned)f2bf(cm[2]) | ((unsigned)f2bf(cm[3]) << 16);
        *(uint2*)(mg + (size_t)p * HID + h * HS + lk * 4) = pk2;
    }
}

// ---------- edge softmax pass: wave per (dst,head), streams scores+mg; bf16 agg out ----------
__global__ __launch_bounds__(256) void edge_soft_kernel(
    const float* __restrict__ scores, const unsigned short* __restrict__ mg,
    const int* __restrict__ row_ptr, const int* __restrict__ deg,
    unsigned short* __restrict__ aggb) {
    int u = blockIdx.x * 4 + (threadIdx.x >> 6);   // (d,h) unit, grid exact
    int lane = threadIdx.x & 63;
    int d = u >> 3, h = u & 7;
    int slot = lane >> 4, o = lane & 15;
    int beg = row_ptr[d], dg = deg[d];

    float m = -INFINITY, den = 0.f, acc = 0.f;
    for (int c = 0; c < dg; c += 4) {
        int idx = c + slot;
        bool valid = idx < dg;
        int p = beg + (valid ? idx : dg - 1);
        float a = scores[p * NH + h];
        float mgv = bf2f(mg[(size_t)p * HID + h * HS + o]);
        if (!valid) a = -INFINITY;
        float am = fmaxf(a, __shfl_xor(a, 16));
        am = fmaxf(am, __shfl_xor(am, 32));
        float mn = fmaxf(m, am);
        float scale = (m == -INFINITY) ? 0.f : expf(m - mn);
        float ex = expf(a - mn);
        float exs = ex + __shfl_xor(ex, 16);
        exs += __shfl_xor(exs, 32);
        den = den * scale + exs;
        acc = acc * scale + ex * mgv;
        m = mn;
    }
    acc += __shfl_xor(acc, 16);
    acc += __shfl_xor(acc, 32);
    if (slot == 0)
        aggb[(size_t)d * HID + h * HS + o] = f2bf(acc / (den + 1e-16f));
}

extern "C" void kernel_launch(void* const* d_in, const int* in_sizes, int n_in,
                              void* d_out, int out_size, void* d_ws, size_t ws_size,
                              hipStream_t stream) {
    const float* x     = (const float*)d_in[0];
    const int*   eidx  = (const int*)d_in[1];
    const int*   ntype = (const int*)d_in[2];
    const int*   etype = (const int*)d_in[3];
    const float* Wk    = (const float*)d_in[4];
    const float* Wq    = (const float*)d_in[5];
    const float* Wv    = (const float*)d_in[6];
    const float* Wa    = (const float*)d_in[7];
    const float* pri   = (const float*)d_in[8];
    const float* Watt  = (const float*)d_in[9];
    const float* Wmsg  = (const float*)d_in[10];
    const float* skip  = (const float*)d_in[11];
    const float* ln_g  = (const float*)d_in[12];
    const float* ln_b  = (const float*)d_in[13];
    const float* Wff   = (const float*)d_in[14];
    const float* bff   = (const float*)d_in[15];
    const int* src = eidx;
    const int* dst = eidx + N_EDGES;

    char* ws = (char*)d_ws;
    size_t szN = (size_t)N_NODES * HID * sizeof(float);        // 25.6 MB
    float* embA = (float*)(ws);                                // layer-0 out
    unsigned short* AGGb = (unsigned short*)(ws + szN);        // bf16 agg (12.8 MB)
    char*  kvq  = ws + 2 * szN;
    unsigned short* Kbf = (unsigned short*)kvq;                // 12.8 MB each
    unsigned short* Vbf = (unsigned short*)(kvq + (size_t)N_NODES * HID * 2);
    unsigned short* Qbf = (unsigned short*)(kvq + 2 * (size_t)N_NODES * HID * 2);
    float* l1out = (float*)kvq;                                // aliases K+V (dead by then)
    char*  p    = kvq + 3 * (size_t)N_NODES * HID * 2;
    int* perm    = (int*)p;  p += (size_t)PERM_SZ * 4;
    int* cnt     = (int*)p;  p += TN * 4;
    int* cursor  = (int*)p;  p += TN * 4;
    int* row_ptr = (int*)p;  p += (size_t)N_NODES * 4;
    int* cnt_dst = (int*)p;  p += (size_t)N_NODES * 4;
    int* cur_dst = (int*)p;  p += (size_t)N_NODES * 4;
    int* bsum    = (int*)p;  p += 256 * 4;
    int* ecnt    = (int*)p;  p += NR * 4;
    int* rbase   = (int*)p;  p += (NR + 1) * 4;
    int* rcur    = (int*)p;  p += NR * 4;
    int* csr_sd  = (int*)p;  p += (size_t)N_EDGES * 4;
    int* csr_et  = (int*)p;  p += (size_t)N_EDGES * 4;
    int* rsd     = (int*)p;  p += (size_t)RL_CAP * 4;
    int* rpos    = (int*)p;  p += (size_t)RL_CAP * 4;
    size_t wmat = (size_t)HID * HID;
    unsigned short* WkT  = (unsigned short*)p;  p += 2 * TN * wmat * 2;
    unsigned short* WqT  = (unsigned short*)p;  p += 2 * TN * wmat * 2;
    unsigned short* WvT  = (unsigned short*)p;  p += 2 * TN * wmat * 2;
    unsigned short* WaT  = (unsigned short*)p;  p += 2 * TN * wmat * 2;
    unsigned short* WffT = (unsigned short*)p;  p += wmat * 2;
    unsigned short* WattT = (unsigned short*)p; p += 2 * 64 * 256 * 2;
    unsigned short* WmsgT = (unsigned short*)p; p += 2 * 64 * 256 * 2;
    p = (char*)(((size_t)p + 255) & ~(size_t)255);
    float* scores = (float*)p;          p += (size_t)(N_EDGES + 16) * NH * 4;   // 12.8 MB
    unsigned short* mg = (unsigned short*)p;  p += (size_t)(N_EDGES + 16) * HID * 2; // 102.4 MB

    // weight conversion (once per launch)
    wconv_kernel<<<2 * TN * 8, 256, 0, stream>>>(Wk, WkT);
    wconv_kernel<<<2 * TN * 8, 256, 0, stream>>>(Wq, WqT);
    wconv_kernel<<<2 * TN * 8, 256, 0, stream>>>(Wv, WvT);
    wconv_kernel<<<2 * TN * 8, 256, 0, stream>>>(Wa, WaT);
    wconv_kernel<<<8, 256, 0, stream>>>(Wff, WffT);
    wsmall_conv<<<128, 256, 0, stream>>>(Watt, pri, WattT);     // pri/4 baked in
    wsmall_conv<<<128, 256, 0, stream>>>(Wmsg, nullptr, WmsgT);

    // node type sort (once)
    hipMemsetAsync(cnt, 0, TN * 4, stream);
    hipMemsetAsync(perm, 0xFF, (size_t)PERM_SZ * 4, stream);
    hist_kernel<<<(N_NODES + 255) / 256, 256, 0, stream>>>(ntype, cnt);
    scan_kernel<<<1, 64, 0, stream>>>(cnt, cursor);
    scatter_kernel<<<(N_NODES + 255) / 256, 256, 0, stream>>>(ntype, cursor, perm);

    // edge CSR by dst, then CSR-ordered relation segments (once)
    hipMemsetAsync(cnt_dst, 0, (size_t)N_NODES * 4, stream);
    hipMemsetAsync(ecnt, 0, NR * 4, stream);
    hist_dst_kernel<<<(N_EDGES + 255) / 256, 256, 0, stream>>>(dst, cnt_dst);
    ehist_kernel<<<(N_EDGES + 255) / 256, 256, 0, stream>>>(etype, ecnt);
    scan_block_kernel<<<SCAN_BLKS, 256, 0, stream>>>(cnt_dst, row_ptr, bsum);
    scan_top_kernel<<<1, 256, 0, stream>>>(bsum);
    scan_add_kernel<<<SCAN_BLKS, 256, 0, stream>>>(row_ptr, bsum, cur_dst);
    csr_scatter_kernel<<<(N_EDGES + 255) / 256, 256, 0, stream>>>(src, dst, etype, cur_dst,
                                                                  csr_sd, csr_et);
    escan_kernel<<<1, 64, 0, stream>>>(ecnt, rbase, rcur);
    rinit_kernel<<<(RL_CAP + 255) / 256, 256, 0, stream>>>(rsd, rpos);
    rel_scatter_kernel<<<(N_EDGES + 255) / 256, 256, 0, stream>>>(csr_sd, csr_et, rcur,
                                                                  rsd, rpos);

    for (int l = 0; l < 2; ++l) {
        const float* xin = l ? embA : x;
        float* xout = l ? l1out : embA;
        const float* skip_l = skip + (size_t)l * TN;
        const float* g_l    = ln_g + (size_t)l * HID;
        const float* b_l    = ln_b + (size_t)l * HID;
        const unsigned short* WkT_l = WkT + (size_t)l * TN * wmat;
        const unsigned short* WqT_l = WqT + (size_t)l * TN * wmat;
        const unsigned short* WvT_l = WvT + (size_t)l * TN * wmat;
        const unsigned short* WaT_l = WaT + (size_t)l * TN * wmat;
        const unsigned short* WattT_l = WattT + (size_t)l * 64 * 256;
        const unsigned short* WmsgT_l = WmsgT + (size_t)l * 64 * 256;

        gemm3_mfma<<<MAXTILES, 256, 0, stream>>>(xin, perm, ntype, WkT_l, WqT_l, WvT_l,
                                                 Kbf, Qbf, Vbf);
        transform_kernel<<<T_GRID, 512, 0, stream>>>(Kbf, Vbf, Qbf, rsd, rpos, rbase,
                                                     WattT_l, WmsgT_l, scores, mg);
        edge_soft_kernel<<<N_NODES * NH / 4, 256, 0, stream>>>(scores, mg, row_ptr, cnt_dst,
                                                               AGGb);
        // Wa typed GEMM + SiLU + gated residual + LayerNorm (fused, bf16 agg in)
        gemm1_ln_mfma<<<MAXTILES, 256, 0, stream>>>(AGGb, perm, ntype, WaT_l, xin,
                                                    skip_l, g_l, b_l, xout);
    }
    // final FF: l1out @ Wff + bff -> d_out
    gemm1_mfma<<<(N_NODES + TILE - 1) / TILE, 256, 0, stream>>>(l1out, nullptr, ntype, WffT,
                                                                bff, (float*)d_out);
}

// Round 12
// 656.081 us; speedup vs baseline: 4.0650x; 1.1369x over previous
//
#include <hip/hip_runtime.h>
#include <hip/hip_bf16.h>
#include <math.h>

#define N_NODES 50000
#define N_EDGES 400000
#define HID 128
#define NH 8
#define HS 16
#define TN 8
#define NR 8
#define TILE 32
#define MAXTILES 1571
#define PERM_SZ (MAXTILES * TILE)
#define SCAN_BLKS ((N_NODES + 255) / 256)   // 196
#define RL_CAP 400128                        // E + 8*16 pad, multiple of 16
#define T_GRID 3280                          // >= max tiles per relation segment

typedef __attribute__((ext_vector_type(8))) short bf16x8;
typedef __attribute__((ext_vector_type(4))) float f32x4;

__device__ __forceinline__ unsigned short f2bf(float f) {
    __hip_bfloat16 h = __float2bfloat16(f);
    return *reinterpret_cast<unsigned short*>(&h);
}
__device__ __forceinline__ float bf2f(unsigned short u) {
    return __uint_as_float((unsigned)u << 16);
}

// ---------- node type sort (LDS-aggregated counting sort) ----------
__global__ void hist_kernel(const int* __restrict__ ntype, int* __restrict__ cnt) {
    __shared__ int l[TN];
    if (threadIdx.x < TN) l[threadIdx.x] = 0;
    __syncthreads();
    int i = blockIdx.x * 256 + threadIdx.x;
    if (i < N_NODES) atomicAdd(&l[ntype[i]], 1);
    __syncthreads();
    if (threadIdx.x < TN) atomicAdd(&cnt[threadIdx.x], l[threadIdx.x]);
}
__global__ void scan_kernel(const int* __restrict__ cnt, int* __restrict__ cursor) {
    if (threadIdx.x == 0 && blockIdx.x == 0) {
        int acc = 0;
        for (int t = 0; t < TN; ++t) {
            cursor[t] = acc;
            acc += ((cnt[t] + TILE - 1) / TILE) * TILE;
        }
    }
}
__global__ void scatter_kernel(const int* __restrict__ ntype, int* __restrict__ cursor,
                               int* __restrict__ perm) {
    __shared__ int lcnt[TN], lbase[TN];
    if (threadIdx.x < TN) lcnt[threadIdx.x] = 0;
    __syncthreads();
    int i = blockIdx.x * 256 + threadIdx.x;
    int t = 0, off = 0;
    if (i < N_NODES) {
        t = ntype[i];
        off = atomicAdd(&lcnt[t], 1);
    }
    __syncthreads();
    if (threadIdx.x < TN)
        lbase[threadIdx.x] = atomicAdd(&cursor[threadIdx.x], lcnt[threadIdx.x]);
    __syncthreads();
    if (i < N_NODES) perm[lbase[t] + off] = i;
}

// ---------- edge CSR build (sort by dst) ----------
__global__ void hist_dst_kernel(const int* __restrict__ dst, int* __restrict__ cnt) {
    int e = blockIdx.x * 256 + threadIdx.x;
    if (e < N_EDGES) atomicAdd(&cnt[dst[e]], 1);
}
__global__ void scan_block_kernel(const int* __restrict__ cnt, int* __restrict__ excl,
                                  int* __restrict__ bsum) {
    __shared__ int s[256];
    int tid = threadIdx.x;
    int i = blockIdx.x * 256 + tid;
    int v = (i < N_NODES) ? cnt[i] : 0;
    s[tid] = v;
    __syncthreads();
    for (int off = 1; off < 256; off <<= 1) {
        int t = (tid >= off) ? s[tid - off] : 0;
        __syncthreads();
        s[tid] += t;
        __syncthreads();
    }
    if (i < N_NODES) excl[i] = s[tid] - v;
    if (tid == 255) bsum[blockIdx.x] = s[255];
}
__global__ void scan_top_kernel(int* __restrict__ bsum) {
    __shared__ int s[256];
    int tid = threadIdx.x;
    int v = (tid < SCAN_BLKS) ? bsum[tid] : 0;
    s[tid] = v;
    __syncthreads();
    for (int off = 1; off < 256; off <<= 1) {
        int t = (tid >= off) ? s[tid - off] : 0;
        __syncthreads();
        s[tid] += t;
        __syncthreads();
    }
    if (tid < SCAN_BLKS) bsum[tid] = s[tid] - v;   // exclusive
}
__global__ void scan_add_kernel(int* __restrict__ excl, const int* __restrict__ bsum,
                                int* __restrict__ cursor) {
    int i = blockIdx.x * 256 + threadIdx.x;
    if (i < N_NODES) {
        int v = excl[i] + bsum[blockIdx.x];
        excl[i] = v;        // becomes row_ptr
        cursor[i] = v;
    }
}
// pass 1: place edges at CSR positions (by dst)
__global__ void csr_scatter_kernel(const int* __restrict__ src, const int* __restrict__ dst,
                                   const int* __restrict__ etype, int* __restrict__ cur_dst,
                                   int* __restrict__ csr_sd, int* __restrict__ csr_et) {
    int e = blockIdx.x * 256 + threadIdx.x;
    if (e < N_EDGES) {
        int p = atomicAdd(&cur_dst[dst[e]], 1);
        csr_sd[p] = src[e] | (dst[e] << 16);
        csr_et[p] = etype[e];
    }
}

// ---------- relation sort (CSR-ordered within segments) ----------
__global__ void ehist_kernel(const int* __restrict__ etype, int* __restrict__ ecnt) {
    __shared__ int l[NR];
    if (threadIdx.x < NR) l[threadIdx.x] = 0;
    __syncthreads();
    int e = blockIdx.x * 256 + threadIdx.x;
    if (e < N_EDGES) atomicAdd(&l[etype[e]], 1);
    __syncthreads();
    if (threadIdx.x < NR) atomicAdd(&ecnt[threadIdx.x], l[threadIdx.x]);
}
__global__ void escan_kernel(const int* __restrict__ ecnt, int* __restrict__ rbase,
                             int* __restrict__ rcur) {
    if (threadIdx.x == 0 && blockIdx.x == 0) {
        int acc = 0;
        for (int r = 0; r < NR; ++r) {
            rbase[r] = acc; rcur[r] = acc;
            acc += ((ecnt[r] + 15) / 16) * 16;
        }
        rbase[NR] = acc;
    }
}
__global__ void rinit_kernel(int* __restrict__ rsd, int* __restrict__ rpos) {
    int i = blockIdx.x * 256 + threadIdx.x;
    if (i < RL_CAP) { rsd[i] = 0; rpos[i] = N_EDGES; }   // sentinel -> scratch row E
}
// pass 2: walk CSR positions in order, append to relation segments
__global__ void rel_scatter_kernel(const int* __restrict__ csr_sd, const int* __restrict__ csr_et,
                                   int* __restrict__ rcur, int* __restrict__ rsd,
                                   int* __restrict__ rpos) {
    __shared__ int lcnt[NR], lbase[NR];
    if (threadIdx.x < NR) lcnt[threadIdx.x] = 0;
    __syncthreads();
    int p = blockIdx.x * 256 + threadIdx.x;
    int r = 0, off = 0;
    if (p < N_EDGES) {
        r = csr_et[p];
        off = atomicAdd(&lcnt[r], 1);
    }
    __syncthreads();
    if (threadIdx.x < NR) lbase[threadIdx.x] = atomicAdd(&rcur[threadIdx.x], lcnt[threadIdx.x]);
    __syncthreads();
    if (p < N_EDGES) {
        int rp = lbase[r] + off;
        rsd[rp] = csr_sd[p];
        rpos[rp] = p;
    }
}

// ---------- weight converts ----------
__global__ void wconv_kernel(const float* __restrict__ W, unsigned short* __restrict__ out) {
    int mat = blockIdx.x >> 3, seg = blockIdx.x & 7;
    const float* w = W + (size_t)mat * HID * HID;
    unsigned short* o = out + (size_t)mat * HID * HID;
#pragma unroll
    for (int c = 0; c < 8; ++c) {
        int idx = seg * 2048 + c * 256 + threadIdx.x;
        int i = idx >> 7, j = idx & 127;
        o[j * HID + i] = f2bf(w[idx]);
    }
}
__global__ void wsmall_conv(const float* __restrict__ W, const float* __restrict__ pri,
                            unsigned short* __restrict__ out) {
    int blk = blockIdx.x;                 // l*64 + h*8 + r
    int tid = threadIdx.x;                // 256 = 16x16
    int i = tid >> 4, o = tid & 15;
    float s = pri ? pri[blk] * 0.25f : 1.f;
    out[blk * 256 + o * 16 + i] = f2bf(W[blk * 256 + i * 16 + o] * s);
}

// ---------- MFMA typed GEMM: 32 nodes x 128 outs; K,Q,V all bf16 ----------
__global__ __launch_bounds__(256) void gemm3_mfma(
    const float* __restrict__ x, const int* __restrict__ perm, const int* __restrict__ ntype,
    const unsigned short* __restrict__ WkT, const unsigned short* __restrict__ WqT,
    const unsigned short* __restrict__ WvT,
    unsigned short* __restrict__ Kb, unsigned short* __restrict__ Qb,
    unsigned short* __restrict__ Vb) {
    __shared__ unsigned short xs[TILE][HID + 8];
    __shared__ int nodes[TILE];
    int tid = threadIdx.x;
    if (tid < TILE) nodes[tid] = perm[blockIdx.x * TILE + tid];
    __syncthreads();
    if (nodes[0] < 0) return;
    int t = ntype[nodes[0]];
#pragma unroll
    for (int c = 0; c < 4; ++c) {
        int v = tid + c * 256;
        int ns = v >> 5, ii = (v & 31) * 4;
        int node = nodes[ns];
        float4 val = (node >= 0) ? *(const float4*)(x + (size_t)node * HID + ii)
                                 : make_float4(0.f, 0.f, 0.f, 0.f);
        uint2 pk;
        pk.x = (unsigned)f2bf(val.x) | ((unsigned)f2bf(val.y) << 16);
        pk.y = (unsigned)f2bf(val.z) | ((unsigned)f2bf(val.w) << 16);
        *(uint2*)&xs[ns][ii] = pk;
    }
    __syncthreads();
    int wv = tid >> 6, lane = tid & 63;
    int lrow = lane & 15, lk = lane >> 4;
    bf16x8 af[2][4];
#pragma unroll
    for (int rt = 0; rt < 2; ++rt)
#pragma unroll
        for (int kk = 0; kk < 4; ++kk)
            af[rt][kk] = *(const bf16x8*)&xs[rt * 16 + lrow][kk * 32 + lk * 8];
    size_t woff = (size_t)t * HID * HID + (size_t)lrow * HID + lk * 8;
#pragma unroll
    for (int pp = 0; pp < 6; ++pp) {
        int p = wv * 6 + pp;
        int mat = p >> 3, ct = p & 7;
        const unsigned short* wb =
            (mat == 0 ? WkT : (mat == 1 ? WqT : WvT)) + woff + (size_t)ct * 16 * HID;
        unsigned short* ob = (mat == 0) ? Kb : (mat == 1 ? Qb : Vb);
        f32x4 a0 = {0.f, 0.f, 0.f, 0.f}, a1 = {0.f, 0.f, 0.f, 0.f};
#pragma unroll
        for (int kk = 0; kk < 4; ++kk) {
            bf16x8 bfr = *(const bf16x8*)(wb + kk * 32);
            a0 = __builtin_amdgcn_mfma_f32_16x16x32_bf16(af[0][kk], bfr, a0, 0, 0, 0);
            a1 = __builtin_amdgcn_mfma_f32_16x16x32_bf16(af[1][kk], bfr, a1, 0, 0, 0);
        }
        int col = ct * 16 + lrow;
#pragma unroll
        for (int q = 0; q < 4; ++q) {
            int r0 = lk * 4 + q;
            int n0 = nodes[r0], n1 = nodes[16 + r0];
            if (n0 >= 0) ob[(size_t)n0 * HID + col] = f2bf(a0[q]);
            if (n1 >= 0) ob[(size_t)n1 * HID + col] = f2bf(a1[q]);
        }
    }
}

// ---------- MFMA GEMM (plain, fp32 in, fp32 out, +bias) for final FF ----------
__global__ __launch_bounds__(256) void gemm1_mfma(
    const float* __restrict__ x, const int* __restrict__ perm, const int* __restrict__ ntype,
    const unsigned short* __restrict__ Wt, const float* __restrict__ bias,
    float* __restrict__ out) {
    __shared__ unsigned short xs[TILE][HID + 8];
    __shared__ int nodes[TILE];
    int tid = threadIdx.x;
    if (tid < TILE) {
        int n;
        if (perm) n = perm[blockIdx.x * TILE + tid];
        else { n = blockIdx.x * TILE + tid; if (n >= N_NODES) n = -1; }
        nodes[tid] = n;
    }
    __syncthreads();
    if (nodes[0] < 0) return;
    int t = perm ? ntype[nodes[0]] : 0;
#pragma unroll
    for (int c = 0; c < 4; ++c) {
        int v = tid + c * 256;
        int ns = v >> 5, ii = (v & 31) * 4;
        int node = nodes[ns];
        float4 val = (node >= 0) ? *(const float4*)(x + (size_t)node * HID + ii)
                                 : make_float4(0.f, 0.f, 0.f, 0.f);
        uint2 pk;
        pk.x = (unsigned)f2bf(val.x) | ((unsigned)f2bf(val.y) << 16);
        pk.y = (unsigned)f2bf(val.z) | ((unsigned)f2bf(val.w) << 16);
        *(uint2*)&xs[ns][ii] = pk;
    }
    __syncthreads();
    int wv = tid >> 6, lane = tid & 63;
    int lrow = lane & 15, lk = lane >> 4;
    bf16x8 af[2][4];
#pragma unroll
    for (int rt = 0; rt < 2; ++rt)
#pragma unroll
        for (int kk = 0; kk < 4; ++kk)
            af[rt][kk] = *(const bf16x8*)&xs[rt * 16 + lrow][kk * 32 + lk * 8];
    const unsigned short* wb0 = Wt + (size_t)t * HID * HID + (size_t)lrow * HID + lk * 8;
#pragma unroll
    for (int pp = 0; pp < 2; ++pp) {
        int ct = wv * 2 + pp;
        const unsigned short* wb = wb0 + (size_t)ct * 16 * HID;
        f32x4 a0 = {0.f, 0.f, 0.f, 0.f}, a1 = {0.f, 0.f, 0.f, 0.f};
#pragma unroll
        for (int kk = 0; kk < 4; ++kk) {
            bf16x8 bfr = *(const bf16x8*)(wb + kk * 32);
            a0 = __builtin_amdgcn_mfma_f32_16x16x32_bf16(af[0][kk], bfr, a0, 0, 0, 0);
            a1 = __builtin_amdgcn_mfma_f32_16x16x32_bf16(af[1][kk], bfr, a1, 0, 0, 0);
        }
        float bv = bias ? bias[ct * 16 + lrow] : 0.f;
#pragma unroll
        for (int q = 0; q < 4; ++q) {
            int r0 = lk * 4 + q;
            int n0 = nodes[r0], n1 = nodes[16 + r0];
            if (n0 >= 0) out[(size_t)n0 * HID + ct * 16 + lrow] = a0[q] + bv;
            if (n1 >= 0) out[(size_t)n1 * HID + ct * 16 + lrow] = a1[q] + bv;
        }
    }
}

// ---------- MFMA typed GEMM (bf16 agg in) + SiLU + gated residual + LayerNorm ----------
__global__ __launch_bounds__(256) void gemm1_ln_mfma(
    const unsigned short* __restrict__ aggb, const int* __restrict__ perm,
    const int* __restrict__ ntype, const unsigned short* __restrict__ Wt,
    const float* __restrict__ xin, const float* __restrict__ skip,
    const float* __restrict__ g, const float* __restrict__ b, float* __restrict__ xout) {
    __shared__ unsigned short xs[TILE][HID + 8];
    __shared__ int nodes[TILE];
    __shared__ float psum[TILE][4], psq[TILE][4];
    __shared__ float mu_s[TILE], rv_s[TILE];
    int tid = threadIdx.x;
    if (tid < TILE) nodes[tid] = perm[blockIdx.x * TILE + tid];
    __syncthreads();
    if (nodes[0] < 0) return;
    int t = ntype[nodes[0]];
#pragma unroll
    for (int c = 0; c < 4; ++c) {
        int v = tid + c * 256;
        int ns = v >> 5, ii = (v & 31) * 4;
        int node = nodes[ns];
        uint2 pk = make_uint2(0u, 0u);
        if (node >= 0) pk = *(const uint2*)(aggb + (size_t)node * HID + ii);
        *(uint2*)&xs[ns][ii] = pk;
    }
    __syncthreads();
    int wv = tid >> 6, lane = tid & 63;
    int lrow = lane & 15, lk = lane >> 4;
    bf16x8 af[2][4];
#pragma unroll
    for (int rt = 0; rt < 2; ++rt)
#pragma unroll
        for (int kk = 0; kk < 4; ++kk)
            af[rt][kk] = *(const bf16x8*)&xs[rt * 16 + lrow][kk * 32 + lk * 8];
    const unsigned short* wb0 = Wt + (size_t)t * HID * HID + (size_t)lrow * HID + lk * 8;
    float al = 1.f / (1.f + expf(-skip[t]));
    float om = 1.f - al;
    float ov[2][2][4];   // [pp][half][q]
#pragma unroll
    for (int pp = 0; pp < 2; ++pp) {
        int ct = wv * 2 + pp;
        const unsigned short* wb = wb0 + (size_t)ct * 16 * HID;
        f32x4 a0 = {0.f, 0.f, 0.f, 0.f}, a1 = {0.f, 0.f, 0.f, 0.f};
#pragma unroll
        for (int kk = 0; kk < 4; ++kk) {
            bf16x8 bfr = *(const bf16x8*)(wb + kk * 32);
            a0 = __builtin_amdgcn_mfma_f32_16x16x32_bf16(af[0][kk], bfr, a0, 0, 0, 0);
            a1 = __builtin_amdgcn_mfma_f32_16x16x32_bf16(af[1][kk], bfr, a1, 0, 0, 0);
        }
        int col = ct * 16 + lrow;
#pragma unroll
        for (int q = 0; q < 4; ++q) {
            int n0 = nodes[lk * 4 + q], n1 = nodes[16 + lk * 4 + q];
            float s0 = a0[q] / (1.f + expf(-a0[q]));
            float s1 = a1[q] / (1.f + expf(-a1[q]));
            float x0 = (n0 >= 0) ? xin[(size_t)n0 * HID + col] : 0.f;
            float x1 = (n1 >= 0) ? xin[(size_t)n1 * HID + col] : 0.f;
            ov[pp][0][q] = s0 * al + x0 * om;
            ov[pp][1][q] = s1 * al + x1 * om;
        }
    }
#pragma unroll
    for (int half = 0; half < 2; ++half)
#pragma unroll
        for (int q = 0; q < 4; ++q) {
            float s = ov[0][half][q] + ov[1][half][q];
            float s2 = ov[0][half][q] * ov[0][half][q] + ov[1][half][q] * ov[1][half][q];
            s += __shfl_xor(s, 1); s += __shfl_xor(s, 2);
            s += __shfl_xor(s, 4); s += __shfl_xor(s, 8);
            s2 += __shfl_xor(s2, 1); s2 += __shfl_xor(s2, 2);
            s2 += __shfl_xor(s2, 4); s2 += __shfl_xor(s2, 8);
            if (lrow == 0) {
                int nd = half * 16 + lk * 4 + q;
                psum[nd][wv] = s;
                psq[nd][wv] = s2;
            }
        }
    __syncthreads();
    if (tid < TILE) {
        float s = psum[tid][0] + psum[tid][1] + psum[tid][2] + psum[tid][3];
        float s2 = psq[tid][0] + psq[tid][1] + psq[tid][2] + psq[tid][3];
        float mu = s * (1.f / HID);
        float var = s2 * (1.f / HID) - mu * mu;
        mu_s[tid] = mu;
        rv_s[tid] = rsqrtf(fmaxf(var, 0.f) + 1e-5f);
    }
    __syncthreads();
#pragma unroll
    for (int pp = 0; pp < 2; ++pp) {
        int col = (wv * 2 + pp) * 16 + lrow;
        float gg = g[col], bb = b[col];
#pragma unroll
        for (int q = 0; q < 4; ++q) {
            int i0 = lk * 4 + q, i1 = 16 + lk * 4 + q;
            int n0 = nodes[i0], n1 = nodes[i1];
            if (n0 >= 0) xout[(size_t)n0 * HID + col] = (ov[pp][0][q] - mu_s[i0]) * rv_s[i0] * gg + bb;
            if (n1 >= 0) xout[(size_t)n1 * HID + col] = (ov[pp][1][q] - mu_s[i1]) * rv_s[i1] * gg + bb;
        }
    }
}

// ---------- edge transform: LDS-staged full-line writeout ----------
// 512 threads, wave w = relation w; block j = j-th 16-edge tile of each relation.
// mg rows accumulate in LDS; writeout covers each 128 B line with ONE store instr.
__global__ __launch_bounds__(512) void transform_kernel(
    const unsigned short* __restrict__ Kb, const unsigned short* __restrict__ Vb,
    const unsigned short* __restrict__ Qb,
    const int* __restrict__ rsd, const int* __restrict__ rpos, const int* __restrict__ rbase,
    const unsigned short* __restrict__ WattT, const unsigned short* __restrict__ WmsgT,
    float* __restrict__ scores, unsigned short* __restrict__ mg) {
    __shared__ unsigned short smg[8][16][136];   // 272 B row pitch (16B-aligned)
    __shared__ float ssc[8][16][8];
    int wv = threadIdx.x >> 6;                   // wave = relation
    int r = wv;
    int lane = threadIdx.x & 63;
    int ecol = lane & 15, lk = lane >> 4;
    int tbeg = rbase[r] + blockIdx.x * 16;
    if (tbeg >= rbase[r + 1]) return;            // wave-uniform exit
    int entry = tbeg + ecol;
    int sd = rsd[entry];
    int s = sd & 0xFFFF, dd = (sd >> 16) & 0xFFFF;
    int p = rpos[entry];

    const bf16x8 zz = {0, 0, 0, 0, 0, 0, 0, 0};
#pragma unroll
    for (int h = 0; h < NH; ++h) {
        bf16x8 bk = zz, bv = zz, aa = zz, am = zz;
        if (lk < 2) {
            bk = *(const bf16x8*)(Kb + (size_t)s * HID + h * HS + lk * 8);
            bv = *(const bf16x8*)(Vb + (size_t)s * HID + h * HS + lk * 8);
            int wo = ((h * NR + r) * 16 + ecol) * 16 + lk * 8;
            aa = *(const bf16x8*)(WattT + wo);
            am = *(const bf16x8*)(WmsgT + wo);
        }
        f32x4 ck = {0.f, 0.f, 0.f, 0.f}, cm = {0.f, 0.f, 0.f, 0.f};
        ck = __builtin_amdgcn_mfma_f32_16x16x32_bf16(aa, bk, ck, 0, 0, 0);
        cm = __builtin_amdgcn_mfma_f32_16x16x32_bf16(am, bv, cm, 0, 0, 0);
        uint2 qraw = *(const uint2*)(Qb + (size_t)dd * HID + h * HS + lk * 4);
        float q0 = __uint_as_float(qraw.x << 16);
        float q1 = __uint_as_float(qraw.x & 0xffff0000u);
        float q2 = __uint_as_float(qraw.y << 16);
        float q3 = __uint_as_float(qraw.y & 0xffff0000u);
        float xsc = ck[0] * q0 + ck[1] * q1 + ck[2] * q2 + ck[3] * q3;
        xsc += __shfl_xor(xsc, 16);
        xsc += __shfl_xor(xsc, 32);
        if (lk == 0) ssc[wv][ecol][h] = xsc;
        uint2 pk2;
        pk2.x = (unsigned)f2bf(cm[0]) | ((unsigned)f2bf(cm[1]) << 16);
        pk2.y = (unsigned)f2bf(cm[2]) | ((unsigned)f2bf(cm[3]) << 16);
        *(uint2*)&smg[wv][ecol][h * 16 + lk * 4] = pk2;
    }
    // mg writeout: 32 lines (16 edges x 2), each 128 B line by 8 lanes x 16 B in ONE instr
    int gq = lane >> 3, sub = lane & 7;
#pragma unroll
    for (int c = 0; c < 4; ++c) {
        int li = c * 8 + gq;                 // line index 0..31
        int e = li >> 1, half = li & 1;
        int pe = __shfl(p, e);               // p for edge e (lane e holds it)
        uint4 v = *(const uint4*)&smg[wv][e][half * 64 + sub * 8];
        *(uint4*)(mg + (size_t)pe * HID + half * 64 + sub * 8) = v;
    }
    // scores writeout: 16 edges x 32 B, 2 lanes x 16 B each
    int es = lane >> 1;
    int pe2 = __shfl(p, es & 15);
    if (lane < 32) {
        int hh = lane & 1;
        float4 v = *(const float4*)&ssc[wv][es][hh * 4];
        *(float4*)(scores + (size_t)pe2 * NH + hh * 4) = v;
    }
}

// ---------- edge softmax pass: wave per (dst,head), streams scores+mg; bf16 agg out ----------
__global__ __launch_bounds__(256) void edge_soft_kernel(
    const float* __restrict__ scores, const unsigned short* __restrict__ mg,
    const int* __restrict__ row_ptr, const int* __restrict__ deg,
    unsigned short* __restrict__ aggb) {
    int u = blockIdx.x * 4 + (threadIdx.x >> 6);   // (d,h) unit, grid exact
    int lane = threadIdx.x & 63;
    int d = u >> 3, h = u & 7;
    int slot = lane >> 4, o = lane & 15;
    int beg = row_ptr[d], dg = deg[d];

    float m = -INFINITY, den = 0.f, acc = 0.f;
    for (int c = 0; c < dg; c += 4) {
        int idx = c + slot;
        bool valid = idx < dg;
        int p = beg + (valid ? idx : dg - 1);
        float a = scores[p * NH + h];
        float mgv = bf2f(mg[(size_t)p * HID + h * HS + o]);
        if (!valid) a = -INFINITY;
        float am = fmaxf(a, __shfl_xor(a, 16));
        am = fmaxf(am, __shfl_xor(am, 32));
        float mn = fmaxf(m, am);
        float scale = (m == -INFINITY) ? 0.f : expf(m - mn);
        float ex = expf(a - mn);
        float exs = ex + __shfl_xor(ex, 16);
        exs += __shfl_xor(exs, 32);
        den = den * scale + exs;
        acc = acc * scale + ex * mgv;
        m = mn;
    }
    acc += __shfl_xor(acc, 16);
    acc += __shfl_xor(acc, 32);
    if (slot == 0)
        aggb[(size_t)d * HID + h * HS + o] = f2bf(acc / (den + 1e-16f));
}

extern "C" void kernel_launch(void* const* d_in, const int* in_sizes, int n_in,
                              void* d_out, int out_size, void* d_ws, size_t ws_size,
                              hipStream_t stream) {
    const float* x     = (const float*)d_in[0];
    const int*   eidx  = (const int*)d_in[1];
    const int*   ntype = (const int*)d_in[2];
    const int*   etype = (const int*)d_in[3];
    const float* Wk    = (const float*)d_in[4];
    const float* Wq    = (const float*)d_in[5];
    const float* Wv    = (const float*)d_in[6];
    const float* Wa    = (const float*)d_in[7];
    const float* pri   = (const float*)d_in[8];
    const float* Watt  = (const float*)d_in[9];
    const float* Wmsg  = (const float*)d_in[10];
    const float* skip  = (const float*)d_in[11];
    const float* ln_g  = (const float*)d_in[12];
    const float* ln_b  = (const float*)d_in[13];
    const float* Wff   = (const float*)d_in[14];
    const float* bff   = (const float*)d_in[15];
    const int* src = eidx;
    const int* dst = eidx + N_EDGES;

    char* ws = (char*)d_ws;
    size_t szN = (size_t)N_NODES * HID * sizeof(float);        // 25.6 MB
    float* embA = (float*)(ws);                                // layer-0 out
    unsigned short* AGGb = (unsigned short*)(ws + szN);        // bf16 agg (12.8 MB)
    char*  kvq  = ws + 2 * szN;
    unsigned short* Kbf = (unsigned short*)kvq;                // 12.8 MB each
    unsigned short* Vbf = (unsigned short*)(kvq + (size_t)N_NODES * HID * 2);
    unsigned short* Qbf = (unsigned short*)(kvq + 2 * (size_t)N_NODES * HID * 2);
    float* l1out = (float*)kvq;                                // aliases K+V (dead by then)
    char*  p    = kvq + 3 * (size_t)N_NODES * HID * 2;
    int* perm    = (int*)p;  p += (size_t)PERM_SZ * 4;
    int* cnt     = (int*)p;  p += TN * 4;
    int* cursor  = (int*)p;  p += TN * 4;
    int* row_ptr = (int*)p;  p += (size_t)N_NODES * 4;
    int* cnt_dst = (int*)p;  p += (size_t)N_NODES * 4;
    int* cur_dst = (int*)p;  p += (size_t)N_NODES * 4;
    int* bsum    = (int*)p;  p += 256 * 4;
    int* ecnt    = (int*)p;  p += NR * 4;
    int* rbase   = (int*)p;  p += (NR + 1) * 4;
    int* rcur    = (int*)p;  p += NR * 4;
    int* csr_sd  = (int*)p;  p += (size_t)N_EDGES * 4;
    int* csr_et  = (int*)p;  p += (size_t)N_EDGES * 4;
    int* rsd     = (int*)p;  p += (size_t)RL_CAP * 4;
    int* rpos    = (int*)p;  p += (size_t)RL_CAP * 4;
    size_t wmat = (size_t)HID * HID;
    unsigned short* WkT  = (unsigned short*)p;  p += 2 * TN * wmat * 2;
    unsigned short* WqT  = (unsigned short*)p;  p += 2 * TN * wmat * 2;
    unsigned short* WvT  = (unsigned short*)p;  p += 2 * TN * wmat * 2;
    unsigned short* WaT  = (unsigned short*)p;  p += 2 * TN * wmat * 2;
    unsigned short* WffT = (unsigned short*)p;  p += wmat * 2;
    unsigned short* WattT = (unsigned short*)p; p += 2 * 64 * 256 * 2;
    unsigned short* WmsgT = (unsigned short*)p; p += 2 * 64 * 256 * 2;
    p = (char*)(((size_t)p + 255) & ~(size_t)255);
    float* scores = (float*)p;          p += (size_t)(N_EDGES + 16) * NH * 4;   // 12.8 MB
    unsigned short* mg = (unsigned short*)p;  p += (size_t)(N_EDGES + 16) * HID * 2; // 102.4 MB

    // weight conversion (once per launch)
    wconv_kernel<<<2 * TN * 8, 256, 0, stream>>>(Wk, WkT);
    wconv_kernel<<<2 * TN * 8, 256, 0, stream>>>(Wq, WqT);
    wconv_kernel<<<2 * TN * 8, 256, 0, stream>>>(Wv, WvT);
    wconv_kernel<<<2 * TN * 8, 256, 0, stream>>>(Wa, WaT);
    wconv_kernel<<<8, 256, 0, stream>>>(Wff, WffT);
    wsmall_conv<<<128, 256, 0, stream>>>(Watt, pri, WattT);     // pri/4 baked in
    wsmall_conv<<<128, 256, 0, stream>>>(Wmsg, nullptr, WmsgT);

    // node type sort (once)
    hipMemsetAsync(cnt, 0, TN * 4, stream);
    hipMemsetAsync(perm, 0xFF, (size_t)PERM_SZ * 4, stream);
    hist_kernel<<<(N_NODES + 255) / 256, 256, 0, stream>>>(ntype, cnt);
    scan_kernel<<<1, 64, 0, stream>>>(cnt, cursor);
    scatter_kernel<<<(N_NODES + 255) / 256, 256, 0, stream>>>(ntype, cursor, perm);

    // edge CSR by dst, then CSR-ordered relation segments (once)
    hipMemsetAsync(cnt_dst, 0, (size_t)N_NODES * 4, stream);
    hipMemsetAsync(ecnt, 0, NR * 4, stream);
    hist_dst_kernel<<<(N_EDGES + 255) / 256, 256, 0, stream>>>(dst, cnt_dst);
    ehist_kernel<<<(N_EDGES + 255) / 256, 256, 0, stream>>>(etype, ecnt);
    scan_block_kernel<<<SCAN_BLKS, 256, 0, stream>>>(cnt_dst, row_ptr, bsum);
    scan_top_kernel<<<1, 256, 0, stream>>>(bsum);
    scan_add_kernel<<<SCAN_BLKS, 256, 0, stream>>>(row_ptr, bsum, cur_dst);
    csr_scatter_kernel<<<(N_EDGES + 255) / 256, 256, 0, stream>>>(src, dst, etype, cur_dst,
                                                                  csr_sd, csr_et);
    escan_kernel<<<1, 64, 0, stream>>>(ecnt, rbase, rcur);
    rinit_kernel<<<(RL_CAP + 255) / 256, 256, 0, stream>>>(rsd, rpos);
    rel_scatter_kernel<<<(N_EDGES + 255) / 256, 256, 0, stream>>>(csr_sd, csr_et, rcur,
                                                                  rsd, rpos);

    for (int l = 0; l < 2; ++l) {
        const float* xin = l ? embA : x;
        float* xout = l ? l1out : embA;
        const float* skip_l = skip + (size_t)l * TN;
        const float* g_l    = ln_g + (size_t)l * HID;
        const float* b_l    = ln_b + (size_t)l * HID;
        const unsigned short* WkT_l = WkT + (size_t)l * TN * wmat;
        const unsigned short* WqT_l = WqT + (size_t)l * TN * wmat;
        const unsigned short* WvT_l = WvT + (size_t)l * TN * wmat;
        const unsigned short* WaT_l = WaT + (size_t)l * TN * wmat;
        const unsigned short* WattT_l = WattT + (size_t)l * 64 * 256;
        const unsigned short* WmsgT_l = WmsgT + (size_t)l * 64 * 256;

        gemm3_mfma<<<MAXTILES, 256, 0, stream>>>(xin, perm, ntype, WkT_l, WqT_l, WvT_l,
                                                 Kbf, Qbf, Vbf);
        transform_kernel<<<T_GRID, 512, 0, stream>>>(Kbf, Vbf, Qbf, rsd, rpos, rbase,
                                                     WattT_l, WmsgT_l, scores, mg);
        edge_soft_kernel<<<N_NODES * NH / 4, 256, 0, stream>>>(scores, mg, row_ptr, cnt_dst,
                                                               AGGb);
        // Wa typed GEMM + SiLU + gated residual + LayerNorm (fused, bf16 agg in)
        gemm1_ln_mfma<<<MAXTILES, 256, 0, stream>>>(AGGb, perm, ntype, WaT_l, xin,
                                                    skip_l, g_l, b_l, xout);
    }
    // final FF: l1out @ Wff + bff -> d_out
    gemm1_mfma<<<(N_NODES + TILE - 1) / TILE, 256, 0, stream>>>(l1out, nullptr, ntype, WffT,
                                                                bff, (float*)d_out);
}

// Round 13
// 625.187 us; speedup vs baseline: 4.2659x; 1.0494x over previous
//
#include <hip/hip_runtime.h>
#include <hip/hip_bf16.h>
#include <math.h>

#define N_NODES 50000
#define N_EDGES 400000
#define HID 128
#define NH 8
#define HS 16
#define TN 8
#define NR 8
#define TILE 32
#define MAXTILES 1571
#define PERM_SZ (MAXTILES * TILE)
#define SCAN_BLKS ((N_NODES + 255) / 256)   // 196
#define RL_CAP 400128                        // E + 8*16 pad, multiple of 16
#define T_GRID 3280                          // >= max tiles per relation segment

typedef __attribute__((ext_vector_type(8))) short bf16x8;
typedef __attribute__((ext_vector_type(4))) float f32x4;

__device__ __forceinline__ unsigned short f2bf(float f) {
    __hip_bfloat16 h = __float2bfloat16(f);
    return *reinterpret_cast<unsigned short*>(&h);
}
__device__ __forceinline__ float bf2f(unsigned short u) {
    return __uint_as_float((unsigned)u << 16);
}

// ---------- node type sort (LDS-aggregated counting sort) ----------
__global__ void hist_kernel(const int* __restrict__ ntype, int* __restrict__ cnt) {
    __shared__ int l[TN];
    if (threadIdx.x < TN) l[threadIdx.x] = 0;
    __syncthreads();
    int i = blockIdx.x * 256 + threadIdx.x;
    if (i < N_NODES) atomicAdd(&l[ntype[i]], 1);
    __syncthreads();
    if (threadIdx.x < TN) atomicAdd(&cnt[threadIdx.x], l[threadIdx.x]);
}
__global__ void scan_kernel(const int* __restrict__ cnt, int* __restrict__ cursor) {
    if (threadIdx.x == 0 && blockIdx.x == 0) {
        int acc = 0;
        for (int t = 0; t < TN; ++t) {
            cursor[t] = acc;
            acc += ((cnt[t] + TILE - 1) / TILE) * TILE;
        }
    }
}
__global__ void scatter_kernel(const int* __restrict__ ntype, int* __restrict__ cursor,
                               int* __restrict__ perm) {
    __shared__ int lcnt[TN], lbase[TN];
    if (threadIdx.x < TN) lcnt[threadIdx.x] = 0;
    __syncthreads();
    int i = blockIdx.x * 256 + threadIdx.x;
    int t = 0, off = 0;
    if (i < N_NODES) {
        t = ntype[i];
        off = atomicAdd(&lcnt[t], 1);
    }
    __syncthreads();
    if (threadIdx.x < TN)
        lbase[threadIdx.x] = atomicAdd(&cursor[threadIdx.x], lcnt[threadIdx.x]);
    __syncthreads();
    if (i < N_NODES) perm[lbase[t] + off] = i;
}

// ---------- edge CSR build (sort by dst) ----------
__global__ void hist_dst_kernel(const int* __restrict__ dst, int* __restrict__ cnt) {
    int e = blockIdx.x * 256 + threadIdx.x;
    if (e < N_EDGES) atomicAdd(&cnt[dst[e]], 1);
}
__global__ void scan_block_kernel(const int* __restrict__ cnt, int* __restrict__ excl,
                                  int* __restrict__ bsum) {
    __shared__ int s[256];
    int tid = threadIdx.x;
    int i = blockIdx.x * 256 + tid;
    int v = (i < N_NODES) ? cnt[i] : 0;
    s[tid] = v;
    __syncthreads();
    for (int off = 1; off < 256; off <<= 1) {
        int t = (tid >= off) ? s[tid - off] : 0;
        __syncthreads();
        s[tid] += t;
        __syncthreads();
    }
    if (i < N_NODES) excl[i] = s[tid] - v;
    if (tid == 255) bsum[blockIdx.x] = s[255];
}
__global__ void scan_top_kernel(int* __restrict__ bsum) {
    __shared__ int s[256];
    int tid = threadIdx.x;
    int v = (tid < SCAN_BLKS) ? bsum[tid] : 0;
    s[tid] = v;
    __syncthreads();
    for (int off = 1; off < 256; off <<= 1) {
        int t = (tid >= off) ? s[tid - off] : 0;
        __syncthreads();
        s[tid] += t;
        __syncthreads();
    }
    if (tid < SCAN_BLKS) bsum[tid] = s[tid] - v;   // exclusive
}
__global__ void scan_add_kernel(int* __restrict__ excl, const int* __restrict__ bsum,
                                int* __restrict__ cursor) {
    int i = blockIdx.x * 256 + threadIdx.x;
    if (i < N_NODES) {
        int v = excl[i] + bsum[blockIdx.x];
        excl[i] = v;        // becomes row_ptr
        cursor[i] = v;
    }
}
// pass 1: place edges at CSR positions (by dst)
__global__ void csr_scatter_kernel(const int* __restrict__ src, const int* __restrict__ dst,
                                   const int* __restrict__ etype, int* __restrict__ cur_dst,
                                   int* __restrict__ csr_sd, int* __restrict__ csr_et) {
    int e = blockIdx.x * 256 + threadIdx.x;
    if (e < N_EDGES) {
        int p = atomicAdd(&cur_dst[dst[e]], 1);
        csr_sd[p] = src[e] | (dst[e] << 16);
        csr_et[p] = etype[e];
    }
}

// ---------- relation sort (CSR-ordered within segments) ----------
__global__ void ehist_kernel(const int* __restrict__ etype, int* __restrict__ ecnt) {
    __shared__ int l[NR];
    if (threadIdx.x < NR) l[threadIdx.x] = 0;
    __syncthreads();
    int e = blockIdx.x * 256 + threadIdx.x;
    if (e < N_EDGES) atomicAdd(&l[etype[e]], 1);
    __syncthreads();
    if (threadIdx.x < NR) atomicAdd(&ecnt[threadIdx.x], l[threadIdx.x]);
}
__global__ void escan_kernel(const int* __restrict__ ecnt, int* __restrict__ rbase,
                             int* __restrict__ rcur) {
    if (threadIdx.x == 0 && blockIdx.x == 0) {
        int acc = 0;
        for (int r = 0; r < NR; ++r) {
            rbase[r] = acc; rcur[r] = acc;
            acc += ((ecnt[r] + 15) / 16) * 16;
        }
        rbase[NR] = acc;
    }
}
__global__ void rinit_kernel(int* __restrict__ rsd, int* __restrict__ rpos) {
    int i = blockIdx.x * 256 + threadIdx.x;
    if (i < RL_CAP) { rsd[i] = 0; rpos[i] = N_EDGES; }   // sentinel -> scratch row E
}
// pass 2: walk CSR positions in order, append to relation segments
__global__ void rel_scatter_kernel(const int* __restrict__ csr_sd, const int* __restrict__ csr_et,
                                   int* __restrict__ rcur, int* __restrict__ rsd,
                                   int* __restrict__ rpos) {
    __shared__ int lcnt[NR], lbase[NR];
    if (threadIdx.x < NR) lcnt[threadIdx.x] = 0;
    __syncthreads();
    int p = blockIdx.x * 256 + threadIdx.x;
    int r = 0, off = 0;
    if (p < N_EDGES) {
        r = csr_et[p];
        off = atomicAdd(&lcnt[r], 1);
    }
    __syncthreads();
    if (threadIdx.x < NR) lbase[threadIdx.x] = atomicAdd(&rcur[threadIdx.x], lcnt[threadIdx.x]);
    __syncthreads();
    if (p < N_EDGES) {
        int rp = lbase[r] + off;
        rsd[rp] = csr_sd[p];
        rpos[rp] = p;
    }
}

// ---------- weight converts ----------
__global__ void wconv_kernel(const float* __restrict__ W, unsigned short* __restrict__ out) {
    int mat = blockIdx.x >> 3, seg = blockIdx.x & 7;
    const float* w = W + (size_t)mat * HID * HID;
    unsigned short* o = out + (size_t)mat * HID * HID;
#pragma unroll
    for (int c = 0; c < 8; ++c) {
        int idx = seg * 2048 + c * 256 + threadIdx.x;
        int i = idx >> 7, j = idx & 127;
        o[j * HID + i] = f2bf(w[idx]);
    }
}
__global__ void wsmall_conv(const float* __restrict__ W, const float* __restrict__ pri,
                            unsigned short* __restrict__ out) {
    int blk = blockIdx.x;                 // l*64 + h*8 + r
    int tid = threadIdx.x;                // 256 = 16x16
    int i = tid >> 4, o = tid & 15;
    float s = pri ? pri[blk] * 0.25f : 1.f;
    out[blk * 256 + o * 16 + i] = f2bf(W[blk * 256 + i * 16 + o] * s);
}

// ---------- MFMA typed GEMM: 32 nodes x 128 outs; K,Q,V all bf16 ----------
__global__ __launch_bounds__(256) void gemm3_mfma(
    const float* __restrict__ x, const int* __restrict__ perm, const int* __restrict__ ntype,
    const unsigned short* __restrict__ WkT, const unsigned short* __restrict__ WqT,
    const unsigned short* __restrict__ WvT,
    unsigned short* __restrict__ Kb, unsigned short* __restrict__ Qb,
    unsigned short* __restrict__ Vb) {
    __shared__ unsigned short xs[TILE][HID + 8];
    __shared__ int nodes[TILE];
    int tid = threadIdx.x;
    if (tid < TILE) nodes[tid] = perm[blockIdx.x * TILE + tid];
    __syncthreads();
    if (nodes[0] < 0) return;
    int t = ntype[nodes[0]];
#pragma unroll
    for (int c = 0; c < 4; ++c) {
        int v = tid + c * 256;
        int ns = v >> 5, ii = (v & 31) * 4;
        int node = nodes[ns];
        float4 val = (node >= 0) ? *(const float4*)(x + (size_t)node * HID + ii)
                                 : make_float4(0.f, 0.f, 0.f, 0.f);
        uint2 pk;
        pk.x = (unsigned)f2bf(val.x) | ((unsigned)f2bf(val.y) << 16);
        pk.y = (unsigned)f2bf(val.z) | ((unsigned)f2bf(val.w) << 16);
        *(uint2*)&xs[ns][ii] = pk;
    }
    __syncthreads();
    int wv = tid >> 6, lane = tid & 63;
    int lrow = lane & 15, lk = lane >> 4;
    bf16x8 af[2][4];
#pragma unroll
    for (int rt = 0; rt < 2; ++rt)
#pragma unroll
        for (int kk = 0; kk < 4; ++kk)
            af[rt][kk] = *(const bf16x8*)&xs[rt * 16 + lrow][kk * 32 + lk * 8];
    size_t woff = (size_t)t * HID * HID + (size_t)lrow * HID + lk * 8;
#pragma unroll
    for (int pp = 0; pp < 6; ++pp) {
        int p = wv * 6 + pp;
        int mat = p >> 3, ct = p & 7;
        const unsigned short* wb =
            (mat == 0 ? WkT : (mat == 1 ? WqT : WvT)) + woff + (size_t)ct * 16 * HID;
        unsigned short* ob = (mat == 0) ? Kb : (mat == 1 ? Qb : Vb);
        f32x4 a0 = {0.f, 0.f, 0.f, 0.f}, a1 = {0.f, 0.f, 0.f, 0.f};
#pragma unroll
        for (int kk = 0; kk < 4; ++kk) {
            bf16x8 bfr = *(const bf16x8*)(wb + kk * 32);
            a0 = __builtin_amdgcn_mfma_f32_16x16x32_bf16(af[0][kk], bfr, a0, 0, 0, 0);
            a1 = __builtin_amdgcn_mfma_f32_16x16x32_bf16(af[1][kk], bfr, a1, 0, 0, 0);
        }
        int col = ct * 16 + lrow;
#pragma unroll
        for (int q = 0; q < 4; ++q) {
            int r0 = lk * 4 + q;
            int n0 = nodes[r0], n1 = nodes[16 + r0];
            if (n0 >= 0) ob[(size_t)n0 * HID + col] = f2bf(a0[q]);
            if (n1 >= 0) ob[(size_t)n1 * HID + col] = f2bf(a1[q]);
        }
    }
}

// ---------- MFMA GEMM (plain, fp32 in, fp32 out, +bias) for final FF ----------
__global__ __launch_bounds__(256) void gemm1_mfma(
    const float* __restrict__ x, const int* __restrict__ perm, const int* __restrict__ ntype,
    const unsigned short* __restrict__ Wt, const float* __restrict__ bias,
    float* __restrict__ out) {
    __shared__ unsigned short xs[TILE][HID + 8];
    __shared__ int nodes[TILE];
    int tid = threadIdx.x;
    if (tid < TILE) {
        int n;
        if (perm) n = perm[blockIdx.x * TILE + tid];
        else { n = blockIdx.x * TILE + tid; if (n >= N_NODES) n = -1; }
        nodes[tid] = n;
    }
    __syncthreads();
    if (nodes[0] < 0) return;
    int t = perm ? ntype[nodes[0]] : 0;
#pragma unroll
    for (int c = 0; c < 4; ++c) {
        int v = tid + c * 256;
        int ns = v >> 5, ii = (v & 31) * 4;
        int node = nodes[ns];
        float4 val = (node >= 0) ? *(const float4*)(x + (size_t)node * HID + ii)
                                 : make_float4(0.f, 0.f, 0.f, 0.f);
        uint2 pk;
        pk.x = (unsigned)f2bf(val.x) | ((unsigned)f2bf(val.y) << 16);
        pk.y = (unsigned)f2bf(val.z) | ((unsigned)f2bf(val.w) << 16);
        *(uint2*)&xs[ns][ii] = pk;
    }
    __syncthreads();
    int wv = tid >> 6, lane = tid & 63;
    int lrow = lane & 15, lk = lane >> 4;
    bf16x8 af[2][4];
#pragma unroll
    for (int rt = 0; rt < 2; ++rt)
#pragma unroll
        for (int kk = 0; kk < 4; ++kk)
            af[rt][kk] = *(const bf16x8*)&xs[rt * 16 + lrow][kk * 32 + lk * 8];
    const unsigned short* wb0 = Wt + (size_t)t * HID * HID + (size_t)lrow * HID + lk * 8;
#pragma unroll
    for (int pp = 0; pp < 2; ++pp) {
        int ct = wv * 2 + pp;
        const unsigned short* wb = wb0 + (size_t)ct * 16 * HID;
        f32x4 a0 = {0.f, 0.f, 0.f, 0.f}, a1 = {0.f, 0.f, 0.f, 0.f};
#pragma unroll
        for (int kk = 0; kk < 4; ++kk) {
            bf16x8 bfr = *(const bf16x8*)(wb + kk * 32);
            a0 = __builtin_amdgcn_mfma_f32_16x16x32_bf16(af[0][kk], bfr, a0, 0, 0, 0);
            a1 = __builtin_amdgcn_mfma_f32_16x16x32_bf16(af[1][kk], bfr, a1, 0, 0, 0);
        }
        float bv = bias ? bias[ct * 16 + lrow] : 0.f;
#pragma unroll
        for (int q = 0; q < 4; ++q) {
            int r0 = lk * 4 + q;
            int n0 = nodes[r0], n1 = nodes[16 + r0];
            if (n0 >= 0) out[(size_t)n0 * HID + ct * 16 + lrow] = a0[q] + bv;
            if (n1 >= 0) out[(size_t)n1 * HID + ct * 16 + lrow] = a1[q] + bv;
        }
    }
}

// ---------- MFMA typed GEMM (bf16 agg in) + SiLU + gated residual + LayerNorm ----------
__global__ __launch_bounds__(256) void gemm1_ln_mfma(
    const unsigned short* __restrict__ aggb, const int* __restrict__ perm,
    const int* __restrict__ ntype, const unsigned short* __restrict__ Wt,
    const float* __restrict__ xin, const float* __restrict__ skip,
    const float* __restrict__ g, const float* __restrict__ b, float* __restrict__ xout) {
    __shared__ unsigned short xs[TILE][HID + 8];
    __shared__ int nodes[TILE];
    __shared__ float psum[TILE][4], psq[TILE][4];
    __shared__ float mu_s[TILE], rv_s[TILE];
    int tid = threadIdx.x;
    if (tid < TILE) nodes[tid] = perm[blockIdx.x * TILE + tid];
    __syncthreads();
    if (nodes[0] < 0) return;
    int t = ntype[nodes[0]];
#pragma unroll
    for (int c = 0; c < 4; ++c) {
        int v = tid + c * 256;
        int ns = v >> 5, ii = (v & 31) * 4;
        int node = nodes[ns];
        uint2 pk = make_uint2(0u, 0u);
        if (node >= 0) pk = *(const uint2*)(aggb + (size_t)node * HID + ii);
        *(uint2*)&xs[ns][ii] = pk;
    }
    __syncthreads();
    int wv = tid >> 6, lane = tid & 63;
    int lrow = lane & 15, lk = lane >> 4;
    bf16x8 af[2][4];
#pragma unroll
    for (int rt = 0; rt < 2; ++rt)
#pragma unroll
        for (int kk = 0; kk < 4; ++kk)
            af[rt][kk] = *(const bf16x8*)&xs[rt * 16 + lrow][kk * 32 + lk * 8];
    const unsigned short* wb0 = Wt + (size_t)t * HID * HID + (size_t)lrow * HID + lk * 8;
    float al = 1.f / (1.f + __expf(-skip[t]));
    float om = 1.f - al;
    float ov[2][2][4];   // [pp][half][q]
#pragma unroll
    for (int pp = 0; pp < 2; ++pp) {
        int ct = wv * 2 + pp;
        const unsigned short* wb = wb0 + (size_t)ct * 16 * HID;
        f32x4 a0 = {0.f, 0.f, 0.f, 0.f}, a1 = {0.f, 0.f, 0.f, 0.f};
#pragma unroll
        for (int kk = 0; kk < 4; ++kk) {
            bf16x8 bfr = *(const bf16x8*)(wb + kk * 32);
            a0 = __builtin_amdgcn_mfma_f32_16x16x32_bf16(af[0][kk], bfr, a0, 0, 0, 0);
            a1 = __builtin_amdgcn_mfma_f32_16x16x32_bf16(af[1][kk], bfr, a1, 0, 0, 0);
        }
        int col = ct * 16 + lrow;
#pragma unroll
        for (int q = 0; q < 4; ++q) {
            int n0 = nodes[lk * 4 + q], n1 = nodes[16 + lk * 4 + q];
            float s0 = a0[q] / (1.f + __expf(-a0[q]));
            float s1 = a1[q] / (1.f + __expf(-a1[q]));
            float x0 = (n0 >= 0) ? xin[(size_t)n0 * HID + col] : 0.f;
            float x1 = (n1 >= 0) ? xin[(size_t)n1 * HID + col] : 0.f;
            ov[pp][0][q] = s0 * al + x0 * om;
            ov[pp][1][q] = s1 * al + x1 * om;
        }
    }
#pragma unroll
    for (int half = 0; half < 2; ++half)
#pragma unroll
        for (int q = 0; q < 4; ++q) {
            float s = ov[0][half][q] + ov[1][half][q];
            float s2 = ov[0][half][q] * ov[0][half][q] + ov[1][half][q] * ov[1][half][q];
            s += __shfl_xor(s, 1); s += __shfl_xor(s, 2);
            s += __shfl_xor(s, 4); s += __shfl_xor(s, 8);
            s2 += __shfl_xor(s2, 1); s2 += __shfl_xor(s2, 2);
            s2 += __shfl_xor(s2, 4); s2 += __shfl_xor(s2, 8);
            if (lrow == 0) {
                int nd = half * 16 + lk * 4 + q;
                psum[nd][wv] = s;
                psq[nd][wv] = s2;
            }
        }
    __syncthreads();
    if (tid < TILE) {
        float s = psum[tid][0] + psum[tid][1] + psum[tid][2] + psum[tid][3];
        float s2 = psq[tid][0] + psq[tid][1] + psq[tid][2] + psq[tid][3];
        float mu = s * (1.f / HID);
        float var = s2 * (1.f / HID) - mu * mu;
        mu_s[tid] = mu;
        rv_s[tid] = rsqrtf(fmaxf(var, 0.f) + 1e-5f);
    }
    __syncthreads();
#pragma unroll
    for (int pp = 0; pp < 2; ++pp) {
        int col = (wv * 2 + pp) * 16 + lrow;
        float gg = g[col], bb = b[col];
#pragma unroll
        for (int q = 0; q < 4; ++q) {
            int i0 = lk * 4 + q, i1 = 16 + lk * 4 + q;
            int n0 = nodes[i0], n1 = nodes[i1];
            if (n0 >= 0) xout[(size_t)n0 * HID + col] = (ov[pp][0][q] - mu_s[i0]) * rv_s[i0] * gg + bb;
            if (n1 >= 0) xout[(size_t)n1 * HID + col] = (ov[pp][1][q] - mu_s[i1]) * rv_s[i1] * gg + bb;
        }
    }
}

// ---------- edge transform: LDS-staged full-line writeout ----------
__global__ __launch_bounds__(512) void transform_kernel(
    const unsigned short* __restrict__ Kb, const unsigned short* __restrict__ Vb,
    const unsigned short* __restrict__ Qb,
    const int* __restrict__ rsd, const int* __restrict__ rpos, const int* __restrict__ rbase,
    const unsigned short* __restrict__ WattT, const unsigned short* __restrict__ WmsgT,
    float* __restrict__ scores, unsigned short* __restrict__ mg) {
    __shared__ unsigned short smg[8][16][136];   // 272 B row pitch (16B-aligned)
    __shared__ float ssc[8][16][8];
    int wv = threadIdx.x >> 6;                   // wave = relation
    int r = wv;
    int lane = threadIdx.x & 63;
    int ecol = lane & 15, lk = lane >> 4;
    int tbeg = rbase[r] + blockIdx.x * 16;
    if (tbeg >= rbase[r + 1]) return;            // wave-uniform exit
    int entry = tbeg + ecol;
    int sd = rsd[entry];
    int s = sd & 0xFFFF, dd = (sd >> 16) & 0xFFFF;
    int p = rpos[entry];

    const bf16x8 zz = {0, 0, 0, 0, 0, 0, 0, 0};
#pragma unroll
    for (int h = 0; h < NH; ++h) {
        bf16x8 bk = zz, bv = zz, aa = zz, am = zz;
        if (lk < 2) {
            bk = *(const bf16x8*)(Kb + (size_t)s * HID + h * HS + lk * 8);
            bv = *(const bf16x8*)(Vb + (size_t)s * HID + h * HS + lk * 8);
            int wo = ((h * NR + r) * 16 + ecol) * 16 + lk * 8;
            aa = *(const bf16x8*)(WattT + wo);
            am = *(const bf16x8*)(WmsgT + wo);
        }
        f32x4 ck = {0.f, 0.f, 0.f, 0.f}, cm = {0.f, 0.f, 0.f, 0.f};
        ck = __builtin_amdgcn_mfma_f32_16x16x32_bf16(aa, bk, ck, 0, 0, 0);
        cm = __builtin_amdgcn_mfma_f32_16x16x32_bf16(am, bv, cm, 0, 0, 0);
        uint2 qraw = *(const uint2*)(Qb + (size_t)dd * HID + h * HS + lk * 4);
        float q0 = __uint_as_float(qraw.x << 16);
        float q1 = __uint_as_float(qraw.x & 0xffff0000u);
        float q2 = __uint_as_float(qraw.y << 16);
        float q3 = __uint_as_float(qraw.y & 0xffff0000u);
        float xsc = ck[0] * q0 + ck[1] * q1 + ck[2] * q2 + ck[3] * q3;
        xsc += __shfl_xor(xsc, 16);
        xsc += __shfl_xor(xsc, 32);
        if (lk == 0) ssc[wv][ecol][h] = xsc;
        uint2 pk2;
        pk2.x = (unsigned)f2bf(cm[0]) | ((unsigned)f2bf(cm[1]) << 16);
        pk2.y = (unsigned)f2bf(cm[2]) | ((unsigned)f2bf(cm[3]) << 16);
        *(uint2*)&smg[wv][ecol][h * 16 + lk * 4] = pk2;
    }
    // mg writeout: 32 lines (16 edges x 2), each 128 B line by 8 lanes x 16 B in ONE instr
    int gq = lane >> 3, sub = lane & 7;
#pragma unroll
    for (int c = 0; c < 4; ++c) {
        int li = c * 8 + gq;                 // line index 0..31
        int e = li >> 1, half = li & 1;
        int pe = __shfl(p, e);               // p for edge e (lane e holds it)
        uint4 v = *(const uint4*)&smg[wv][e][half * 64 + sub * 8];
        *(uint4*)(mg + (size_t)pe * HID + half * 64 + sub * 8) = v;
    }
    // scores writeout: 16 edges x 32 B, 2 lanes x 16 B each
    int es = lane >> 1;
    int pe2 = __shfl(p, es & 15);
    if (lane < 32) {
        int hh = lane & 1;
        float4 v = *(const float4*)&ssc[wv][es][hh * 4];
        *(float4*)(scores + (size_t)pe2 * NH + hh * 4) = v;
    }
}

// ---------- edge softmax: per-slot online state, shfl-free inner loop ----------
// wave per (d,h); slot s handles edges s, s+4, s+8, ... independently; the 4
// partial softmax states merge exactly once at the end.
__global__ __launch_bounds__(256) void edge_soft_kernel(
    const float* __restrict__ scores, const unsigned short* __restrict__ mg,
    const int* __restrict__ row_ptr, const int* __restrict__ deg,
    unsigned short* __restrict__ aggb) {
    int u = blockIdx.x * 4 + (threadIdx.x >> 6);   // (d,h) unit, grid exact
    int lane = threadIdx.x & 63;
    int d = u >> 3, h = u & 7;
    int slot = lane >> 4, o = lane & 15;
    int beg = row_ptr[d], dg = deg[d];

    float m = -INFINITY, den = 0.f, acc = 0.f;
    for (int idx = slot; idx < dg; idx += 4) {
        int p = beg + idx;
        float a = scores[p * NH + h];
        float mgv = bf2f(mg[(size_t)p * HID + h * HS + o]);
        float mn = fmaxf(m, a);
        float scale = __expf(m - mn);              // 0 on first iter (m=-inf, mn finite)
        float ex = __expf(a - mn);
        den = den * scale + ex;
        acc = acc * scale + ex * mgv;
        m = mn;
    }
    // merge 4 per-slot partial softmax states (exact)
    float mg1 = fmaxf(m, __shfl_xor(m, 16));
    float mgl = fmaxf(mg1, __shfl_xor(mg1, 32));
    float f = (m > -INFINITY) ? __expf(m - mgl) : 0.f;   // guards deg==0 / empty slot NaN
    den *= f;
    acc *= f;
    den += __shfl_xor(den, 16); den += __shfl_xor(den, 32);
    acc += __shfl_xor(acc, 16); acc += __shfl_xor(acc, 32);
    if (slot == 0)
        aggb[(size_t)d * HID + h * HS + o] = f2bf(acc / (den + 1e-16f));
}

extern "C" void kernel_launch(void* const* d_in, const int* in_sizes, int n_in,
                              void* d_out, int out_size, void* d_ws, size_t ws_size,
                              hipStream_t stream) {
    const float* x     = (const float*)d_in[0];
    const int*   eidx  = (const int*)d_in[1];
    const int*   ntype = (const int*)d_in[2];
    const int*   etype = (const int*)d_in[3];
    const float* Wk    = (const float*)d_in[4];
    const float* Wq    = (const float*)d_in[5];
    const float* Wv    = (const float*)d_in[6];
    const float* Wa    = (const float*)d_in[7];
    const float* pri   = (const float*)d_in[8];
    const float* Watt  = (const float*)d_in[9];
    const float* Wmsg  = (const float*)d_in[10];
    const float* skip  = (const float*)d_in[11];
    const float* ln_g  = (const float*)d_in[12];
    const float* ln_b  = (const float*)d_in[13];
    const float* Wff   = (const float*)d_in[14];
    const float* bff   = (const float*)d_in[15];
    const int* src = eidx;
    const int* dst = eidx + N_EDGES;

    char* ws = (char*)d_ws;
    size_t szN = (size_t)N_NODES * HID * sizeof(float);        // 25.6 MB
    float* embA = (float*)(ws);                                // layer-0 out
    unsigned short* AGGb = (unsigned short*)(ws + szN);        // bf16 agg (12.8 MB)
    char*  kvq  = ws + 2 * szN;
    unsigned short* Kbf = (unsigned short*)kvq;                // 12.8 MB each
    unsigned short* Vbf = (unsigned short*)(kvq + (size_t)N_NODES * HID * 2);
    unsigned short* Qbf = (unsigned short*)(kvq + 2 * (size_t)N_NODES * HID * 2);
    float* l1out = (float*)kvq;                                // aliases K+V (dead by then)
    char*  p    = kvq + 3 * (size_t)N_NODES * HID * 2;
    int* perm    = (int*)p;  p += (size_t)PERM_SZ * 4;
    int* cnt     = (int*)p;  p += TN * 4;
    int* cursor  = (int*)p;  p += TN * 4;
    int* row_ptr = (int*)p;  p += (size_t)N_NODES * 4;
    int* cnt_dst = (int*)p;  p += (size_t)N_NODES * 4;
    int* cur_dst = (int*)p;  p += (size_t)N_NODES * 4;
    int* bsum    = (int*)p;  p += 256 * 4;
    int* ecnt    = (int*)p;  p += NR * 4;
    int* rbase   = (int*)p;  p += (NR + 1) * 4;
    int* rcur    = (int*)p;  p += NR * 4;
    int* csr_sd  = (int*)p;  p += (size_t)N_EDGES * 4;
    int* csr_et  = (int*)p;  p += (size_t)N_EDGES * 4;
    int* rsd     = (int*)p;  p += (size_t)RL_CAP * 4;
    int* rpos    = (int*)p;  p += (size_t)RL_CAP * 4;
    size_t wmat = (size_t)HID * HID;
    unsigned short* WkT  = (unsigned short*)p;  p += 2 * TN * wmat * 2;
    unsigned short* WqT  = (unsigned short*)p;  p += 2 * TN * wmat * 2;
    unsigned short* WvT  = (unsigned short*)p;  p += 2 * TN * wmat * 2;
    unsigned short* WaT  = (unsigned short*)p;  p += 2 * TN * wmat * 2;
    unsigned short* WffT = (unsigned short*)p;  p += wmat * 2;
    unsigned short* WattT = (unsigned short*)p; p += 2 * 64 * 256 * 2;
    unsigned short* WmsgT = (unsigned short*)p; p += 2 * 64 * 256 * 2;
    p = (char*)(((size_t)p + 255) & ~(size_t)255);
    float* scores = (float*)p;          p += (size_t)(N_EDGES + 16) * NH * 4;   // 12.8 MB
    unsigned short* mg = (unsigned short*)p;  p += (size_t)(N_EDGES + 16) * HID * 2; // 102.4 MB

    // weight conversion (once per launch)
    wconv_kernel<<<2 * TN * 8, 256, 0, stream>>>(Wk, WkT);
    wconv_kernel<<<2 * TN * 8, 256, 0, stream>>>(Wq, WqT);
    wconv_kernel<<<2 * TN * 8, 256, 0, stream>>>(Wv, WvT);
    wconv_kernel<<<2 * TN * 8, 256, 0, stream>>>(Wa, WaT);
    wconv_kernel<<<8, 256, 0, stream>>>(Wff, WffT);
    wsmall_conv<<<128, 256, 0, stream>>>(Watt, pri, WattT);     // pri/4 baked in
    wsmall_conv<<<128, 256, 0, stream>>>(Wmsg, nullptr, WmsgT);

    // node type sort (once)
    hipMemsetAsync(cnt, 0, TN * 4, stream);
    hipMemsetAsync(perm, 0xFF, (size_t)PERM_SZ * 4, stream);
    hist_kernel<<<(N_NODES + 255) / 256, 256, 0, stream>>>(ntype, cnt);
    scan_kernel<<<1, 64, 0, stream>>>(cnt, cursor);
    scatter_kernel<<<(N_NODES + 255) / 256, 256, 0, stream>>>(ntype, cursor, perm);

    // edge CSR by dst, then CSR-ordered relation segments (once)
    hipMemsetAsync(cnt_dst, 0, (size_t)N_NODES * 4, stream);
    hipMemsetAsync(ecnt, 0, NR * 4, stream);
    hist_dst_kernel<<<(N_EDGES + 255) / 256, 256, 0, stream>>>(dst, cnt_dst);
    ehist_kernel<<<(N_EDGES + 255) / 256, 256, 0, stream>>>(etype, ecnt);
    scan_block_kernel<<<SCAN_BLKS, 256, 0, stream>>>(cnt_dst, row_ptr, bsum);
    scan_top_kernel<<<1, 256, 0, stream>>>(bsum);
    scan_add_kernel<<<SCAN_BLKS, 256, 0, stream>>>(row_ptr, bsum, cur_dst);
    csr_scatter_kernel<<<(N_EDGES + 255) / 256, 256, 0, stream>>>(src, dst, etype, cur_dst,
                                                                  csr_sd, csr_et);
    escan_kernel<<<1, 64, 0, stream>>>(ecnt, rbase, rcur);
    rinit_kernel<<<(RL_CAP + 255) / 256, 256, 0, stream>>>(rsd, rpos);
    rel_scatter_kernel<<<(N_EDGES + 255) / 256, 256, 0, stream>>>(csr_sd, csr_et, rcur,
                                                                  rsd, rpos);

    for (int l = 0; l < 2; ++l) {
        const float* xin = l ? embA : x;
        float* xout = l ? l1out : embA;
        const float* skip_l = skip + (size_t)l * TN;
        const float* g_l    = ln_g + (size_t)l * HID;
        const float* b_l    = ln_b + (size_t)l * HID;
        const unsigned short* WkT_l = WkT + (size_t)l * TN * wmat;
        const unsigned short* WqT_l = WqT + (size_t)l * TN * wmat;
        const unsigned short* WvT_l = WvT + (size_t)l * TN * wmat;
        const unsigned short* WaT_l = WaT + (size_t)l * TN * wmat;
        const unsigned short* WattT_l = WattT + (size_t)l * 64 * 256;
        const unsigned short* WmsgT_l = WmsgT + (size_t)l * 64 * 256;

        gemm3_mfma<<<MAXTILES, 256, 0, stream>>>(xin, perm, ntype, WkT_l, WqT_l, WvT_l,
                                                 Kbf, Qbf, Vbf);
        transform_kernel<<<T_GRID, 512, 0, stream>>>(Kbf, Vbf, Qbf, rsd, rpos, rbase,
                                                     WattT_l, WmsgT_l, scores, mg);
        edge_soft_kernel<<<N_NODES * NH / 4, 256, 0, stream>>>(scores, mg, row_ptr, cnt_dst,
                                                               AGGb);
        // Wa typed GEMM + SiLU + gated residual + LayerNorm (fused, bf16 agg in)
        gemm1_ln_mfma<<<MAXTILES, 256, 0, stream>>>(AGGb, perm, ntype, WaT_l, xin,
                                                    skip_l, g_l, b_l, xout);
    }
    // final FF: l1out @ Wff + bff -> d_out
    gemm1_mfma<<<(N_NODES + TILE - 1) / TILE, 256, 0, stream>>>(l1out, nullptr, ntype, WffT,
                                                                bff, (float*)d_out);
}

// Round 14
// 488.365 us; speedup vs baseline: 5.4610x; 1.2802x over previous
//
#include <hip/hip_runtime.h>
#include <hip/hip_bf16.h>
#include <math.h>

#define N_NODES 50000
#define N_EDGES 400000
#define HID 128
#define NH 8
#define HS 16
#define TN 8
#define NR 8
#define TILE 32
#define MAXTILES 1571
#define PERM_SZ (MAXTILES * TILE)
#define SCAN_BLKS ((N_NODES + 255) / 256)   // 196
#define RL_CAP 400128                        // E + 8*16 pad, multiple of 16
#define T_GRID 3280                          // >= max tiles per relation segment

typedef __attribute__((ext_vector_type(8))) short bf16x8;
typedef __attribute__((ext_vector_type(4))) float f32x4;

__device__ __forceinline__ unsigned short f2bf(float f) {
    __hip_bfloat16 h = __float2bfloat16(f);
    return *reinterpret_cast<unsigned short*>(&h);
}
__device__ __forceinline__ float bf2f(unsigned short u) {
    return __uint_as_float((unsigned)u << 16);
}

// ---------- node type sort (LDS-aggregated counting sort) ----------
__global__ void hist_kernel(const int* __restrict__ ntype, int* __restrict__ cnt) {
    __shared__ int l[TN];
    if (threadIdx.x < TN) l[threadIdx.x] = 0;
    __syncthreads();
    int i = blockIdx.x * 256 + threadIdx.x;
    if (i < N_NODES) atomicAdd(&l[ntype[i]], 1);
    __syncthreads();
    if (threadIdx.x < TN) atomicAdd(&cnt[threadIdx.x], l[threadIdx.x]);
}
__global__ void scan_kernel(const int* __restrict__ cnt, int* __restrict__ cursor) {
    if (threadIdx.x == 0 && blockIdx.x == 0) {
        int acc = 0;
        for (int t = 0; t < TN; ++t) {
            cursor[t] = acc;
            acc += ((cnt[t] + TILE - 1) / TILE) * TILE;
        }
    }
}
__global__ void scatter_kernel(const int* __restrict__ ntype, int* __restrict__ cursor,
                               int* __restrict__ perm) {
    __shared__ int lcnt[TN], lbase[TN];
    if (threadIdx.x < TN) lcnt[threadIdx.x] = 0;
    __syncthreads();
    int i = blockIdx.x * 256 + threadIdx.x;
    int t = 0, off = 0;
    if (i < N_NODES) {
        t = ntype[i];
        off = atomicAdd(&lcnt[t], 1);
    }
    __syncthreads();
    if (threadIdx.x < TN)
        lbase[threadIdx.x] = atomicAdd(&cursor[threadIdx.x], lcnt[threadIdx.x]);
    __syncthreads();
    if (i < N_NODES) perm[lbase[t] + off] = i;
}

// ---------- edge CSR build (sort by dst) ----------
__global__ void hist_dst_kernel(const int* __restrict__ dst, int* __restrict__ cnt) {
    int e = blockIdx.x * 256 + threadIdx.x;
    if (e < N_EDGES) atomicAdd(&cnt[dst[e]], 1);
}
__global__ void scan_block_kernel(const int* __restrict__ cnt, int* __restrict__ excl,
                                  int* __restrict__ bsum) {
    __shared__ int s[256];
    int tid = threadIdx.x;
    int i = blockIdx.x * 256 + tid;
    int v = (i < N_NODES) ? cnt[i] : 0;
    s[tid] = v;
    __syncthreads();
    for (int off = 1; off < 256; off <<= 1) {
        int t = (tid >= off) ? s[tid - off] : 0;
        __syncthreads();
        s[tid] += t;
        __syncthreads();
    }
    if (i < N_NODES) excl[i] = s[tid] - v;
    if (tid == 255) bsum[blockIdx.x] = s[255];
}
__global__ void scan_top_kernel(int* __restrict__ bsum) {
    __shared__ int s[256];
    int tid = threadIdx.x;
    int v = (tid < SCAN_BLKS) ? bsum[tid] : 0;
    s[tid] = v;
    __syncthreads();
    for (int off = 1; off < 256; off <<= 1) {
        int t = (tid >= off) ? s[tid - off] : 0;
        __syncthreads();
        s[tid] += t;
        __syncthreads();
    }
    if (tid < SCAN_BLKS) bsum[tid] = s[tid] - v;   // exclusive
}
__global__ void scan_add_kernel(int* __restrict__ excl, const int* __restrict__ bsum,
                                int* __restrict__ cursor) {
    int i = blockIdx.x * 256 + threadIdx.x;
    if (i < N_NODES) {
        int v = excl[i] + bsum[blockIdx.x];
        excl[i] = v;        // becomes row_ptr
        cursor[i] = v;
    }
}
// pass 1: place edges at CSR positions (by dst)
__global__ void csr_scatter_kernel(const int* __restrict__ src, const int* __restrict__ dst,
                                   const int* __restrict__ etype, int* __restrict__ cur_dst,
                                   int* __restrict__ csr_sd, int* __restrict__ csr_et) {
    int e = blockIdx.x * 256 + threadIdx.x;
    if (e < N_EDGES) {
        int p = atomicAdd(&cur_dst[dst[e]], 1);
        csr_sd[p] = src[e] | (dst[e] << 16);
        csr_et[p] = etype[e];
    }
}

// ---------- relation sort (CSR-ordered within segments) ----------
__global__ void ehist_kernel(const int* __restrict__ etype, int* __restrict__ ecnt) {
    __shared__ int l[NR];
    if (threadIdx.x < NR) l[threadIdx.x] = 0;
    __syncthreads();
    int e = blockIdx.x * 256 + threadIdx.x;
    if (e < N_EDGES) atomicAdd(&l[etype[e]], 1);
    __syncthreads();
    if (threadIdx.x < NR) atomicAdd(&ecnt[threadIdx.x], l[threadIdx.x]);
}
__global__ void escan_kernel(const int* __restrict__ ecnt, int* __restrict__ rbase,
                             int* __restrict__ rcur) {
    if (threadIdx.x == 0 && blockIdx.x == 0) {
        int acc = 0;
        for (int r = 0; r < NR; ++r) {
            rbase[r] = acc; rcur[r] = acc;
            acc += ((ecnt[r] + 15) / 16) * 16;
        }
        rbase[NR] = acc;
    }
}
__global__ void rinit_kernel(int* __restrict__ rsd, int* __restrict__ rpos) {
    int i = blockIdx.x * 256 + threadIdx.x;
    if (i < RL_CAP) { rsd[i] = 0; rpos[i] = N_EDGES; }   // sentinel -> scratch row E
}
// pass 2: walk CSR positions in order, append to relation segments
__global__ void rel_scatter_kernel(const int* __restrict__ csr_sd, const int* __restrict__ csr_et,
                                   int* __restrict__ rcur, int* __restrict__ rsd,
                                   int* __restrict__ rpos) {
    __shared__ int lcnt[NR], lbase[NR];
    if (threadIdx.x < NR) lcnt[threadIdx.x] = 0;
    __syncthreads();
    int p = blockIdx.x * 256 + threadIdx.x;
    int r = 0, off = 0;
    if (p < N_EDGES) {
        r = csr_et[p];
        off = atomicAdd(&lcnt[r], 1);
    }
    __syncthreads();
    if (threadIdx.x < NR) lbase[threadIdx.x] = atomicAdd(&rcur[threadIdx.x], lcnt[threadIdx.x]);
    __syncthreads();
    if (p < N_EDGES) {
        int rp = lbase[r] + off;
        rsd[rp] = csr_sd[p];
        rpos[rp] = p;
    }
}

// ---------- weight converts ----------
__global__ void wconv_kernel(const float* __restrict__ W, unsigned short* __restrict__ out) {
    int mat = blockIdx.x >> 3, seg = blockIdx.x & 7;
    const float* w = W + (size_t)mat * HID * HID;
    unsigned short* o = out + (size_t)mat * HID * HID;
#pragma unroll
    for (int c = 0; c < 8; ++c) {
        int idx = seg * 2048 + c * 256 + threadIdx.x;
        int i = idx >> 7, j = idx & 127;
        o[j * HID + i] = f2bf(w[idx]);
    }
}
__global__ void wsmall_conv(const float* __restrict__ W, const float* __restrict__ pri,
                            unsigned short* __restrict__ out) {
    int blk = blockIdx.x;                 // l*64 + h*8 + r
    int tid = threadIdx.x;                // 256 = 16x16
    int i = tid >> 4, o = tid & 15;
    float s = pri ? pri[blk] * 0.25f : 1.f;
    out[blk * 256 + o * 16 + i] = f2bf(W[blk * 256 + i * 16 + o] * s);
}

// ---------- MFMA typed GEMM: 32 nodes x 128 outs; K,Q,V all bf16 ----------
__global__ __launch_bounds__(256) void gemm3_mfma(
    const float* __restrict__ x, const int* __restrict__ perm, const int* __restrict__ ntype,
    const unsigned short* __restrict__ WkT, const unsigned short* __restrict__ WqT,
    const unsigned short* __restrict__ WvT,
    unsigned short* __restrict__ Kb, unsigned short* __restrict__ Qb,
    unsigned short* __restrict__ Vb) {
    __shared__ unsigned short xs[TILE][HID + 8];
    __shared__ int nodes[TILE];
    int tid = threadIdx.x;
    if (tid < TILE) nodes[tid] = perm[blockIdx.x * TILE + tid];
    __syncthreads();
    if (nodes[0] < 0) return;
    int t = ntype[nodes[0]];
#pragma unroll
    for (int c = 0; c < 4; ++c) {
        int v = tid + c * 256;
        int ns = v >> 5, ii = (v & 31) * 4;
        int node = nodes[ns];
        float4 val = (node >= 0) ? *(const float4*)(x + (size_t)node * HID + ii)
                                 : make_float4(0.f, 0.f, 0.f, 0.f);
        uint2 pk;
        pk.x = (unsigned)f2bf(val.x) | ((unsigned)f2bf(val.y) << 16);
        pk.y = (unsigned)f2bf(val.z) | ((unsigned)f2bf(val.w) << 16);
        *(uint2*)&xs[ns][ii] = pk;
    }
    __syncthreads();
    int wv = tid >> 6, lane = tid & 63;
    int lrow = lane & 15, lk = lane >> 4;
    bf16x8 af[2][4];
#pragma unroll
    for (int rt = 0; rt < 2; ++rt)
#pragma unroll
        for (int kk = 0; kk < 4; ++kk)
            af[rt][kk] = *(const bf16x8*)&xs[rt * 16 + lrow][kk * 32 + lk * 8];
    size_t woff = (size_t)t * HID * HID + (size_t)lrow * HID + lk * 8;
#pragma unroll
    for (int pp = 0; pp < 6; ++pp) {
        int p = wv * 6 + pp;
        int mat = p >> 3, ct = p & 7;
        const unsigned short* wb =
            (mat == 0 ? WkT : (mat == 1 ? WqT : WvT)) + woff + (size_t)ct * 16 * HID;
        unsigned short* ob = (mat == 0) ? Kb : (mat == 1 ? Qb : Vb);
        f32x4 a0 = {0.f, 0.f, 0.f, 0.f}, a1 = {0.f, 0.f, 0.f, 0.f};
#pragma unroll
        for (int kk = 0; kk < 4; ++kk) {
            bf16x8 bfr = *(const bf16x8*)(wb + kk * 32);
            a0 = __builtin_amdgcn_mfma_f32_16x16x32_bf16(af[0][kk], bfr, a0, 0, 0, 0);
            a1 = __builtin_amdgcn_mfma_f32_16x16x32_bf16(af[1][kk], bfr, a1, 0, 0, 0);
        }
        int col = ct * 16 + lrow;
#pragma unroll
        for (int q = 0; q < 4; ++q) {
            int r0 = lk * 4 + q;
            int n0 = nodes[r0], n1 = nodes[16 + r0];
            if (n0 >= 0) ob[(size_t)n0 * HID + col] = f2bf(a0[q]);
            if (n1 >= 0) ob[(size_t)n1 * HID + col] = f2bf(a1[q]);
        }
    }
}

// ---------- MFMA GEMM (plain, fp32 in, fp32 out, +bias) for final FF ----------
__global__ __launch_bounds__(256) void gemm1_mfma(
    const float* __restrict__ x, const int* __restrict__ perm, const int* __restrict__ ntype,
    const unsigned short* __restrict__ Wt, const float* __restrict__ bias,
    float* __restrict__ out) {
    __shared__ unsigned short xs[TILE][HID + 8];
    __shared__ int nodes[TILE];
    int tid = threadIdx.x;
    if (tid < TILE) {
        int n;
        if (perm) n = perm[blockIdx.x * TILE + tid];
        else { n = blockIdx.x * TILE + tid; if (n >= N_NODES) n = -1; }
        nodes[tid] = n;
    }
    __syncthreads();
    if (nodes[0] < 0) return;
    int t = perm ? ntype[nodes[0]] : 0;
#pragma unroll
    for (int c = 0; c < 4; ++c) {
        int v = tid + c * 256;
        int ns = v >> 5, ii = (v & 31) * 4;
        int node = nodes[ns];
        float4 val = (node >= 0) ? *(const float4*)(x + (size_t)node * HID + ii)
                                 : make_float4(0.f, 0.f, 0.f, 0.f);
        uint2 pk;
        pk.x = (unsigned)f2bf(val.x) | ((unsigned)f2bf(val.y) << 16);
        pk.y = (unsigned)f2bf(val.z) | ((unsigned)f2bf(val.w) << 16);
        *(uint2*)&xs[ns][ii] = pk;
    }
    __syncthreads();
    int wv = tid >> 6, lane = tid & 63;
    int lrow = lane & 15, lk = lane >> 4;
    bf16x8 af[2][4];
#pragma unroll
    for (int rt = 0; rt < 2; ++rt)
#pragma unroll
        for (int kk = 0; kk < 4; ++kk)
            af[rt][kk] = *(const bf16x8*)&xs[rt * 16 + lrow][kk * 32 + lk * 8];
    const unsigned short* wb0 = Wt + (size_t)t * HID * HID + (size_t)lrow * HID + lk * 8;
#pragma unroll
    for (int pp = 0; pp < 2; ++pp) {
        int ct = wv * 2 + pp;
        const unsigned short* wb = wb0 + (size_t)ct * 16 * HID;
        f32x4 a0 = {0.f, 0.f, 0.f, 0.f}, a1 = {0.f, 0.f, 0.f, 0.f};
#pragma unroll
        for (int kk = 0; kk < 4; ++kk) {
            bf16x8 bfr = *(const bf16x8*)(wb + kk * 32);
            a0 = __builtin_amdgcn_mfma_f32_16x16x32_bf16(af[0][kk], bfr, a0, 0, 0, 0);
            a1 = __builtin_amdgcn_mfma_f32_16x16x32_bf16(af[1][kk], bfr, a1, 0, 0, 0);
        }
        float bv = bias ? bias[ct * 16 + lrow] : 0.f;
#pragma unroll
        for (int q = 0; q < 4; ++q) {
            int r0 = lk * 4 + q;
            int n0 = nodes[r0], n1 = nodes[16 + r0];
            if (n0 >= 0) out[(size_t)n0 * HID + ct * 16 + lrow] = a0[q] + bv;
            if (n1 >= 0) out[(size_t)n1 * HID + ct * 16 + lrow] = a1[q] + bv;
        }
    }
}

// ---------- MFMA typed GEMM (bf16 agg in) + SiLU + gated residual + LayerNorm ----------
__global__ __launch_bounds__(256) void gemm1_ln_mfma(
    const unsigned short* __restrict__ aggb, const int* __restrict__ perm,
    const int* __restrict__ ntype, const unsigned short* __restrict__ Wt,
    const float* __restrict__ xin, const float* __restrict__ skip,
    const float* __restrict__ g, const float* __restrict__ b, float* __restrict__ xout) {
    __shared__ unsigned short xs[TILE][HID + 8];
    __shared__ int nodes[TILE];
    __shared__ float psum[TILE][4], psq[TILE][4];
    __shared__ float mu_s[TILE], rv_s[TILE];
    int tid = threadIdx.x;
    if (tid < TILE) nodes[tid] = perm[blockIdx.x * TILE + tid];
    __syncthreads();
    if (nodes[0] < 0) return;
    int t = ntype[nodes[0]];
#pragma unroll
    for (int c = 0; c < 4; ++c) {
        int v = tid + c * 256;
        int ns = v >> 5, ii = (v & 31) * 4;
        int node = nodes[ns];
        uint2 pk = make_uint2(0u, 0u);
        if (node >= 0) pk = *(const uint2*)(aggb + (size_t)node * HID + ii);
        *(uint2*)&xs[ns][ii] = pk;
    }
    __syncthreads();
    int wv = tid >> 6, lane = tid & 63;
    int lrow = lane & 15, lk = lane >> 4;
    bf16x8 af[2][4];
#pragma unroll
    for (int rt = 0; rt < 2; ++rt)
#pragma unroll
        for (int kk = 0; kk < 4; ++kk)
            af[rt][kk] = *(const bf16x8*)&xs[rt * 16 + lrow][kk * 32 + lk * 8];
    const unsigned short* wb0 = Wt + (size_t)t * HID * HID + (size_t)lrow * HID + lk * 8;
    float al = 1.f / (1.f + __expf(-skip[t]));
    float om = 1.f - al;
    float ov[2][2][4];   // [pp][half][q]
#pragma unroll
    for (int pp = 0; pp < 2; ++pp) {
        int ct = wv * 2 + pp;
        const unsigned short* wb = wb0 + (size_t)ct * 16 * HID;
        f32x4 a0 = {0.f, 0.f, 0.f, 0.f}, a1 = {0.f, 0.f, 0.f, 0.f};
#pragma unroll
        for (int kk = 0; kk < 4; ++kk) {
            bf16x8 bfr = *(const bf16x8*)(wb + kk * 32);
            a0 = __builtin_amdgcn_mfma_f32_16x16x32_bf16(af[0][kk], bfr, a0, 0, 0, 0);
            a1 = __builtin_amdgcn_mfma_f32_16x16x32_bf16(af[1][kk], bfr, a1, 0, 0, 0);
        }
        int col = ct * 16 + lrow;
#pragma unroll
        for (int q = 0; q < 4; ++q) {
            int n0 = nodes[lk * 4 + q], n1 = nodes[16 + lk * 4 + q];
            float s0 = a0[q] / (1.f + __expf(-a0[q]));
            float s1 = a1[q] / (1.f + __expf(-a1[q]));
            float x0 = (n0 >= 0) ? xin[(size_t)n0 * HID + col] : 0.f;
            float x1 = (n1 >= 0) ? xin[(size_t)n1 * HID + col] : 0.f;
            ov[pp][0][q] = s0 * al + x0 * om;
            ov[pp][1][q] = s1 * al + x1 * om;
        }
    }
#pragma unroll
    for (int half = 0; half < 2; ++half)
#pragma unroll
        for (int q = 0; q < 4; ++q) {
            float s = ov[0][half][q] + ov[1][half][q];
            float s2 = ov[0][half][q] * ov[0][half][q] + ov[1][half][q] * ov[1][half][q];
            s += __shfl_xor(s, 1); s += __shfl_xor(s, 2);
            s += __shfl_xor(s, 4); s += __shfl_xor(s, 8);
            s2 += __shfl_xor(s2, 1); s2 += __shfl_xor(s2, 2);
            s2 += __shfl_xor(s2, 4); s2 += __shfl_xor(s2, 8);
            if (lrow == 0) {
                int nd = half * 16 + lk * 4 + q;
                psum[nd][wv] = s;
                psq[nd][wv] = s2;
            }
        }
    __syncthreads();
    if (tid < TILE) {
        float s = psum[tid][0] + psum[tid][1] + psum[tid][2] + psum[tid][3];
        float s2 = psq[tid][0] + psq[tid][1] + psq[tid][2] + psq[tid][3];
        float mu = s * (1.f / HID);
        float var = s2 * (1.f / HID) - mu * mu;
        mu_s[tid] = mu;
        rv_s[tid] = rsqrtf(fmaxf(var, 0.f) + 1e-5f);
    }
    __syncthreads();
#pragma unroll
    for (int pp = 0; pp < 2; ++pp) {
        int col = (wv * 2 + pp) * 16 + lrow;
        float gg = g[col], bb = b[col];
#pragma unroll
        for (int q = 0; q < 4; ++q) {
            int i0 = lk * 4 + q, i1 = 16 + lk * 4 + q;
            int n0 = nodes[i0], n1 = nodes[i1];
            if (n0 >= 0) xout[(size_t)n0 * HID + col] = (ov[pp][0][q] - mu_s[i0]) * rv_s[i0] * gg + bb;
            if (n1 >= 0) xout[(size_t)n1 * HID + col] = (ov[pp][1][q] - mu_s[i1]) * rv_s[i1] * gg + bb;
        }
    }
}

// ---------- edge transform: LDS-staged full-line writeout ----------
__global__ __launch_bounds__(512) void transform_kernel(
    const unsigned short* __restrict__ Kb, const unsigned short* __restrict__ Vb,
    const unsigned short* __restrict__ Qb,
    const int* __restrict__ rsd, const int* __restrict__ rpos, const int* __restrict__ rbase,
    const unsigned short* __restrict__ WattT, const unsigned short* __restrict__ WmsgT,
    float* __restrict__ scores, unsigned short* __restrict__ mg) {
    __shared__ unsigned short smg[8][16][136];   // 272 B row pitch (16B-aligned)
    __shared__ float ssc[8][16][8];
    int wv = threadIdx.x >> 6;                   // wave = relation
    int r = wv;
    int lane = threadIdx.x & 63;
    int ecol = lane & 15, lk = lane >> 4;
    int tbeg = rbase[r] + blockIdx.x * 16;
    if (tbeg >= rbase[r + 1]) return;            // wave-uniform exit
    int entry = tbeg + ecol;
    int sd = rsd[entry];
    int s = sd & 0xFFFF, dd = (sd >> 16) & 0xFFFF;
    int p = rpos[entry];

    const bf16x8 zz = {0, 0, 0, 0, 0, 0, 0, 0};
#pragma unroll
    for (int h = 0; h < NH; ++h) {
        bf16x8 bk = zz, bv = zz, aa = zz, am = zz;
        if (lk < 2) {
            bk = *(const bf16x8*)(Kb + (size_t)s * HID + h * HS + lk * 8);
            bv = *(const bf16x8*)(Vb + (size_t)s * HID + h * HS + lk * 8);
            int wo = ((h * NR + r) * 16 + ecol) * 16 + lk * 8;
            aa = *(const bf16x8*)(WattT + wo);
            am = *(const bf16x8*)(WmsgT + wo);
        }
        f32x4 ck = {0.f, 0.f, 0.f, 0.f}, cm = {0.f, 0.f, 0.f, 0.f};
        ck = __builtin_amdgcn_mfma_f32_16x16x32_bf16(aa, bk, ck, 0, 0, 0);
        cm = __builtin_amdgcn_mfma_f32_16x16x32_bf16(am, bv, cm, 0, 0, 0);
        uint2 qraw = *(const uint2*)(Qb + (size_t)dd * HID + h * HS + lk * 4);
        float q0 = __uint_as_float(qraw.x << 16);
        float q1 = __uint_as_float(qraw.x & 0xffff0000u);
        float q2 = __uint_as_float(qraw.y << 16);
        float q3 = __uint_as_float(qraw.y & 0xffff0000u);
        float xsc = ck[0] * q0 + ck[1] * q1 + ck[2] * q2 + ck[3] * q3;
        xsc += __shfl_xor(xsc, 16);
        xsc += __shfl_xor(xsc, 32);
        if (lk == 0) ssc[wv][ecol][h] = xsc;
        uint2 pk2;
        pk2.x = (unsigned)f2bf(cm[0]) | ((unsigned)f2bf(cm[1]) << 16);
        pk2.y = (unsigned)f2bf(cm[2]) | ((unsigned)f2bf(cm[3]) << 16);
        *(uint2*)&smg[wv][ecol][h * 16 + lk * 4] = pk2;
    }
    // mg writeout: 32 lines (16 edges x 2), each 128 B line by 8 lanes x 16 B in ONE instr
    int gq = lane >> 3, sub = lane & 7;
#pragma unroll
    for (int c = 0; c < 4; ++c) {
        int li = c * 8 + gq;                 // line index 0..31
        int e = li >> 1, half = li & 1;
        int pe = __shfl(p, e);               // p for edge e (lane e holds it)
        uint4 v = *(const uint4*)&smg[wv][e][half * 64 + sub * 8];
        *(uint4*)(mg + (size_t)pe * HID + half * 64 + sub * 8) = v;
    }
    // scores writeout: 16 edges x 32 B, 2 lanes x 16 B each
    int es = lane >> 1;
    int pe2 = __shfl(p, es & 15);
    if (lane < 32) {
        int hh = lane & 1;
        float4 v = *(const float4*)&ssc[wv][es][hh * 4];
        *(float4*)(scores + (size_t)pe2 * NH + hh * 4) = v;
    }
}

// ---------- edge softmax: one wave per dst node, all 8 heads, lane-local online state ----------
// lane = h*8 + j : head h, dim-pair (2j, 2j+1). Zero shuffles; coalesced 256 B mg loads.
__global__ __launch_bounds__(256) void edge_soft_kernel(
    const float* __restrict__ scores, const unsigned short* __restrict__ mg,
    const int* __restrict__ row_ptr, const int* __restrict__ deg,
    unsigned short* __restrict__ aggb) {
    int d = blockIdx.x * 4 + (threadIdx.x >> 6);
    if (d >= N_NODES) return;
    int lane = threadIdx.x & 63;
    int h = lane >> 3, j = lane & 7;
    int beg = row_ptr[d], dg = deg[d];

    const float* sc = scores + (size_t)beg * NH + h;
    const unsigned short* mgp = mg + (size_t)beg * HID + h * HS + j * 2;

    float m = -INFINITY, den = 0.f, a0 = 0.f, a1 = 0.f;
    for (int e = 0; e < dg; ++e) {
        float a = sc[(size_t)e * NH];
        unsigned mgu = *(const unsigned*)(mgp + (size_t)e * HID);
        float g0 = __uint_as_float(mgu << 16);
        float g1 = __uint_as_float(mgu & 0xffff0000u);
        float mn = fmaxf(m, a);
        float scale = __expf(m - mn);          // 0 on first iter (m = -inf)
        float ex = __expf(a - mn);
        den = den * scale + ex;
        a0 = a0 * scale + ex * g0;
        a1 = a1 * scale + ex * g1;
        m = mn;
    }
    float inv = 1.f / (den + 1e-16f);
    unsigned r0 = (unsigned)f2bf(a0 * inv);
    unsigned r1 = (unsigned)f2bf(a1 * inv);
    *(unsigned*)(aggb + (size_t)d * HID + h * HS + j * 2) = r0 | (r1 << 16);
}

extern "C" void kernel_launch(void* const* d_in, const int* in_sizes, int n_in,
                              void* d_out, int out_size, void* d_ws, size_t ws_size,
                              hipStream_t stream) {
    const float* x     = (const float*)d_in[0];
    const int*   eidx  = (const int*)d_in[1];
    const int*   ntype = (const int*)d_in[2];
    const int*   etype = (const int*)d_in[3];
    const float* Wk    = (const float*)d_in[4];
    const float* Wq    = (const float*)d_in[5];
    const float* Wv    = (const float*)d_in[6];
    const float* Wa    = (const float*)d_in[7];
    const float* pri   = (const float*)d_in[8];
    const float* Watt  = (const float*)d_in[9];
    const float* Wmsg  = (const float*)d_in[10];
    const float* skip  = (const float*)d_in[11];
    const float* ln_g  = (const float*)d_in[12];
    const float* ln_b  = (const float*)d_in[13];
    const float* Wff   = (const float*)d_in[14];
    const float* bff   = (const float*)d_in[15];
    const int* src = eidx;
    const int* dst = eidx + N_EDGES;

    char* ws = (char*)d_ws;
    size_t szN = (size_t)N_NODES * HID * sizeof(float);        // 25.6 MB
    float* embA = (float*)(ws);                                // layer-0 out
    unsigned short* AGGb = (unsigned short*)(ws + szN);        // bf16 agg (12.8 MB)
    char*  kvq  = ws + 2 * szN;
    unsigned short* Kbf = (unsigned short*)kvq;                // 12.8 MB each
    unsigned short* Vbf = (unsigned short*)(kvq + (size_t)N_NODES * HID * 2);
    unsigned short* Qbf = (unsigned short*)(kvq + 2 * (size_t)N_NODES * HID * 2);
    float* l1out = (float*)kvq;                                // aliases K+V (dead by then)
    char*  p    = kvq + 3 * (size_t)N_NODES * HID * 2;
    int* perm    = (int*)p;  p += (size_t)PERM_SZ * 4;
    int* cnt     = (int*)p;  p += TN * 4;
    int* cursor  = (int*)p;  p += TN * 4;
    int* row_ptr = (int*)p;  p += (size_t)N_NODES * 4;
    int* cnt_dst = (int*)p;  p += (size_t)N_NODES * 4;
    int* cur_dst = (int*)p;  p += (size_t)N_NODES * 4;
    int* bsum    = (int*)p;  p += 256 * 4;
    int* ecnt    = (int*)p;  p += NR * 4;
    int* rbase   = (int*)p;  p += (NR + 1) * 4;
    int* rcur    = (int*)p;  p += NR * 4;
    int* csr_sd  = (int*)p;  p += (size_t)N_EDGES * 4;
    int* csr_et  = (int*)p;  p += (size_t)N_EDGES * 4;
    int* rsd     = (int*)p;  p += (size_t)RL_CAP * 4;
    int* rpos    = (int*)p;  p += (size_t)RL_CAP * 4;
    size_t wmat = (size_t)HID * HID;
    unsigned short* WkT  = (unsigned short*)p;  p += 2 * TN * wmat * 2;
    unsigned short* WqT  = (unsigned short*)p;  p += 2 * TN * wmat * 2;
    unsigned short* WvT  = (unsigned short*)p;  p += 2 * TN * wmat * 2;
    unsigned short* WaT  = (unsigned short*)p;  p += 2 * TN * wmat * 2;
    unsigned short* WffT = (unsigned short*)p;  p += wmat * 2;
    unsigned short* WattT = (unsigned short*)p; p += 2 * 64 * 256 * 2;
    unsigned short* WmsgT = (unsigned short*)p; p += 2 * 64 * 256 * 2;
    p = (char*)(((size_t)p + 255) & ~(size_t)255);
    float* scores = (float*)p;          p += (size_t)(N_EDGES + 16) * NH * 4;   // 12.8 MB
    unsigned short* mg = (unsigned short*)p;  p += (size_t)(N_EDGES + 16) * HID * 2; // 102.4 MB

    // weight conversion (once per launch)
    wconv_kernel<<<2 * TN * 8, 256, 0, stream>>>(Wk, WkT);
    wconv_kernel<<<2 * TN * 8, 256, 0, stream>>>(Wq, WqT);
    wconv_kernel<<<2 * TN * 8, 256, 0, stream>>>(Wv, WvT);
    wconv_kernel<<<2 * TN * 8, 256, 0, stream>>>(Wa, WaT);
    wconv_kernel<<<8, 256, 0, stream>>>(Wff, WffT);
    wsmall_conv<<<128, 256, 0, stream>>>(Watt, pri, WattT);     // pri/4 baked in
    wsmall_conv<<<128, 256, 0, stream>>>(Wmsg, nullptr, WmsgT);

    // node type sort (once)
    hipMemsetAsync(cnt, 0, TN * 4, stream);
    hipMemsetAsync(perm, 0xFF, (size_t)PERM_SZ * 4, stream);
    hist_kernel<<<(N_NODES + 255) / 256, 256, 0, stream>>>(ntype, cnt);
    scan_kernel<<<1, 64, 0, stream>>>(cnt, cursor);
    scatter_kernel<<<(N_NODES + 255) / 256, 256, 0, stream>>>(ntype, cursor, perm);

    // edge CSR by dst, then CSR-ordered relation segments (once)
    hipMemsetAsync(cnt_dst, 0, (size_t)N_NODES * 4, stream);
    hipMemsetAsync(ecnt, 0, NR * 4, stream);
    hist_dst_kernel<<<(N_EDGES + 255) / 256, 256, 0, stream>>>(dst, cnt_dst);
    ehist_kernel<<<(N_EDGES + 255) / 256, 256, 0, stream>>>(etype, ecnt);
    scan_block_kernel<<<SCAN_BLKS, 256, 0, stream>>>(cnt_dst, row_ptr, bsum);
    scan_top_kernel<<<1, 256, 0, stream>>>(bsum);
    scan_add_kernel<<<SCAN_BLKS, 256, 0, stream>>>(row_ptr, bsum, cur_dst);
    csr_scatter_kernel<<<(N_EDGES + 255) / 256, 256, 0, stream>>>(src, dst, etype, cur_dst,
                                                                  csr_sd, csr_et);
    escan_kernel<<<1, 64, 0, stream>>>(ecnt, rbase, rcur);
    rinit_kernel<<<(RL_CAP + 255) / 256, 256, 0, stream>>>(rsd, rpos);
    rel_scatter_kernel<<<(N_EDGES + 255) / 256, 256, 0, stream>>>(csr_sd, csr_et, rcur,
                                                                  rsd, rpos);

    for (int l = 0; l < 2; ++l) {
        const float* xin = l ? embA : x;
        float* xout = l ? l1out : embA;
        const float* skip_l = skip + (size_t)l * TN;
        const float* g_l    = ln_g + (size_t)l * HID;
        const float* b_l    = ln_b + (size_t)l * HID;
        const unsigned short* WkT_l = WkT + (size_t)l * TN * wmat;
        const unsigned short* WqT_l = WqT + (size_t)l * TN * wmat;
        const unsigned short* WvT_l = WvT + (size_t)l * TN * wmat;
        const unsigned short* WaT_l = WaT + (size_t)l * TN * wmat;
        const unsigned short* WattT_l = WattT + (size_t)l * 64 * 256;
        const unsigned short* WmsgT_l = WmsgT + (size_t)l * 64 * 256;

        gemm3_mfma<<<MAXTILES, 256, 0, stream>>>(xin, perm, ntype, WkT_l, WqT_l, WvT_l,
                                                 Kbf, Qbf, Vbf);
        transform_kernel<<<T_GRID, 512, 0, stream>>>(Kbf, Vbf, Qbf, rsd, rpos, rbase,
                                                     WattT_l, WmsgT_l, scores, mg);
        edge_soft_kernel<<<(N_NODES + 3) / 4, 256, 0, stream>>>(scores, mg, row_ptr, cnt_dst,
                                                                AGGb);
        // Wa typed GEMM + SiLU + gated residual + LayerNorm (fused, bf16 agg in)
        gemm1_ln_mfma<<<MAXTILES, 256, 0, stream>>>(AGGb, perm, ntype, WaT_l, xin,
                                                    skip_l, g_l, b_l, xout);
    }
    // final FF: l1out @ Wff + bff -> d_out
    gemm1_mfma<<<(N_NODES + TILE - 1) / TILE, 256, 0, stream>>>(l1out, nullptr, ntype, WffT,
                                                                bff, (float*)d_out);
}

// Round 15
// 438.778 us; speedup vs baseline: 6.0782x; 1.1130x over previous
//
#include <hip/hip_runtime.h>
#include <hip/hip_bf16.h>
#include <math.h>

#define N_NODES 50000
#define N_EDGES 400000
#define HID 128
#define NH 8
#define HS 16
#define TN 8
#define NR 8
#define TILE 32
#define MAXTILES 1571
#define PERM_SZ (MAXTILES * TILE)
#define SCAN_BLKS ((N_NODES + 255) / 256)   // 196
#define NB 3125                              // dst windows of 16 nodes (exact)
#define TPBMAX 26                            // max 16-edge tiles per window
#define CAP 288                              // max edges per window (14 sigma)

typedef __attribute__((ext_vector_type(8))) short bf16x8;
typedef __attribute__((ext_vector_type(4))) float f32x4;

__device__ __forceinline__ unsigned short f2bf(float f) {
    __hip_bfloat16 h = __float2bfloat16(f);
    return *reinterpret_cast<unsigned short*>(&h);
}
__device__ __forceinline__ float bf2f(unsigned short u) {
    return __uint_as_float((unsigned)u << 16);
}

// ---------- node type sort (LDS-aggregated counting sort) ----------
__global__ void hist_kernel(const int* __restrict__ ntype, int* __restrict__ cnt) {
    __shared__ int l[TN];
    if (threadIdx.x < TN) l[threadIdx.x] = 0;
    __syncthreads();
    int i = blockIdx.x * 256 + threadIdx.x;
    if (i < N_NODES) atomicAdd(&l[ntype[i]], 1);
    __syncthreads();
    if (threadIdx.x < TN) atomicAdd(&cnt[threadIdx.x], l[threadIdx.x]);
}
__global__ void scan_kernel(const int* __restrict__ cnt, int* __restrict__ cursor) {
    if (threadIdx.x == 0 && blockIdx.x == 0) {
        int acc = 0;
        for (int t = 0; t < TN; ++t) {
            cursor[t] = acc;
            acc += ((cnt[t] + TILE - 1) / TILE) * TILE;
        }
    }
}
__global__ void scatter_kernel(const int* __restrict__ ntype, int* __restrict__ cursor,
                               int* __restrict__ perm) {
    __shared__ int lcnt[TN], lbase[TN];
    if (threadIdx.x < TN) lcnt[threadIdx.x] = 0;
    __syncthreads();
    int i = blockIdx.x * 256 + threadIdx.x;
    int t = 0, off = 0;
    if (i < N_NODES) {
        t = ntype[i];
        off = atomicAdd(&lcnt[t], 1);
    }
    __syncthreads();
    if (threadIdx.x < TN)
        lbase[threadIdx.x] = atomicAdd(&cursor[threadIdx.x], lcnt[threadIdx.x]);
    __syncthreads();
    if (i < N_NODES) perm[lbase[t] + off] = i;
}

// ---------- edge CSR build (sort by dst) ----------
__global__ void hist_dst_kernel(const int* __restrict__ dst, int* __restrict__ cnt) {
    int e = blockIdx.x * 256 + threadIdx.x;
    if (e < N_EDGES) atomicAdd(&cnt[dst[e]], 1);
}
__global__ void scan_block_kernel(const int* __restrict__ cnt, int* __restrict__ excl,
                                  int* __restrict__ bsum) {
    __shared__ int s[256];
    int tid = threadIdx.x;
    int i = blockIdx.x * 256 + tid;
    int v = (i < N_NODES) ? cnt[i] : 0;
    s[tid] = v;
    __syncthreads();
    for (int off = 1; off < 256; off <<= 1) {
        int t = (tid >= off) ? s[tid - off] : 0;
        __syncthreads();
        s[tid] += t;
        __syncthreads();
    }
    if (i < N_NODES) excl[i] = s[tid] - v;
    if (tid == 255) bsum[blockIdx.x] = s[255];
}
__global__ void scan_top_kernel(int* __restrict__ bsum) {
    __shared__ int s[256];
    int tid = threadIdx.x;
    int v = (tid < SCAN_BLKS) ? bsum[tid] : 0;
    s[tid] = v;
    __syncthreads();
    for (int off = 1; off < 256; off <<= 1) {
        int t = (tid >= off) ? s[tid - off] : 0;
        __syncthreads();
        s[tid] += t;
        __syncthreads();
    }
    if (tid < SCAN_BLKS) bsum[tid] = s[tid] - v;   // exclusive
}
__global__ void scan_add_kernel(int* __restrict__ excl, const int* __restrict__ bsum,
                                int* __restrict__ cursor) {
    int i = blockIdx.x * 256 + threadIdx.x;
    if (i < N_NODES) {
        int v = excl[i] + bsum[blockIdx.x];
        excl[i] = v;        // becomes row_ptr
        cursor[i] = v;
    }
}
// place edges at CSR positions (by dst)
__global__ void csr_scatter_kernel(const int* __restrict__ src, const int* __restrict__ dst,
                                   const int* __restrict__ etype, int* __restrict__ cur_dst,
                                   int* __restrict__ csr_sd, int* __restrict__ csr_et) {
    int e = blockIdx.x * 256 + threadIdx.x;
    if (e < N_EDGES) {
        int p = atomicAdd(&cur_dst[dst[e]], 1);
        csr_sd[p] = src[e] | (dst[e] << 16);
        csr_et[p] = etype[e];
    }
}

// ---------- per-window relation tile build (once) ----------
// block b = dst window [16b,16b+16); bucket its CSR edges by relation into
// padded 16-edge tiles. Lane r (<8) handles relation r serially.
__global__ void btile_build(const int* __restrict__ row_ptr,
                            const int* __restrict__ csr_sd, const int* __restrict__ csr_et,
                            int* __restrict__ btile_sd, int* __restrict__ btile_lp,
                            int* __restrict__ btile_r, int* __restrict__ ntb) {
    int b = blockIdx.x;
    int lane = threadIdx.x;              // 64 threads = 1 wave
    int p0 = row_ptr[b * 16];
    int p1 = (b == NB - 1) ? N_EDGES : row_ptr[b * 16 + 16];
    int cnt = 0;
    if (lane < 8) {
        for (int p = p0; p < p1; ++p) cnt += (csr_et[p] == lane);
    }
    int tiles = (cnt + 15) >> 4;
    int pre = 0, total = 0;
    for (int k = 0; k < 8; ++k) {
        int tk = __shfl(tiles, k);
        if (k < lane) pre += tk;
        total += tk;
    }
    if (lane == 0) ntb[b] = total;
    if (lane < 8) {
        int tbase = b * TPBMAX + pre;
        for (int t = 0; t < tiles; ++t) btile_r[tbase + t] = lane;
        int off = 0;
        for (int p = p0; p < p1; ++p) {
            if (csr_et[p] == lane) {
                int idx = (tbase + (off >> 4)) * 16 + (off & 15);
                btile_sd[idx] = csr_sd[p];
                btile_lp[idx] = p - p0;
                ++off;
            }
        }
        for (; off < tiles * 16; ++off) {
            int idx = (tbase + (off >> 4)) * 16 + (off & 15);
            btile_sd[idx] = 0;
            btile_lp[idx] = CAP;         // scratch slot
        }
    }
}

// ---------- weight converts ----------
__global__ void wconv_kernel(const float* __restrict__ W, unsigned short* __restrict__ out) {
    int mat = blockIdx.x >> 3, seg = blockIdx.x & 7;
    const float* w = W + (size_t)mat * HID * HID;
    unsigned short* o = out + (size_t)mat * HID * HID;
#pragma unroll
    for (int c = 0; c < 8; ++c) {
        int idx = seg * 2048 + c * 256 + threadIdx.x;
        int i = idx >> 7, j = idx & 127;
        o[j * HID + i] = f2bf(w[idx]);
    }
}
__global__ void wsmall_conv(const float* __restrict__ W, const float* __restrict__ pri,
                            unsigned short* __restrict__ out) {
    int blk = blockIdx.x;                 // l*64 + h*8 + r
    int tid = threadIdx.x;                // 256 = 16x16
    int i = tid >> 4, o = tid & 15;
    float s = pri ? pri[blk] * 0.25f : 1.f;
    out[blk * 256 + o * 16 + i] = f2bf(W[blk * 256 + i * 16 + o] * s);
}

// ---------- MFMA typed GEMM: 32 nodes x 128 outs; K,Q,V all bf16 ----------
__global__ __launch_bounds__(256) void gemm3_mfma(
    const float* __restrict__ x, const int* __restrict__ perm, const int* __restrict__ ntype,
    const unsigned short* __restrict__ WkT, const unsigned short* __restrict__ WqT,
    const unsigned short* __restrict__ WvT,
    unsigned short* __restrict__ Kb, unsigned short* __restrict__ Qb,
    unsigned short* __restrict__ Vb) {
    __shared__ unsigned short xs[TILE][HID + 8];
    __shared__ int nodes[TILE];
    int tid = threadIdx.x;
    if (tid < TILE) nodes[tid] = perm[blockIdx.x * TILE + tid];
    __syncthreads();
    if (nodes[0] < 0) return;
    int t = ntype[nodes[0]];
#pragma unroll
    for (int c = 0; c < 4; ++c) {
        int v = tid + c * 256;
        int ns = v >> 5, ii = (v & 31) * 4;
        int node = nodes[ns];
        float4 val = (node >= 0) ? *(const float4*)(x + (size_t)node * HID + ii)
                                 : make_float4(0.f, 0.f, 0.f, 0.f);
        uint2 pk;
        pk.x = (unsigned)f2bf(val.x) | ((unsigned)f2bf(val.y) << 16);
        pk.y = (unsigned)f2bf(val.z) | ((unsigned)f2bf(val.w) << 16);
        *(uint2*)&xs[ns][ii] = pk;
    }
    __syncthreads();
    int wv = tid >> 6, lane = tid & 63;
    int lrow = lane & 15, lk = lane >> 4;
    bf16x8 af[2][4];
#pragma unroll
    for (int rt = 0; rt < 2; ++rt)
#pragma unroll
        for (int kk = 0; kk < 4; ++kk)
            af[rt][kk] = *(const bf16x8*)&xs[rt * 16 + lrow][kk * 32 + lk * 8];
    size_t woff = (size_t)t * HID * HID + (size_t)lrow * HID + lk * 8;
#pragma unroll
    for (int pp = 0; pp < 6; ++pp) {
        int p = wv * 6 + pp;
        int mat = p >> 3, ct = p & 7;
        const unsigned short* wb =
            (mat == 0 ? WkT : (mat == 1 ? WqT : WvT)) + woff + (size_t)ct * 16 * HID;
        unsigned short* ob = (mat == 0) ? Kb : (mat == 1 ? Qb : Vb);
        f32x4 a0 = {0.f, 0.f, 0.f, 0.f}, a1 = {0.f, 0.f, 0.f, 0.f};
#pragma unroll
        for (int kk = 0; kk < 4; ++kk) {
            bf16x8 bfr = *(const bf16x8*)(wb + kk * 32);
            a0 = __builtin_amdgcn_mfma_f32_16x16x32_bf16(af[0][kk], bfr, a0, 0, 0, 0);
            a1 = __builtin_amdgcn_mfma_f32_16x16x32_bf16(af[1][kk], bfr, a1, 0, 0, 0);
        }
        int col = ct * 16 + lrow;
#pragma unroll
        for (int q = 0; q < 4; ++q) {
            int r0 = lk * 4 + q;
            int n0 = nodes[r0], n1 = nodes[16 + r0];
            if (n0 >= 0) ob[(size_t)n0 * HID + col] = f2bf(a0[q]);
            if (n1 >= 0) ob[(size_t)n1 * HID + col] = f2bf(a1[q]);
        }
    }
}

// ---------- MFMA GEMM (plain, fp32 in, fp32 out, +bias) for final FF ----------
__global__ __launch_bounds__(256) void gemm1_mfma(
    const float* __restrict__ x, const int* __restrict__ perm, const int* __restrict__ ntype,
    const unsigned short* __restrict__ Wt, const float* __restrict__ bias,
    float* __restrict__ out) {
    __shared__ unsigned short xs[TILE][HID + 8];
    __shared__ int nodes[TILE];
    int tid = threadIdx.x;
    if (tid < TILE) {
        int n;
        if (perm) n = perm[blockIdx.x * TILE + tid];
        else { n = blockIdx.x * TILE + tid; if (n >= N_NODES) n = -1; }
        nodes[tid] = n;
    }
    __syncthreads();
    if (nodes[0] < 0) return;
    int t = perm ? ntype[nodes[0]] : 0;
#pragma unroll
    for (int c = 0; c < 4; ++c) {
        int v = tid + c * 256;
        int ns = v >> 5, ii = (v & 31) * 4;
        int node = nodes[ns];
        float4 val = (node >= 0) ? *(const float4*)(x + (size_t)node * HID + ii)
                                 : make_float4(0.f, 0.f, 0.f, 0.f);
        uint2 pk;
        pk.x = (unsigned)f2bf(val.x) | ((unsigned)f2bf(val.y) << 16);
        pk.y = (unsigned)f2bf(val.z) | ((unsigned)f2bf(val.w) << 16);
        *(uint2*)&xs[ns][ii] = pk;
    }
    __syncthreads();
    int wv = tid >> 6, lane = tid & 63;
    int lrow = lane & 15, lk = lane >> 4;
    bf16x8 af[2][4];
#pragma unroll
    for (int rt = 0; rt < 2; ++rt)
#pragma unroll
        for (int kk = 0; kk < 4; ++kk)
            af[rt][kk] = *(const bf16x8*)&xs[rt * 16 + lrow][kk * 32 + lk * 8];
    const unsigned short* wb0 = Wt + (size_t)t * HID * HID + (size_t)lrow * HID + lk * 8;
#pragma unroll
    for (int pp = 0; pp < 2; ++pp) {
        int ct = wv * 2 + pp;
        const unsigned short* wb = wb0 + (size_t)ct * 16 * HID;
        f32x4 a0 = {0.f, 0.f, 0.f, 0.f}, a1 = {0.f, 0.f, 0.f, 0.f};
#pragma unroll
        for (int kk = 0; kk < 4; ++kk) {
            bf16x8 bfr = *(const bf16x8*)(wb + kk * 32);
            a0 = __builtin_amdgcn_mfma_f32_16x16x32_bf16(af[0][kk], bfr, a0, 0, 0, 0);
            a1 = __builtin_amdgcn_mfma_f32_16x16x32_bf16(af[1][kk], bfr, a1, 0, 0, 0);
        }
        float bv = bias ? bias[ct * 16 + lrow] : 0.f;
#pragma unroll
        for (int q = 0; q < 4; ++q) {
            int r0 = lk * 4 + q;
            int n0 = nodes[r0], n1 = nodes[16 + r0];
            if (n0 >= 0) out[(size_t)n0 * HID + ct * 16 + lrow] = a0[q] + bv;
            if (n1 >= 0) out[(size_t)n1 * HID + ct * 16 + lrow] = a1[q] + bv;
        }
    }
}

// ---------- MFMA typed GEMM (bf16 agg in) + SiLU + gated residual + LayerNorm ----------
__global__ __launch_bounds__(256) void gemm1_ln_mfma(
    const unsigned short* __restrict__ aggb, const int* __restrict__ perm,
    const int* __restrict__ ntype, const unsigned short* __restrict__ Wt,
    const float* __restrict__ xin, const float* __restrict__ skip,
    const float* __restrict__ g, const float* __restrict__ b, float* __restrict__ xout) {
    __shared__ unsigned short xs[TILE][HID + 8];
    __shared__ int nodes[TILE];
    __shared__ float psum[TILE][4], psq[TILE][4];
    __shared__ float mu_s[TILE], rv_s[TILE];
    int tid = threadIdx.x;
    if (tid < TILE) nodes[tid] = perm[blockIdx.x * TILE + tid];
    __syncthreads();
    if (nodes[0] < 0) return;
    int t = ntype[nodes[0]];
#pragma unroll
    for (int c = 0; c < 4; ++c) {
        int v = tid + c * 256;
        int ns = v >> 5, ii = (v & 31) * 4;
        int node = nodes[ns];
        uint2 pk = make_uint2(0u, 0u);
        if (node >= 0) pk = *(const uint2*)(aggb + (size_t)node * HID + ii);
        *(uint2*)&xs[ns][ii] = pk;
    }
    __syncthreads();
    int wv = tid >> 6, lane = tid & 63;
    int lrow = lane & 15, lk = lane >> 4;
    bf16x8 af[2][4];
#pragma unroll
    for (int rt = 0; rt < 2; ++rt)
#pragma unroll
        for (int kk = 0; kk < 4; ++kk)
            af[rt][kk] = *(const bf16x8*)&xs[rt * 16 + lrow][kk * 32 + lk * 8];
    const unsigned short* wb0 = Wt + (size_t)t * HID * HID + (size_t)lrow * HID + lk * 8;
    float al = 1.f / (1.f + __expf(-skip[t]));
    float om = 1.f - al;
    float ov[2][2][4];   // [pp][half][q]
#pragma unroll
    for (int pp = 0; pp < 2; ++pp) {
        int ct = wv * 2 + pp;
        const unsigned short* wb = wb0 + (size_t)ct * 16 * HID;
        f32x4 a0 = {0.f, 0.f, 0.f, 0.f}, a1 = {0.f, 0.f, 0.f, 0.f};
#pragma unroll
        for (int kk = 0; kk < 4; ++kk) {
            bf16x8 bfr = *(const bf16x8*)(wb + kk * 32);
            a0 = __builtin_amdgcn_mfma_f32_16x16x32_bf16(af[0][kk], bfr, a0, 0, 0, 0);
            a1 = __builtin_amdgcn_mfma_f32_16x16x32_bf16(af[1][kk], bfr, a1, 0, 0, 0);
        }
        int col = ct * 16 + lrow;
#pragma unroll
        for (int q = 0; q < 4; ++q) {
            int n0 = nodes[lk * 4 + q], n1 = nodes[16 + lk * 4 + q];
            float s0 = a0[q] / (1.f + __expf(-a0[q]));
            float s1 = a1[q] / (1.f + __expf(-a1[q]));
            float x0 = (n0 >= 0) ? xin[(size_t)n0 * HID + col] : 0.f;
            float x1 = (n1 >= 0) ? xin[(size_t)n1 * HID + col] : 0.f;
            ov[pp][0][q] = s0 * al + x0 * om;
            ov[pp][1][q] = s1 * al + x1 * om;
        }
    }
#pragma unroll
    for (int half = 0; half < 2; ++half)
#pragma unroll
        for (int q = 0; q < 4; ++q) {
            float s = ov[0][half][q] + ov[1][half][q];
            float s2 = ov[0][half][q] * ov[0][half][q] + ov[1][half][q] * ov[1][half][q];
            s += __shfl_xor(s, 1); s += __shfl_xor(s, 2);
            s += __shfl_xor(s, 4); s += __shfl_xor(s, 8);
            s2 += __shfl_xor(s2, 1); s2 += __shfl_xor(s2, 2);
            s2 += __shfl_xor(s2, 4); s2 += __shfl_xor(s2, 8);
            if (lrow == 0) {
                int nd = half * 16 + lk * 4 + q;
                psum[nd][wv] = s;
                psq[nd][wv] = s2;
            }
        }
    __syncthreads();
    if (tid < TILE) {
        float s = psum[tid][0] + psum[tid][1] + psum[tid][2] + psum[tid][3];
        float s2 = psq[tid][0] + psq[tid][1] + psq[tid][2] + psq[tid][3];
        float mu = s * (1.f / HID);
        float var = s2 * (1.f / HID) - mu * mu;
        mu_s[tid] = mu;
        rv_s[tid] = rsqrtf(fmaxf(var, 0.f) + 1e-5f);
    }
    __syncthreads();
#pragma unroll
    for (int pp = 0; pp < 2; ++pp) {
        int col = (wv * 2 + pp) * 16 + lrow;
        float gg = g[col], bb = b[col];
#pragma unroll
        for (int q = 0; q < 4; ++q) {
            int i0 = lk * 4 + q, i1 = 16 + lk * 4 + q;
            int n0 = nodes[i0], n1 = nodes[i1];
            if (n0 >= 0) xout[(size_t)n0 * HID + col] = (ov[pp][0][q] - mu_s[i0]) * rv_s[i0] * gg + bb;
            if (n1 >= 0) xout[(size_t)n1 * HID + col] = (ov[pp][1][q] - mu_s[i1]) * rv_s[i1] * gg + bb;
        }
    }
}

// ---------- fused attention: per dst-window transform (MFMA) + softmax, LDS intermediate ----------
// block b = dst window [16b,16b+16). Two passes of 4 heads.
// Phase 1: 8 waves process the window's relation tiles; scores/mg -> LDS at local CSR pos.
// Phase 2: wave w handles dst nodes 2w,2w+1; lane = h2*16+o lane-local online softmax.
__global__ __launch_bounds__(512) void fused_attn_kernel(
    const unsigned short* __restrict__ Kb, const unsigned short* __restrict__ Vb,
    const unsigned short* __restrict__ Qb,
    const int* __restrict__ row_ptr, const int* __restrict__ deg,
    const int* __restrict__ btile_sd, const int* __restrict__ btile_lp,
    const int* __restrict__ btile_r, const int* __restrict__ ntb,
    const unsigned short* __restrict__ WattT, const unsigned short* __restrict__ WmsgT,
    unsigned short* __restrict__ aggb) {
    __shared__ unsigned short smg[CAP + 1][72];   // 4 heads x 16 dims (+8 pad)
    __shared__ float ssc[CAP + 1][4];
    int b = blockIdx.x;
    int wv = threadIdx.x >> 6, lane = threadIdx.x & 63;
    int ecol = lane & 15, lk = lane >> 4;
    int nt = ntb[b];
    int p0 = row_ptr[b * 16];
    const bf16x8 zz = {0, 0, 0, 0, 0, 0, 0, 0};

#pragma unroll
    for (int pass = 0; pass < 2; ++pass) {
        int hbase = pass * 4;
        // ---- phase 1: relation tiles -> LDS scores/mg ----
        for (int t = wv; t < nt; t += 8) {
            int ti = b * TPBMAX + t;
            int r = btile_r[ti];
            int sd = btile_sd[ti * 16 + ecol];
            int lp = btile_lp[ti * 16 + ecol];
            int s = sd & 0xFFFF, dd = ((unsigned)sd >> 16);
#pragma unroll
            for (int hh = 0; hh < 4; ++hh) {
                int h = hbase + hh;
                bf16x8 bk = zz, bv = zz, aa = zz, am = zz;
                if (lk < 2) {
                    bk = *(const bf16x8*)(Kb + (size_t)s * HID + h * HS + lk * 8);
                    bv = *(const bf16x8*)(Vb + (size_t)s * HID + h * HS + lk * 8);
                    int wo = ((h * NR + r) * 16 + ecol) * 16 + lk * 8;
                    aa = *(const bf16x8*)(WattT + wo);
                    am = *(const bf16x8*)(WmsgT + wo);
                }
                f32x4 ck = {0.f, 0.f, 0.f, 0.f}, cm = {0.f, 0.f, 0.f, 0.f};
                ck = __builtin_amdgcn_mfma_f32_16x16x32_bf16(aa, bk, ck, 0, 0, 0);
                cm = __builtin_amdgcn_mfma_f32_16x16x32_bf16(am, bv, cm, 0, 0, 0);
                uint2 qraw = *(const uint2*)(Qb + (size_t)dd * HID + h * HS + lk * 4);
                float q0 = __uint_as_float(qraw.x << 16);
                float q1 = __uint_as_float(qraw.x & 0xffff0000u);
                float q2 = __uint_as_float(qraw.y << 16);
                float q3 = __uint_as_float(qraw.y & 0xffff0000u);
                float xsc = ck[0] * q0 + ck[1] * q1 + ck[2] * q2 + ck[3] * q3;
                xsc += __shfl_xor(xsc, 16);
                xsc += __shfl_xor(xsc, 32);
                if (lk == 0) ssc[lp][hh] = xsc;
                uint2 pk2;
                pk2.x = (unsigned)f2bf(cm[0]) | ((unsigned)f2bf(cm[1]) << 16);
                pk2.y = (unsigned)f2bf(cm[2]) | ((unsigned)f2bf(cm[3]) << 16);
                *(uint2*)&smg[lp][hh * 16 + lk * 4] = pk2;
            }
        }
        __syncthreads();
        // ---- phase 2: per-dst online softmax over LDS ----
        int h2 = lane >> 4, o = lane & 15;
#pragma unroll
        for (int i = 0; i < 2; ++i) {
            int d = b * 16 + wv * 2 + i;
            int lo = row_ptr[d] - p0;
            int dg = deg[d];
            float m = -INFINITY, den = 0.f, acc = 0.f;
            for (int e = 0; e < dg; ++e) {
                int lp = lo + e;
                float a = ssc[lp][h2];
                float gv = bf2f(smg[lp][h2 * 16 + o]);
                float mn = fmaxf(m, a);
                float scale = __expf(m - mn);
                float ex = __expf(a - mn);
                den = den * scale + ex;
                acc = acc * scale + ex * gv;
                m = mn;
            }
            aggb[(size_t)d * HID + (hbase + h2) * HS + o] = f2bf(acc / (den + 1e-16f));
        }
        __syncthreads();
    }
}

extern "C" void kernel_launch(void* const* d_in, const int* in_sizes, int n_in,
                              void* d_out, int out_size, void* d_ws, size_t ws_size,
                              hipStream_t stream) {
    const float* x     = (const float*)d_in[0];
    const int*   eidx  = (const int*)d_in[1];
    const int*   ntype = (const int*)d_in[2];
    const int*   etype = (const int*)d_in[3];
    const float* Wk    = (const float*)d_in[4];
    const float* Wq    = (const float*)d_in[5];
    const float* Wv    = (const float*)d_in[6];
    const float* Wa    = (const float*)d_in[7];
    const float* pri   = (const float*)d_in[8];
    const float* Watt  = (const float*)d_in[9];
    const float* Wmsg  = (const float*)d_in[10];
    const float* skip  = (const float*)d_in[11];
    const float* ln_g  = (const float*)d_in[12];
    const float* ln_b  = (const float*)d_in[13];
    const float* Wff   = (const float*)d_in[14];
    const float* bff   = (const float*)d_in[15];
    const int* src = eidx;
    const int* dst = eidx + N_EDGES;

    char* ws = (char*)d_ws;
    size_t szN = (size_t)N_NODES * HID * sizeof(float);        // 25.6 MB
    float* embA = (float*)(ws);                                // layer-0 out
    unsigned short* AGGb = (unsigned short*)(ws + szN);        // bf16 agg (12.8 MB)
    char*  kvq  = ws + 2 * szN;
    unsigned short* Kbf = (unsigned short*)kvq;                // 12.8 MB each
    unsigned short* Vbf = (unsigned short*)(kvq + (size_t)N_NODES * HID * 2);
    unsigned short* Qbf = (unsigned short*)(kvq + 2 * (size_t)N_NODES * HID * 2);
    float* l1out = (float*)kvq;                                // aliases K+V (dead by then)
    char*  p    = kvq + 3 * (size_t)N_NODES * HID * 2;
    int* perm    = (int*)p;  p += (size_t)PERM_SZ * 4;
    int* cnt     = (int*)p;  p += TN * 4;
    int* cursor  = (int*)p;  p += TN * 4;
    int* row_ptr = (int*)p;  p += (size_t)N_NODES * 4;
    int* cnt_dst = (int*)p;  p += (size_t)N_NODES * 4;
    int* cur_dst = (int*)p;  p += (size_t)N_NODES * 4;
    int* bsum    = (int*)p;  p += 256 * 4;
    int* csr_sd  = (int*)p;  p += (size_t)N_EDGES * 4;
    int* csr_et  = (int*)p;  p += (size_t)N_EDGES * 4;
    int* btile_sd = (int*)p; p += (size_t)NB * TPBMAX * 16 * 4;   // 5.2 MB
    int* btile_lp = (int*)p; p += (size_t)NB * TPBMAX * 16 * 4;   // 5.2 MB
    int* btile_r  = (int*)p; p += (size_t)NB * TPBMAX * 4;
    int* ntb      = (int*)p; p += (size_t)NB * 4;
    size_t wmat = (size_t)HID * HID;
    unsigned short* WkT  = (unsigned short*)p;  p += 2 * TN * wmat * 2;
    unsigned short* WqT  = (unsigned short*)p;  p += 2 * TN * wmat * 2;
    unsigned short* WvT  = (unsigned short*)p;  p += 2 * TN * wmat * 2;
    unsigned short* WaT  = (unsigned short*)p;  p += 2 * TN * wmat * 2;
    unsigned short* WffT = (unsigned short*)p;  p += wmat * 2;
    unsigned short* WattT = (unsigned short*)p; p += 2 * 64 * 256 * 2;
    unsigned short* WmsgT = (unsigned short*)p; p += 2 * 64 * 256 * 2;

    // weight conversion (once per launch)
    wconv_kernel<<<2 * TN * 8, 256, 0, stream>>>(Wk, WkT);
    wconv_kernel<<<2 * TN * 8, 256, 0, stream>>>(Wq, WqT);
    wconv_kernel<<<2 * TN * 8, 256, 0, stream>>>(Wv, WvT);
    wconv_kernel<<<2 * TN * 8, 256, 0, stream>>>(Wa, WaT);
    wconv_kernel<<<8, 256, 0, stream>>>(Wff, WffT);
    wsmall_conv<<<128, 256, 0, stream>>>(Watt, pri, WattT);     // pri/4 baked in
    wsmall_conv<<<128, 256, 0, stream>>>(Wmsg, nullptr, WmsgT);

    // node type sort (once)
    hipMemsetAsync(cnt, 0, TN * 4, stream);
    hipMemsetAsync(perm, 0xFF, (size_t)PERM_SZ * 4, stream);
    hist_kernel<<<(N_NODES + 255) / 256, 256, 0, stream>>>(ntype, cnt);
    scan_kernel<<<1, 64, 0, stream>>>(cnt, cursor);
    scatter_kernel<<<(N_NODES + 255) / 256, 256, 0, stream>>>(ntype, cursor, perm);

    // edge CSR by dst, then per-window relation tiles (once)
    hipMemsetAsync(cnt_dst, 0, (size_t)N_NODES * 4, stream);
    hist_dst_kernel<<<(N_EDGES + 255) / 256, 256, 0, stream>>>(dst, cnt_dst);
    scan_block_kernel<<<SCAN_BLKS, 256, 0, stream>>>(cnt_dst, row_ptr, bsum);
    scan_top_kernel<<<1, 256, 0, stream>>>(bsum);
    scan_add_kernel<<<SCAN_BLKS, 256, 0, stream>>>(row_ptr, bsum, cur_dst);
    csr_scatter_kernel<<<(N_EDGES + 255) / 256, 256, 0, stream>>>(src, dst, etype, cur_dst,
                                                                  csr_sd, csr_et);
    btile_build<<<NB, 64, 0, stream>>>(row_ptr, csr_sd, csr_et,
                                       btile_sd, btile_lp, btile_r, ntb);

    for (int l = 0; l < 2; ++l) {
        const float* xin = l ? embA : x;
        float* xout = l ? l1out : embA;
        const float* skip_l = skip + (size_t)l * TN;
        const float* g_l    = ln_g + (size_t)l * HID;
        const float* b_l    = ln_b + (size_t)l * HID;
        const unsigned short* WkT_l = WkT + (size_t)l * TN * wmat;
        const unsigned short* WqT_l = WqT + (size_t)l * TN * wmat;
        const unsigned short* WvT_l = WvT + (size_t)l * TN * wmat;
        const unsigned short* WaT_l = WaT + (size_t)l * TN * wmat;
        const unsigned short* WattT_l = WattT + (size_t)l * 64 * 256;
        const unsigned short* WmsgT_l = WmsgT + (size_t)l * 64 * 256;

        gemm3_mfma<<<MAXTILES, 256, 0, stream>>>(xin, perm, ntype, WkT_l, WqT_l, WvT_l,
                                                 Kbf, Qbf, Vbf);
        fused_attn_kernel<<<NB, 512, 0, stream>>>(Kbf, Vbf, Qbf, row_ptr, cnt_dst,
                                                  btile_sd, btile_lp, btile_r, ntb,
                                                  WattT_l, WmsgT_l, AGGb);
        // Wa typed GEMM + SiLU + gated residual + LayerNorm (fused, bf16 agg in)
        gemm1_ln_mfma<<<MAXTILES, 256, 0, stream>>>(AGGb, perm, ntype, WaT_l, xin,
                                                    skip_l, g_l, b_l, xout);
    }
    // final FF: l1out @ Wff + bff -> d_out
    gemm1_mfma<<<(N_NODES + TILE - 1) / TILE, 256, 0, stream>>>(l1out, nullptr, ntype, WffT,
                                                                bff, (float*)d_out);
}